// Round 8
// baseline (1243.667 us; speedup 1.0000x reference)
//
#include <hip/hip_runtime.h>
#include <hip/hip_bf16.h>
#include <math.h>

#define B_TOTAL 40960
#define NGRP 20
#define GSZ 2048
#define HPAD 68
#define CPART 4

typedef short short8 __attribute__((ext_vector_type(8)));
typedef short short4v __attribute__((ext_vector_type(4)));
typedef float f32x4 __attribute__((ext_vector_type(4)));
typedef float f32x16 __attribute__((ext_vector_type(16)));

// ---------------- group scatter ----------------
__global__ void k_scatter(const int* __restrict__ bid, int* __restrict__ grp,
                          int* __restrict__ cnt)
{
    int i = blockIdx.x * 256 + threadIdx.x;
    if (i < B_TOTAL) {
        int g = bid[i];
        int p = atomicAdd(&cnt[g], 1);
        grp[g * GSZ + p] = i;
    }
}

// ---------------- bf16 helpers ----------------
__device__ __forceinline__ unsigned short bf16rne(float v)
{
    unsigned int u = __float_as_uint(v);
    unsigned int r = (u + 0x7FFFu + ((u >> 16) & 1u)) >> 16;
    return (unsigned short)r;
}

__device__ __forceinline__ float bf2f(unsigned short h)
{
    return __uint_as_float((unsigned int)h << 16);
}

__device__ __forceinline__ void splitbf16(const float* v, short8& hi, short8& lo)
{
    #pragma unroll
    for (int j = 0; j < 8; j++) {
        unsigned short h = bf16rne(v[j]);
        hi[j] = (short)h;
        lo[j] = (short)bf16rne(v[j] - bf2f(h));
    }
}

// ordered-float key: monotonic unsigned encoding of float
__device__ __forceinline__ unsigned int fkey(float f)
{
    unsigned int u = __float_as_uint(f);
    unsigned int m = (unsigned int)((int)u >> 31) | 0x80000000u;
    return u ^ m;
}

__device__ __forceinline__ void ins3u(unsigned long long k,
    unsigned long long& k0, unsigned long long& k1, unsigned long long& k2)
{
    if (k < k0)      { k2 = k1; k1 = k0; k0 = k; }
    else if (k < k1) { k2 = k1; k1 = k; }
    else if (k < k2) { k2 = k; }
}

__device__ __forceinline__ void merge16(unsigned long long& a,
    unsigned long long& b, unsigned long long& c)
{
    #pragma unroll
    for (int m = 1; m <= 8; m <<= 1) {
        unsigned long long o0 = (unsigned long long)__shfl_xor((long long)a, m);
        unsigned long long o1 = (unsigned long long)__shfl_xor((long long)b, m);
        unsigned long long o2 = (unsigned long long)__shfl_xor((long long)c, m);
        ins3u(o0, a, b, c);
        ins3u(o1, a, b, c);
        ins3u(o2, a, b, c);
    }
}

// ---------------- kNN stage 1: gather -> packed bf16 hi/lo planes + norms ----------------
__global__ __launch_bounds__(256) void k_gather(const float* __restrict__ x,
    const int* __restrict__ grp, unsigned short* __restrict__ xbh,
    unsigned short* __restrict__ xbl, float* __restrict__ cn)
{
    __shared__ float tile[128][65];
    __shared__ int ids[128];
    const int tid = threadIdx.x;
    const int g = blockIdx.y;
    const int q0 = blockIdx.x * 128;
    if (tid < 128) ids[tid] = grp[g * GSZ + q0 + tid];
    __syncthreads();
    for (int s = tid; s < 128 * 64; s += 256) {
        int q = s >> 6, d = s & 63;
        tile[q][d] = (d < 63) ? x[(size_t)ids[q] * 90 + d] : 0.f;
    }
    __syncthreads();
    if (tid < 128) {
        float a = 0.f;
        #pragma unroll
        for (int d = 0; d < 63; d++) a = fmaf(tile[tid][d], tile[tid][d], a);
        cn[g * GSZ + q0 + tid] = a;
    }
    for (int s = tid; s < 128 * 32; s += 256) {
        int q = s >> 5, dp = (s & 31) << 1;
        float v0 = tile[q][dp], v1 = tile[q][dp + 1];
        unsigned short h0 = bf16rne(v0), h1 = bf16rne(v1);
        unsigned short l0 = bf16rne(v0 - bf2f(h0)), l1 = bf16rne(v1 - bf2f(h1));
        size_t pt = (size_t)g * GSZ + q0 + q;
        ((unsigned int*)xbh)[pt * 32 + (dp >> 1)] = (unsigned int)h0 | ((unsigned int)h1 << 16);
        ((unsigned int*)xbl)[pt * 32 + (dp >> 1)] = (unsigned int)l0 | ((unsigned int)l1 << 16);
    }
}

// ---------------- kNN stage 2: MFMA distance tiles, global_load_lds staging, u64 top-3 ----------------
__device__ __forceinline__ void knn_issue(const unsigned short* __restrict__ xbh,
    const unsigned short* __restrict__ xbl, char* cbufp, size_t gbase,
    int cbeg, int chunk, int wave, int lane)
{
    #pragma unroll
    for (int r = 0; r < 4; r++) {
        int s = r * 4 + wave;
        const unsigned short* plane = (s < 8) ? xbh : xbl;
        const unsigned short* gp = plane + (gbase + cbeg + chunk * 64 + lane) * 64 + (s & 7) * 8;
        __builtin_amdgcn_global_load_lds(
            (const __attribute__((address_space(1))) void*)gp,
            (__attribute__((address_space(3))) void*)(cbufp + (s << 10)), 16, 0, 0);
    }
}

__global__ __launch_bounds__(256) void k_knn_mfma(const unsigned short* __restrict__ xbh,
    const unsigned short* __restrict__ xbl, const float* __restrict__ cn,
    unsigned long long* __restrict__ pkey)
{
    __shared__ char cbuf[2][16384];
    const int tid = threadIdx.x;
    const int lane = tid & 63;
    const int wave = tid >> 6;
    const int g = blockIdx.z;
    const int part = blockIdx.y;
    const int qt0 = blockIdx.x * 64 + wave * 16;
    const size_t gbase = (size_t)g * GSZ;
    const int lp = lane & 15;
    const int kgrp = lane >> 4;
    const int kg = kgrp << 3;

    const size_t qb = (gbase + qt0 + lp) * 64;
    short8 ah0 = *(const short8*)(xbh + qb + kg);
    short8 ah1 = *(const short8*)(xbh + qb + 32 + kg);
    short8 al0 = *(const short8*)(xbl + qb + kg);
    short8 al1 = *(const short8*)(xbl + qb + 32 + kg);

    const int qp0 = qt0 + (kgrp << 2);   // query row of acc[r] is qp0 + r

    unsigned long long K00 = ~0ull, K01 = ~0ull, K02 = ~0ull;
    unsigned long long K10 = ~0ull, K11 = ~0ull, K12 = ~0ull;
    unsigned long long K20 = ~0ull, K21 = ~0ull, K22 = ~0ull;
    unsigned long long K30 = ~0ull, K31 = ~0ull, K32 = ~0ull;

    const int cbeg = part * (GSZ / CPART);

    knn_issue(xbh, xbl, cbuf[0], gbase, cbeg, 0, wave, lane);

    for (int ch = 0; ch < 8; ch++) {
        const int cur = ch & 1;
        __syncthreads();   // vmcnt(0)+barrier: cbuf[cur] DMA complete, all prior reads retired
        if (ch < 7)
            knn_issue(xbh, xbl, cbuf[cur ^ 1], gbase, cbeg, ch + 1, wave, lane);
        const int cc0 = cbeg + ch * 64;
        #pragma unroll
        for (int ct = 0; ct < 4; ct++) {
            const int coff = ((ct * 16 + lp) << 4);
            short8 bh0 = *(const short8*)&cbuf[cur][((kgrp)      << 10) + coff];
            short8 bh1 = *(const short8*)&cbuf[cur][((4 + kgrp)  << 10) + coff];
            short8 bl0 = *(const short8*)&cbuf[cur][((8 + kgrp)  << 10) + coff];
            short8 bl1 = *(const short8*)&cbuf[cur][((12 + kgrp) << 10) + coff];
            f32x4 acc = {0.f, 0.f, 0.f, 0.f};
            acc = __builtin_amdgcn_mfma_f32_16x16x32_bf16(ah0, bh0, acc, 0, 0, 0);
            acc = __builtin_amdgcn_mfma_f32_16x16x32_bf16(ah1, bh1, acc, 0, 0, 0);
            acc = __builtin_amdgcn_mfma_f32_16x16x32_bf16(al0, bh0, acc, 0, 0, 0);
            acc = __builtin_amdgcn_mfma_f32_16x16x32_bf16(al1, bh1, acc, 0, 0, 0);
            acc = __builtin_amdgcn_mfma_f32_16x16x32_bf16(ah0, bl0, acc, 0, 0, 0);
            acc = __builtin_amdgcn_mfma_f32_16x16x32_bf16(ah1, bl1, acc, 0, 0, 0);
            const float cnv = cn[gbase + cc0 + ct * 16 + lp];
            const int cpos = cc0 + ct * 16 + lp;
            const unsigned long long kbase = (unsigned int)cpos;
            {
                float val = fmaf(-2.f, acc[0], cnv);
                unsigned long long k = ((unsigned long long)fkey(val) << 32) | kbase;
                if (cpos != qp0 + 0) ins3u(k, K00, K01, K02);
            }
            {
                float val = fmaf(-2.f, acc[1], cnv);
                unsigned long long k = ((unsigned long long)fkey(val) << 32) | kbase;
                if (cpos != qp0 + 1) ins3u(k, K10, K11, K12);
            }
            {
                float val = fmaf(-2.f, acc[2], cnv);
                unsigned long long k = ((unsigned long long)fkey(val) << 32) | kbase;
                if (cpos != qp0 + 2) ins3u(k, K20, K21, K22);
            }
            {
                float val = fmaf(-2.f, acc[3], cnv);
                unsigned long long k = ((unsigned long long)fkey(val) << 32) | kbase;
                if (cpos != qp0 + 3) ins3u(k, K30, K31, K32);
            }
        }
    }

    merge16(K00, K01, K02);
    merge16(K10, K11, K12);
    merge16(K20, K21, K22);
    merge16(K30, K31, K32);

    if (lp == 0) {
        size_t ob = (gbase + (size_t)qp0) * (CPART * 3) + part * 3;
        pkey[ob + 0] = K00; pkey[ob + 1] = K01; pkey[ob + 2] = K02;
        pkey[ob + 12 + 0] = K10; pkey[ob + 12 + 1] = K11; pkey[ob + 12 + 2] = K12;
        pkey[ob + 24 + 0] = K20; pkey[ob + 24 + 1] = K21; pkey[ob + 24 + 2] = K22;
        pkey[ob + 36 + 0] = K30; pkey[ob + 36 + 1] = K31; pkey[ob + 36 + 2] = K32;
    }
}

// ---------------- kNN stage 3: merge CPART partials from u64 keys ----------------
__global__ void k_knn_merge(const unsigned long long* __restrict__ pkey,
                            const int* __restrict__ grp, int* __restrict__ nbr)
{
    int t = blockIdx.x * 256 + threadIdx.x;
    if (t >= NGRP * GSZ) return;
    int g = t >> 11;
    unsigned long long k0 = ~0ull, k1 = ~0ull, k2 = ~0ull;
    const unsigned long long* pk = pkey + (size_t)t * (CPART * 3);
    #pragma unroll
    for (int r = 0; r < CPART * 3; r++) ins3u(pk[r], k0, k1, k2);
    int qi = grp[t];
    nbr[(size_t)qi * 3 + 0] = grp[(g << 11) + (int)(k0 & 0xFFFFFFFFull)];
    nbr[(size_t)qi * 3 + 1] = grp[(g << 11) + (int)(k1 & 0xFFFFFFFFull)];
    nbr[(size_t)qi * 3 + 2] = grp[(g << 11) + (int)(k2 & 0xFFFFFFFFull)];
}

// ---------------- trunk weight prep: split-bf16, fragment-major ----------------
__global__ void k_wprep(const float* __restrict__ w0, const float* __restrict__ wmid,
                        const float* __restrict__ wskip, const float* __restrict__ wfin,
                        unsigned short* __restrict__ wfrag)
{
    int t = blockIdx.x * 256 + threadIdx.x;
    if (t >= 557056) return;
    const int CUMa[10] = {0,4,20,36,52,72,88,104,120,136};
    const int KCa[9]   = {4,16,16,16,20,16,16,16,16};
    int q = t >> 12;
    int L = 0;
    #pragma unroll
    for (int i = 0; i < 9; i++) if (q >= CUMa[i + 1]) L = i + 1;
    int cum = 0, kcn = 16;
    #pragma unroll
    for (int i = 0; i < 9; i++) if (L == i) { cum = CUMa[i]; kcn = KCa[i]; }
    int u = t - (cum << 12);
    int j = u & 7, lane = (u >> 3) & 63;
    int ckk = u >> 9;
    int kc = ckk % kcn, ct = ckk / kcn;
    int col = ct * 32 + (lane & 31);
    int k = kc * 16 + ((lane >> 5) << 3) + j;
    float w;
    if (L == 0)      w = (k < 63)  ? w0[k * 256 + col] : 0.f;
    else if (L == 4) w = (k < 256) ? wskip[(63 + k) * 256 + col]
                       : (k < 319) ? wskip[(k - 256) * 256 + col] : 0.f;
    else if (L == 8) w = wfin[k * 256 + col];
    else {
        int m = (L <= 3) ? (L - 1) : (L - 2);
        w = wmid[(size_t)m * 65536 + k * 256 + col];
    }
    unsigned short hi = bf16rne(w);
    unsigned short lo = bf16rne(w - bf2f(hi));
    size_t base = ((size_t)cum << 13) + (size_t)(ct * kcn + kc) * 1024 + lane * 8 + j;
    wfrag[base] = hi;
    wfrag[base + 512] = lo;
}

// ---------------- fused trunk MLP: 4 waves share one 32-row tile, split-bf16 H in LDS ----------------
template<int KCH, int KCX, int OUTMODE>
__device__ __forceinline__ void mlayer(unsigned short (*Hh)[264], unsigned short (*Hl)[264],
    int rowbase, const float* __restrict__ x, const unsigned short* __restrict__ wl,
    const float* __restrict__ bias, float* __restrict__ gout, int lane, int wave)
{
    const int r31 = lane & 31, g = lane >> 5;
    constexpr int KC = KCH + KCX;
    short8 xh[KCX > 0 ? KCX : 1], xl[KCX > 0 ? KCX : 1];
    if (KCX > 0) {
        #pragma unroll
        for (int t = 0; t < KCX; t++) {
            float v[8];
            #pragma unroll
            for (int j = 0; j < 8; j++) {
                int kx = t * 16 + g * 8 + j;
                v[j] = (kx < 63) ? x[(size_t)(rowbase + r31) * 90 + kx] : 0.f;
            }
            splitbf16(v, xh[t], xl[t]);
        }
    }
    const int ct0 = wave * 2;
    f32x16 acc0, acc1;
    #pragma unroll
    for (int r = 0; r < 16; r++) { acc0[r] = 0.f; acc1[r] = 0.f; }
    const unsigned short* wp0 = wl + (size_t)ct0 * KC * 1024 + lane * 8;
    const unsigned short* wp1 = wp0 + (size_t)KC * 1024;
    #pragma unroll
    for (int kc = 0; kc < KCH; kc++) {
        short8 ah = *(const short8*)&Hh[r31][kc * 16 + g * 8];
        short8 al = *(const short8*)&Hl[r31][kc * 16 + g * 8];
        short8 b0h = *(const short8*)(wp0 + kc * 1024);
        short8 b0l = *(const short8*)(wp0 + kc * 1024 + 512);
        short8 b1h = *(const short8*)(wp1 + kc * 1024);
        short8 b1l = *(const short8*)(wp1 + kc * 1024 + 512);
        acc0 = __builtin_amdgcn_mfma_f32_32x32x16_bf16(ah, b0h, acc0, 0, 0, 0);
        acc1 = __builtin_amdgcn_mfma_f32_32x32x16_bf16(ah, b1h, acc1, 0, 0, 0);
        acc0 = __builtin_amdgcn_mfma_f32_32x32x16_bf16(al, b0h, acc0, 0, 0, 0);
        acc1 = __builtin_amdgcn_mfma_f32_32x32x16_bf16(al, b1h, acc1, 0, 0, 0);
        acc0 = __builtin_amdgcn_mfma_f32_32x32x16_bf16(ah, b0l, acc0, 0, 0, 0);
        acc1 = __builtin_amdgcn_mfma_f32_32x32x16_bf16(ah, b1l, acc1, 0, 0, 0);
    }
    #pragma unroll
    for (int t = 0; t < KCX; t++) {
        const int kc = KCH + t;
        short8 b0h = *(const short8*)(wp0 + kc * 1024);
        short8 b0l = *(const short8*)(wp0 + kc * 1024 + 512);
        short8 b1h = *(const short8*)(wp1 + kc * 1024);
        short8 b1l = *(const short8*)(wp1 + kc * 1024 + 512);
        acc0 = __builtin_amdgcn_mfma_f32_32x32x16_bf16(xh[t], b0h, acc0, 0, 0, 0);
        acc1 = __builtin_amdgcn_mfma_f32_32x32x16_bf16(xh[t], b1h, acc1, 0, 0, 0);
        acc0 = __builtin_amdgcn_mfma_f32_32x32x16_bf16(xl[t], b0h, acc0, 0, 0, 0);
        acc1 = __builtin_amdgcn_mfma_f32_32x32x16_bf16(xl[t], b1h, acc1, 0, 0, 0);
        acc0 = __builtin_amdgcn_mfma_f32_32x32x16_bf16(xh[t], b0l, acc0, 0, 0, 0);
        acc1 = __builtin_amdgcn_mfma_f32_32x32x16_bf16(xh[t], b1l, acc1, 0, 0, 0);
    }
    const float bv0 = bias[ct0 * 32 + r31];
    const float bv1 = bias[ct0 * 32 + 32 + r31];
    if (OUTMODE == 0) {
        __syncthreads();
        #pragma unroll
        for (int r = 0; r < 16; r++) {
            int row = (r & 3) + 8 * (r >> 2) + 4 * g;
            float v0 = fmaxf(acc0[r] + bv0, 0.f);
            float v1 = fmaxf(acc1[r] + bv1, 0.f);
            unsigned short h0 = bf16rne(v0), h1 = bf16rne(v1);
            Hh[row][ct0 * 32 + r31] = h0;
            Hl[row][ct0 * 32 + r31] = bf16rne(v0 - bf2f(h0));
            Hh[row][ct0 * 32 + 32 + r31] = h1;
            Hl[row][ct0 * 32 + 32 + r31] = bf16rne(v1 - bf2f(h1));
        }
        __syncthreads();
    } else {
        #pragma unroll
        for (int r = 0; r < 16; r++) {
            int row = (r & 3) + 8 * (r >> 2) + 4 * g;
            gout[(size_t)(rowbase + row) * 256 + ct0 * 32 + r31] = acc0[r] + bv0;
            gout[(size_t)(rowbase + row) * 256 + ct0 * 32 + 32 + r31] = acc1[r] + bv1;
        }
    }
}

__global__ __launch_bounds__(256, 4) void k_trunk_mfma(const float* __restrict__ x,
    const unsigned short* __restrict__ wfrag,
    const float* __restrict__ b0, const float* __restrict__ bmid,
    const float* __restrict__ bskip, const float* __restrict__ bfin,
    const float* __restrict__ wsig, const float* __restrict__ bsig,
    float* __restrict__ feat, float* __restrict__ out)
{
    __shared__ unsigned short Hh[32][264];
    __shared__ unsigned short Hl[32][264];
    const int lane = threadIdx.x & 63;
    const int wave = threadIdx.x >> 6;
    const int rowbase = blockIdx.x * 32;
    const unsigned short* W = wfrag;
    mlayer<0, 4, 0>(Hh, Hl, rowbase, x, W + (size_t)0   * 8192, b0,          nullptr, lane, wave);
    mlayer<16,0, 0>(Hh, Hl, rowbase, x, W + (size_t)4   * 8192, bmid + 0,    nullptr, lane, wave);
    mlayer<16,0, 0>(Hh, Hl, rowbase, x, W + (size_t)20  * 8192, bmid + 256,  nullptr, lane, wave);
    mlayer<16,0, 0>(Hh, Hl, rowbase, x, W + (size_t)36  * 8192, bmid + 512,  nullptr, lane, wave);
    mlayer<16,4, 0>(Hh, Hl, rowbase, x, W + (size_t)52  * 8192, bskip,       nullptr, lane, wave);
    mlayer<16,0, 0>(Hh, Hl, rowbase, x, W + (size_t)72  * 8192, bmid + 768,  nullptr, lane, wave);
    mlayer<16,0, 0>(Hh, Hl, rowbase, x, W + (size_t)88  * 8192, bmid + 1024, nullptr, lane, wave);
    mlayer<16,0, 0>(Hh, Hl, rowbase, x, W + (size_t)104 * 8192, bmid + 1280, nullptr, lane, wave);
    mlayer<16,0, 1>(Hh, Hl, rowbase, x, W + (size_t)120 * 8192, bfin,        feat,    lane, wave);
    if (wave == 0) {
        const int r31 = lane & 31, g = lane >> 5;
        float s = 0.f;
        #pragma unroll
        for (int kk = 0; kk < 32; kk++) {
            short4v hh = *(const short4v*)&Hh[r31][g * 128 + kk * 4];
            short4v hl = *(const short4v*)&Hl[r31][g * 128 + kk * 4];
            float4 wv = *(const float4*)&wsig[g * 128 + kk * 4];
            s = fmaf(bf2f((unsigned short)hh[0]) + bf2f((unsigned short)hl[0]), wv.x, s);
            s = fmaf(bf2f((unsigned short)hh[1]) + bf2f((unsigned short)hl[1]), wv.y, s);
            s = fmaf(bf2f((unsigned short)hh[2]) + bf2f((unsigned short)hl[2]), wv.z, s);
            s = fmaf(bf2f((unsigned short)hh[3]) + bf2f((unsigned short)hl[3]), wv.w, s);
        }
        s += __shfl_xor(s, 32);
        if (lane < 32) out[(size_t)(rowbase + r31) * 4 + 3] = s + bsig[0];
    }
}

// ---------------- helpers for fp32 tile GEMMs (pq/edge) ----------------
__device__ __forceinline__ void fma88(float acc[8][8], float4 a0, float4 a1,
                                      float4 b0, float4 b1)
{
    float av[8] = {a0.x,a0.y,a0.z,a0.w,a1.x,a1.y,a1.z,a1.w};
    float bv[8] = {b0.x,b0.y,b0.z,b0.w,b1.x,b1.y,b1.z,b1.w};
    #pragma unroll
    for (int i = 0; i < 8; i++)
        #pragma unroll
        for (int j = 0; j < 8; j++)
            acc[i][j] = fmaf(av[i], bv[j], acc[i][j]);
}

__device__ __forceinline__ void stage_wpq(const float* __restrict__ ew1, int k0, int K,
                                          float4 st[4], int tid)
{
    #pragma unroll
    for (int u = 0; u < 4; u++) {
        int f = tid + (u << 8);
        int kk = f >> 6, c4 = (f & 63) << 2;
        int k = k0 + kk;
        if (k >= K) st[u] = make_float4(0.f, 0.f, 0.f, 0.f);
        else st[u] = (c4 < 128) ? *(const float4*)&ew1[(size_t)k * 128 + c4]
                                : *(const float4*)&ew1[(size_t)(K + k) * 128 + (c4 - 128)];
    }
}

__device__ __forceinline__ void stage_write(float (*buf)[256], const float4 st[4], int tid)
{
    #pragma unroll
    for (int u = 0; u < 4; u++) {
        int f = tid + (u << 8);
        int kk = f >> 6, c4 = (f & 63) << 2;
        *(float4*)&buf[kk][c4] = st[u];
    }
}

// ---------------- PQ GEMMs for edge convs ----------------
__global__ __launch_bounds__(256) void k_pq1(const float* __restrict__ feat,
    const float* __restrict__ x, const float* __restrict__ ew1,
    float* __restrict__ PQ)
{
    __shared__ float aT[288][HPAD];
    __shared__ float wbuf[2][16][256];
    const int tid = threadIdx.x;
    const int tx = tid & 31, ty = tid >> 5;
    const int cLo = tx * 4, cHi = 128 + tx * 4, r0 = ty * 8;
    const int row0 = blockIdx.x * 64;
    const int K = 283;
    for (int s = tid; s < 64 * 256; s += 256) {
        int r = s >> 8, k = s & 255;
        aT[k][r] = feat[(size_t)(row0 + r) * 256 + k];
    }
    for (int s = tid; s < 32 * 64; s += 256) {
        int dd = s >> 6, r = s & 63;
        aT[256 + dd][r] = (dd < 27) ? x[(size_t)(row0 + r) * 90 + 63 + dd] : 0.f;
    }
    float4 st[4];
    stage_wpq(ew1, 0, K, st, tid);
    __syncthreads();
    stage_write(wbuf[0], st, tid);
    __syncthreads();

    float acc[8][8];
    #pragma unroll
    for (int i = 0; i < 8; i++)
        #pragma unroll
        for (int j = 0; j < 8; j++) acc[i][j] = 0.f;

    const int nch = (K + 15) >> 4;
    for (int c = 0; c < nch; c++) {
        const int cur = c & 1;
        const bool more = (c + 1 < nch);
        if (more) stage_wpq(ew1, (c + 1) << 4, K, st, tid);
        const float (*wb)[256] = wbuf[cur];
        const int kbase = c << 4;
        #pragma unroll
        for (int kk = 0; kk < 16; kk++) {
            const int k = kbase + kk;
            float4 a0 = *(const float4*)&aT[k][r0];
            float4 a1 = *(const float4*)&aT[k][r0 + 4];
            float4 b0 = *(const float4*)&wb[kk][cLo];
            float4 b1 = *(const float4*)&wb[kk][cHi];
            fma88(acc, a0, a1, b0, b1);
        }
        if (more) stage_write(wbuf[cur ^ 1], st, tid);
        __syncthreads();
    }
    #pragma unroll
    for (int i = 0; i < 8; i++) {
        *(float4*)&PQ[(size_t)(row0 + r0 + i) * 256 + cLo] =
            make_float4(acc[i][0], acc[i][1], acc[i][2], acc[i][3]);
        *(float4*)&PQ[(size_t)(row0 + r0 + i) * 256 + cHi] =
            make_float4(acc[i][4], acc[i][5], acc[i][6], acc[i][7]);
    }
}

__global__ __launch_bounds__(256) void k_pq2(const float* __restrict__ d1,
    const float* __restrict__ ew1, float* __restrict__ PQ)
{
    __shared__ float aT[128][HPAD];
    __shared__ float wbuf[2][16][256];
    const int tid = threadIdx.x;
    const int tx = tid & 31, ty = tid >> 5;
    const int cLo = tx * 4, cHi = 128 + tx * 4, r0 = ty * 8;
    const int row0 = blockIdx.x * 64;
    const int K = 128;
    for (int s = tid; s < 64 * 128; s += 256) {
        int r = s >> 7, k = s & 127;
        aT[k][r] = d1[(size_t)(row0 + r) * 128 + k];
    }
    float4 st[4];
    stage_wpq(ew1, 0, K, st, tid);
    __syncthreads();
    stage_write(wbuf[0], st, tid);
    __syncthreads();

    float acc[8][8];
    #pragma unroll
    for (int i = 0; i < 8; i++)
        #pragma unroll
        for (int j = 0; j < 8; j++) acc[i][j] = 0.f;

    for (int c = 0; c < 8; c++) {
        const int cur = c & 1;
        const bool more = (c < 7);
        if (more) stage_wpq(ew1, (c + 1) << 4, K, st, tid);
        const float (*wb)[256] = wbuf[cur];
        const int kbase = c << 4;
        #pragma unroll
        for (int kk = 0; kk < 16; kk++) {
            const int k = kbase + kk;
            float4 a0 = *(const float4*)&aT[k][r0];
            float4 a1 = *(const float4*)&aT[k][r0 + 4];
            float4 b0 = *(const float4*)&wb[kk][cLo];
            float4 b1 = *(const float4*)&wb[kk][cHi];
            fma88(acc, a0, a1, b0, b1);
        }
        if (more) stage_write(wbuf[cur ^ 1], st, tid);
        __syncthreads();
    }
    #pragma unroll
    for (int i = 0; i < 8; i++) {
        *(float4*)&PQ[(size_t)(row0 + r0 + i) * 256 + cLo] =
            make_float4(acc[i][0], acc[i][1], acc[i][2], acc[i][3]);
        *(float4*)&PQ[(size_t)(row0 + r0 + i) * 256 + cHi] =
            make_float4(acc[i][4], acc[i][5], acc[i][6], acc[i][7]);
    }
}

// ---------------- edge conv ----------------
template<int RGB>
__global__ __launch_bounds__(256) void k_edge(const float* __restrict__ PQ,
    const float* __restrict__ b1, const float* __restrict__ w2,
    const float* __restrict__ b2, const int* __restrict__ nbr,
    float* __restrict__ dout,
    const float* __restrict__ wrgb, const float* __restrict__ brgb,
    float* __restrict__ out)
{
    __shared__ float h1T[128][97];
    __shared__ float wb[32][128];
    const int tid = threadIdx.x;
    const int n0 = blockIdx.x * 32;
    {
        const int c = tid & 127, eg = tid >> 7;
        const float bias = b1[c];
        for (int e = eg; e < 96; e += 2) {
            int n = e / 3;
            int jj = e - n * 3;
            int i = n0 + n;
            int j = nbr[(size_t)i * 3 + jj];
            float v = PQ[(size_t)i * 256 + c] + bias
                    + PQ[(size_t)j * 256 + 128 + c] - PQ[(size_t)i * 256 + 128 + c];
            h1T[c][e] = fmaxf(v, 0.f);
        }
    }
    const int cg = tid & 15, rg = tid >> 4;
    const int cLo = cg * 4, cHi = 64 + cg * 4, e0 = rg * 6;
    float acc[6][8];
    #pragma unroll
    for (int m = 0; m < 6; m++)
        #pragma unroll
        for (int j = 0; j < 8; j++) acc[m][j] = 0.f;
    for (int k0 = 0; k0 < 128; k0 += 32) {
        __syncthreads();
        for (int s = tid; s < 32 * 128; s += 256) {
            int kk = s >> 7, c = s & 127;
            wb[kk][c] = w2[(size_t)(k0 + kk) * 128 + c];
        }
        __syncthreads();
        for (int kk = 0; kk < 32; kk++) {
            const int k = k0 + kk;
            float av[6];
            #pragma unroll
            for (int m = 0; m < 6; m++) av[m] = h1T[k][e0 + m];
            float4 w0v = *(const float4*)&wb[kk][cLo];
            float4 w1v = *(const float4*)&wb[kk][cHi];
            float bv[8] = {w0v.x,w0v.y,w0v.z,w0v.w,w1v.x,w1v.y,w1v.z,w1v.w};
            #pragma unroll
            for (int m = 0; m < 6; m++)
                #pragma unroll
                for (int j = 0; j < 8; j++)
                    acc[m][j] = fmaf(av[m], bv[j], acc[m][j]);
        }
    }
    float bb[8];
    #pragma unroll
    for (int j = 0; j < 8; j++) bb[j] = b2[(j < 4) ? (cLo + j) : (cHi + j - 4)];
    float dA[8], dB[8];
    #pragma unroll
    for (int j = 0; j < 8; j++) {
        float h0 = fmaxf(acc[0][j] + bb[j], 0.f);
        float h1 = fmaxf(acc[1][j] + bb[j], 0.f);
        float h2 = fmaxf(acc[2][j] + bb[j], 0.f);
        float h3 = fmaxf(acc[3][j] + bb[j], 0.f);
        float h4 = fmaxf(acc[4][j] + bb[j], 0.f);
        float h5 = fmaxf(acc[5][j] + bb[j], 0.f);
        dA[j] = (h0 + h1 + h2) * (1.f / 3.f);
        dB[j] = (h3 + h4 + h5) * (1.f / 3.f);
    }
    if (!RGB) {
        *(float4*)&dout[(size_t)(n0 + 2*rg) * 128 + cLo] = make_float4(dA[0], dA[1], dA[2], dA[3]);
        *(float4*)&dout[(size_t)(n0 + 2*rg) * 128 + cHi] = make_float4(dA[4], dA[5], dA[6], dA[7]);
        *(float4*)&dout[(size_t)(n0 + 2*rg + 1) * 128 + cLo] = make_float4(dB[0], dB[1], dB[2], dB[3]);
        *(float4*)&dout[(size_t)(n0 + 2*rg + 1) * 128 + cHi] = make_float4(dB[4], dB[5], dB[6], dB[7]);
    } else {
        __syncthreads();
        float* d2L = &h1T[0][0];
        #pragma unroll
        for (int j = 0; j < 4; j++) {
            d2L[(2*rg)     * 130 + cLo + j] = dA[j];
            d2L[(2*rg)     * 130 + cHi + j] = dA[j + 4];
            d2L[(2*rg + 1) * 130 + cLo + j] = dB[j];
            d2L[(2*rg + 1) * 130 + cHi + j] = dB[j + 4];
        }
        __syncthreads();
        if (tid < 96) {
            int n = tid / 3, ch = tid - 3 * (tid / 3);
            float s = brgb[ch];
            for (int k = 0; k < 128; k++) s = fmaf(d2L[n * 130 + k], wrgb[k * 3 + ch], s);
            out[(size_t)(n0 + n) * 4 + ch] = 1.f / (1.f + expf(-s));
        }
    }
}

// ---------------- launch ----------------
extern "C" void kernel_launch(void* const* d_in, const int* in_sizes, int n_in,
                              void* d_out, int out_size, void* d_ws, size_t ws_size,
                              hipStream_t stream)
{
    const float* x     = (const float*)d_in[0];
    const int*   bid   = (const int*)d_in[1];
    const float* w0    = (const float*)d_in[2];
    const float* b0    = (const float*)d_in[3];
    const float* wmid  = (const float*)d_in[4];
    const float* bmid  = (const float*)d_in[5];
    const float* wskip = (const float*)d_in[6];
    const float* bskip = (const float*)d_in[7];
    const float* wfin  = (const float*)d_in[8];
    const float* bfin  = (const float*)d_in[9];
    const float* wsig  = (const float*)d_in[10];
    const float* bsig  = (const float*)d_in[11];
    const float* e1w1  = (const float*)d_in[12];
    const float* e1b1  = (const float*)d_in[13];
    const float* e1w2  = (const float*)d_in[14];
    const float* e1b2  = (const float*)d_in[15];
    const float* e2w1  = (const float*)d_in[16];
    const float* e2b1  = (const float*)d_in[17];
    const float* e2w2  = (const float*)d_in[18];
    const float* e2b2  = (const float*)d_in[19];
    const float* wrgb  = (const float*)d_in[20];
    const float* brgb  = (const float*)d_in[21];
    float* out = (float*)d_out;

    char* ws = (char*)d_ws;
    int* cnt = (int*)ws;
    int* grp = (int*)(ws + 256);
    int* nbr = (int*)(ws + 256 + NGRP * GSZ * 4);
    float* bufA = (float*)(ws + (1 << 20));                // 41.9 MB
    float* bufB = bufA + (size_t)B_TOTAL * 256;            // 41.9 MB

    unsigned short* xbh = (unsigned short*)bufA;
    unsigned short* xbl = xbh + (size_t)B_TOTAL * 64;
    float* cn   = (float*)(xbl + (size_t)B_TOTAL * 64);
    unsigned long long* pkey = (unsigned long long*)(cn + B_TOTAL);  // 40960*12 u64 = 3.9MB
    unsigned short* wfrag = (unsigned short*)((char*)bufB + ((size_t)39 << 20));

    hipMemsetAsync(cnt, 0, 256, stream);
    k_scatter<<<B_TOTAL / 256, 256, 0, stream>>>(bid, grp, cnt);
    k_wprep<<<(557056 + 255) / 256, 256, 0, stream>>>(w0, wmid, wskip, wfin, wfrag);
    k_gather<<<dim3(GSZ / 128, NGRP), 256, 0, stream>>>(x, grp, xbh, xbl, cn);
    k_knn_mfma<<<dim3(GSZ / 64, CPART, NGRP), 256, 0, stream>>>(xbh, xbl, cn, pkey);
    k_knn_merge<<<(NGRP * GSZ + 255) / 256, 256, 0, stream>>>(pkey, grp, nbr);
    k_trunk_mfma<<<B_TOTAL / 32, 256, 0, stream>>>(x, wfrag, b0, bmid, bskip, bfin,
                                                   wsig, bsig, bufA, out);
    k_pq1<<<B_TOTAL / 64, 256, 0, stream>>>(bufA, x, e1w1, bufB);
    k_edge<0><<<B_TOTAL / 32, 256, 0, stream>>>(bufB, e1b1, e1w2, e1b2, nbr, bufA,
                                                nullptr, nullptr, nullptr);
    k_pq2<<<B_TOTAL / 64, 256, 0, stream>>>(bufA, e2w1, bufB);
    k_edge<1><<<B_TOTAL / 32, 256, 0, stream>>>(bufB, e2b1, e2w2, e2b2, nbr, nullptr,
                                                wrgb, brgb, out);
}

// Round 9
// 749.619 us; speedup vs baseline: 1.6591x; 1.6591x over previous
//
#include <hip/hip_runtime.h>
#include <hip/hip_bf16.h>
#include <math.h>

#define B_TOTAL 40960
#define NGRP 20
#define GSZ 2048
#define HPAD 68
#define CPART 4

typedef short short8 __attribute__((ext_vector_type(8)));
typedef short short4v __attribute__((ext_vector_type(4)));
typedef float f32x4 __attribute__((ext_vector_type(4)));
typedef float f32x16 __attribute__((ext_vector_type(16)));

// ---------------- group scatter ----------------
__global__ void k_scatter(const int* __restrict__ bid, int* __restrict__ grp,
                          int* __restrict__ cnt)
{
    int i = blockIdx.x * 256 + threadIdx.x;
    if (i < B_TOTAL) {
        int g = bid[i];
        int p = atomicAdd(&cnt[g], 1);
        grp[g * GSZ + p] = i;
    }
}

// ---------------- bf16 helpers ----------------
__device__ __forceinline__ unsigned short bf16rne(float v)
{
    unsigned int u = __float_as_uint(v);
    unsigned int r = (u + 0x7FFFu + ((u >> 16) & 1u)) >> 16;
    return (unsigned short)r;
}

__device__ __forceinline__ float bf2f(unsigned short h)
{
    return __uint_as_float((unsigned int)h << 16);
}

__device__ __forceinline__ void splitbf16(const float* v, short8& hi, short8& lo)
{
    #pragma unroll
    for (int j = 0; j < 8; j++) {
        unsigned short h = bf16rne(v[j]);
        hi[j] = (short)h;
        lo[j] = (short)bf16rne(v[j] - bf2f(h));
    }
}

// ordered-float key: monotonic unsigned encoding of float
__device__ __forceinline__ unsigned int fkey(float f)
{
    unsigned int u = __float_as_uint(f);
    unsigned int m = (unsigned int)((int)u >> 31) | 0x80000000u;
    return u ^ m;
}

// branch-free sorted insert of (k,i) into ((k0,i0) <= (k1,i1) <= (k2,i2))
__device__ __forceinline__ void ins3p(unsigned int k, unsigned int i,
    unsigned int& k0, unsigned int& i0, unsigned int& k1, unsigned int& i1,
    unsigned int& k2, unsigned int& i2)
{
    bool c0 = k < k0;
    unsigned int tk = c0 ? k0 : k, ti = c0 ? i0 : i;
    k0 = c0 ? k : k0;  i0 = c0 ? i : i0;
    bool c1 = tk < k1;
    unsigned int sk = c1 ? k1 : tk, si = c1 ? i1 : ti;
    k1 = c1 ? tk : k1; i1 = c1 ? ti : i1;
    bool c2 = sk < k2;
    k2 = c2 ? sk : k2; i2 = c2 ? si : i2;
}

__device__ __forceinline__ void mergerow(unsigned int& k0, unsigned int& i0,
    unsigned int& k1, unsigned int& i1, unsigned int& k2, unsigned int& i2)
{
    #pragma unroll
    for (int m = 1; m <= 8; m <<= 1) {
        unsigned int ok0 = (unsigned int)__shfl_xor((int)k0, m);
        unsigned int oi0 = (unsigned int)__shfl_xor((int)i0, m);
        unsigned int ok1 = (unsigned int)__shfl_xor((int)k1, m);
        unsigned int oi1 = (unsigned int)__shfl_xor((int)i1, m);
        unsigned int ok2 = (unsigned int)__shfl_xor((int)k2, m);
        unsigned int oi2 = (unsigned int)__shfl_xor((int)i2, m);
        ins3p(ok0, oi0, k0, i0, k1, i1, k2, i2);
        ins3p(ok1, oi1, k0, i0, k1, i1, k2, i2);
        ins3p(ok2, oi2, k0, i0, k1, i1, k2, i2);
    }
}

// ---------------- kNN stage 1: gather -> packed bf16 hi/lo planes + norms ----------------
__global__ __launch_bounds__(256) void k_gather(const float* __restrict__ x,
    const int* __restrict__ grp, unsigned short* __restrict__ xbh,
    unsigned short* __restrict__ xbl, float* __restrict__ cn)
{
    __shared__ float tile[128][65];
    __shared__ int ids[128];
    const int tid = threadIdx.x;
    const int g = blockIdx.y;
    const int q0 = blockIdx.x * 128;
    if (tid < 128) ids[tid] = grp[g * GSZ + q0 + tid];
    __syncthreads();
    for (int s = tid; s < 128 * 64; s += 256) {
        int q = s >> 6, d = s & 63;
        tile[q][d] = (d < 63) ? x[(size_t)ids[q] * 90 + d] : 0.f;
    }
    __syncthreads();
    if (tid < 128) {
        float a = 0.f;
        #pragma unroll
        for (int d = 0; d < 63; d++) a = fmaf(tile[tid][d], tile[tid][d], a);
        cn[g * GSZ + q0 + tid] = a;
    }
    for (int s = tid; s < 128 * 32; s += 256) {
        int q = s >> 5, dp = (s & 31) << 1;
        float v0 = tile[q][dp], v1 = tile[q][dp + 1];
        unsigned short h0 = bf16rne(v0), h1 = bf16rne(v1);
        unsigned short l0 = bf16rne(v0 - bf2f(h0)), l1 = bf16rne(v1 - bf2f(h1));
        size_t pt = (size_t)g * GSZ + q0 + q;
        ((unsigned int*)xbh)[pt * 32 + (dp >> 1)] = (unsigned int)h0 | ((unsigned int)h1 << 16);
        ((unsigned int*)xbl)[pt * 32 + (dp >> 1)] = (unsigned int)l0 | ((unsigned int)l1 << 16);
    }
}

// ---------------- kNN stage 2: MFMA distance tiles, LDS-shared stream, branch-free top3 ----------------
__global__ __launch_bounds__(256) void k_knn_mfma(const unsigned short* __restrict__ xbh,
    const unsigned short* __restrict__ xbl, const float* __restrict__ cn,
    unsigned long long* __restrict__ pkey)
{
    __shared__ char cbuf[2][16384];
    const int tid = threadIdx.x;
    const int lane = tid & 63;
    const int wave = tid >> 6;
    const int g = blockIdx.z;
    const int part = blockIdx.y;
    const int qt0 = blockIdx.x * 64 + wave * 16;
    const size_t gbase = (size_t)g * GSZ;
    const int lp = lane & 15;
    const int kgrp = lane >> 4;
    const int kg = kgrp << 3;

    const size_t qb = (gbase + qt0 + lp) * 64;
    short8 ah0 = *(const short8*)(xbh + qb + kg);
    short8 ah1 = *(const short8*)(xbh + qb + 32 + kg);
    short8 al0 = *(const short8*)(xbl + qb + kg);
    short8 al1 = *(const short8*)(xbl + qb + 32 + kg);

    const int qp0 = qt0 + (kgrp << 2);   // query row of acc[r] is qp0 + r

    unsigned int K00 = ~0u, I00 = 0, K01 = ~0u, I01 = 0, K02 = ~0u, I02 = 0;
    unsigned int K10 = ~0u, I10 = 0, K11 = ~0u, I11 = 0, K12 = ~0u, I12 = 0;
    unsigned int K20 = ~0u, I20 = 0, K21 = ~0u, I21 = 0, K22 = ~0u, I22 = 0;
    unsigned int K30 = ~0u, I30 = 0, K31 = ~0u, I31 = 0, K32 = ~0u, I32 = 0;

    const int scand = tid & 63;
    const int cbeg = part * (GSZ / CPART);
    const int s0 = wave, s1 = 4 + wave, s2 = 8 + wave, s3 = 12 + wave;
    const unsigned short* pl0 = (s0 < 8) ? xbh : xbl;
    const unsigned short* pl1 = (s1 < 8) ? xbh : xbl;
    const unsigned short* pl2 = (s2 < 8) ? xbh : xbl;
    const unsigned short* pl3 = (s3 < 8) ? xbh : xbl;

    short8 st0, st1, st2, st3;
    {
        size_t cb = (gbase + cbeg + scand) * 64;
        st0 = *(const short8*)(pl0 + cb + (s0 & 7) * 8);
        st1 = *(const short8*)(pl1 + cb + (s1 & 7) * 8);
        st2 = *(const short8*)(pl2 + cb + (s2 & 7) * 8);
        st3 = *(const short8*)(pl3 + cb + (s3 & 7) * 8);
    }
    *(short8*)&cbuf[0][(s0 << 10) + (scand << 4)] = st0;
    *(short8*)&cbuf[0][(s1 << 10) + (scand << 4)] = st1;
    *(short8*)&cbuf[0][(s2 << 10) + (scand << 4)] = st2;
    *(short8*)&cbuf[0][(s3 << 10) + (scand << 4)] = st3;

    for (int ch = 0; ch < 8; ch++) {
        const int cur = ch & 1;
        __syncthreads();                   // cbuf[cur] ready for all waves
        if (ch < 7) {                      // issue next chunk's loads early
            size_t cb = (gbase + cbeg + (ch + 1) * 64 + scand) * 64;
            st0 = *(const short8*)(pl0 + cb + (s0 & 7) * 8);
            st1 = *(const short8*)(pl1 + cb + (s1 & 7) * 8);
            st2 = *(const short8*)(pl2 + cb + (s2 & 7) * 8);
            st3 = *(const short8*)(pl3 + cb + (s3 & 7) * 8);
        }
        const int cc0 = cbeg + ch * 64;
        #pragma unroll
        for (int ct = 0; ct < 4; ct++) {
            const int coff = ((ct * 16 + lp) << 4);
            short8 bh0 = *(const short8*)&cbuf[cur][((kgrp)      << 10) + coff];
            short8 bh1 = *(const short8*)&cbuf[cur][((4 + kgrp)  << 10) + coff];
            short8 bl0 = *(const short8*)&cbuf[cur][((8 + kgrp)  << 10) + coff];
            short8 bl1 = *(const short8*)&cbuf[cur][((12 + kgrp) << 10) + coff];
            f32x4 acc = {0.f, 0.f, 0.f, 0.f};
            acc = __builtin_amdgcn_mfma_f32_16x16x32_bf16(ah0, bh0, acc, 0, 0, 0);
            acc = __builtin_amdgcn_mfma_f32_16x16x32_bf16(ah1, bh1, acc, 0, 0, 0);
            acc = __builtin_amdgcn_mfma_f32_16x16x32_bf16(al0, bh0, acc, 0, 0, 0);
            acc = __builtin_amdgcn_mfma_f32_16x16x32_bf16(al1, bh1, acc, 0, 0, 0);
            acc = __builtin_amdgcn_mfma_f32_16x16x32_bf16(ah0, bl0, acc, 0, 0, 0);
            acc = __builtin_amdgcn_mfma_f32_16x16x32_bf16(ah1, bl1, acc, 0, 0, 0);
            const float cnv = cn[gbase + cc0 + ct * 16 + lp];
            const int cpos = cc0 + ct * 16 + lp;
            const unsigned int ci = (unsigned int)cpos;
            {
                unsigned int k = fkey(fmaf(-2.f, acc[0], cnv));
                k = (cpos == qp0 + 0) ? 0xFFFFFFFFu : k;
                ins3p(k, ci, K00, I00, K01, I01, K02, I02);
            }
            {
                unsigned int k = fkey(fmaf(-2.f, acc[1], cnv));
                k = (cpos == qp0 + 1) ? 0xFFFFFFFFu : k;
                ins3p(k, ci, K10, I10, K11, I11, K12, I12);
            }
            {
                unsigned int k = fkey(fmaf(-2.f, acc[2], cnv));
                k = (cpos == qp0 + 2) ? 0xFFFFFFFFu : k;
                ins3p(k, ci, K20, I20, K21, I21, K22, I22);
            }
            {
                unsigned int k = fkey(fmaf(-2.f, acc[3], cnv));
                k = (cpos == qp0 + 3) ? 0xFFFFFFFFu : k;
                ins3p(k, ci, K30, I30, K31, I31, K32, I32);
            }
        }
        if (ch < 7) {
            *(short8*)&cbuf[cur ^ 1][(s0 << 10) + (scand << 4)] = st0;
            *(short8*)&cbuf[cur ^ 1][(s1 << 10) + (scand << 4)] = st1;
            *(short8*)&cbuf[cur ^ 1][(s2 << 10) + (scand << 4)] = st2;
            *(short8*)&cbuf[cur ^ 1][(s3 << 10) + (scand << 4)] = st3;
        }
    }

    mergerow(K00, I00, K01, I01, K02, I02);
    mergerow(K10, I10, K11, I11, K12, I12);
    mergerow(K20, I20, K21, I21, K22, I22);
    mergerow(K30, I30, K31, I31, K32, I32);

    if (lp == 0) {
        size_t ob = (gbase + (size_t)qp0) * (CPART * 3) + part * 3;
        pkey[ob + 0]  = ((unsigned long long)K00 << 32) | I00;
        pkey[ob + 1]  = ((unsigned long long)K01 << 32) | I01;
        pkey[ob + 2]  = ((unsigned long long)K02 << 32) | I02;
        pkey[ob + 12] = ((unsigned long long)K10 << 32) | I10;
        pkey[ob + 13] = ((unsigned long long)K11 << 32) | I11;
        pkey[ob + 14] = ((unsigned long long)K12 << 32) | I12;
        pkey[ob + 24] = ((unsigned long long)K20 << 32) | I20;
        pkey[ob + 25] = ((unsigned long long)K21 << 32) | I21;
        pkey[ob + 26] = ((unsigned long long)K22 << 32) | I22;
        pkey[ob + 36] = ((unsigned long long)K30 << 32) | I30;
        pkey[ob + 37] = ((unsigned long long)K31 << 32) | I31;
        pkey[ob + 38] = ((unsigned long long)K32 << 32) | I32;
    }
}

// ---------------- kNN stage 3: merge CPART partials from u64 keys ----------------
__device__ __forceinline__ void ins3u(unsigned long long k,
    unsigned long long& k0, unsigned long long& k1, unsigned long long& k2)
{
    if (k < k0)      { k2 = k1; k1 = k0; k0 = k; }
    else if (k < k1) { k2 = k1; k1 = k; }
    else if (k < k2) { k2 = k; }
}

__global__ void k_knn_merge(const unsigned long long* __restrict__ pkey,
                            const int* __restrict__ grp, int* __restrict__ nbr)
{
    int t = blockIdx.x * 256 + threadIdx.x;
    if (t >= NGRP * GSZ) return;
    int g = t >> 11;
    unsigned long long k0 = ~0ull, k1 = ~0ull, k2 = ~0ull;
    const unsigned long long* pk = pkey + (size_t)t * (CPART * 3);
    #pragma unroll
    for (int r = 0; r < CPART * 3; r++) ins3u(pk[r], k0, k1, k2);
    int qi = grp[t];
    nbr[(size_t)qi * 3 + 0] = grp[(g << 11) + (int)(k0 & 0xFFFFFFFFull)];
    nbr[(size_t)qi * 3 + 1] = grp[(g << 11) + (int)(k1 & 0xFFFFFFFFull)];
    nbr[(size_t)qi * 3 + 2] = grp[(g << 11) + (int)(k2 & 0xFFFFFFFFull)];
}

// ---------------- trunk weight prep: split-bf16, fragment-major ----------------
__global__ void k_wprep(const float* __restrict__ w0, const float* __restrict__ wmid,
                        const float* __restrict__ wskip, const float* __restrict__ wfin,
                        unsigned short* __restrict__ wfrag)
{
    int t = blockIdx.x * 256 + threadIdx.x;
    if (t >= 557056) return;
    const int CUMa[10] = {0,4,20,36,52,72,88,104,120,136};
    const int KCa[9]   = {4,16,16,16,20,16,16,16,16};
    int q = t >> 12;
    int L = 0;
    #pragma unroll
    for (int i = 0; i < 9; i++) if (q >= CUMa[i + 1]) L = i + 1;
    int cum = 0, kcn = 16;
    #pragma unroll
    for (int i = 0; i < 9; i++) if (L == i) { cum = CUMa[i]; kcn = KCa[i]; }
    int u = t - (cum << 12);
    int j = u & 7, lane = (u >> 3) & 63;
    int ckk = u >> 9;
    int kc = ckk % kcn, ct = ckk / kcn;
    int col = ct * 32 + (lane & 31);
    int k = kc * 16 + ((lane >> 5) << 3) + j;
    float w;
    if (L == 0)      w = (k < 63)  ? w0[k * 256 + col] : 0.f;
    else if (L == 4) w = (k < 256) ? wskip[(63 + k) * 256 + col]
                       : (k < 319) ? wskip[(k - 256) * 256 + col] : 0.f;
    else if (L == 8) w = wfin[k * 256 + col];
    else {
        int m = (L <= 3) ? (L - 1) : (L - 2);
        w = wmid[(size_t)m * 65536 + k * 256 + col];
    }
    unsigned short hi = bf16rne(w);
    unsigned short lo = bf16rne(w - bf2f(hi));
    size_t base = ((size_t)cum << 13) + (size_t)(ct * kcn + kc) * 1024 + lane * 8 + j;
    wfrag[base] = hi;
    wfrag[base + 512] = lo;
}

// ---------------- fused trunk MLP: 4 waves share one 32-row tile, split-bf16 H in LDS ----------------
template<int KCH, int KCX, int OUTMODE>
__device__ __forceinline__ void mlayer(unsigned short (*Hh)[264], unsigned short (*Hl)[264],
    int rowbase, const float* __restrict__ x, const unsigned short* __restrict__ wl,
    const float* __restrict__ bias, float* __restrict__ gout, int lane, int wave)
{
    const int r31 = lane & 31, g = lane >> 5;
    constexpr int KC = KCH + KCX;
    short8 xh[KCX > 0 ? KCX : 1], xl[KCX > 0 ? KCX : 1];
    if (KCX > 0) {
        #pragma unroll
        for (int t = 0; t < KCX; t++) {
            float v[8];
            #pragma unroll
            for (int j = 0; j < 8; j++) {
                int kx = t * 16 + g * 8 + j;
                v[j] = (kx < 63) ? x[(size_t)(rowbase + r31) * 90 + kx] : 0.f;
            }
            splitbf16(v, xh[t], xl[t]);
        }
    }
    const int ct0 = wave * 2;
    f32x16 acc0, acc1;
    #pragma unroll
    for (int r = 0; r < 16; r++) { acc0[r] = 0.f; acc1[r] = 0.f; }
    const unsigned short* wp0 = wl + (size_t)ct0 * KC * 1024 + lane * 8;
    const unsigned short* wp1 = wp0 + (size_t)KC * 1024;
    #pragma unroll
    for (int kc = 0; kc < KCH; kc++) {
        short8 ah = *(const short8*)&Hh[r31][kc * 16 + g * 8];
        short8 al = *(const short8*)&Hl[r31][kc * 16 + g * 8];
        short8 b0h = *(const short8*)(wp0 + kc * 1024);
        short8 b0l = *(const short8*)(wp0 + kc * 1024 + 512);
        short8 b1h = *(const short8*)(wp1 + kc * 1024);
        short8 b1l = *(const short8*)(wp1 + kc * 1024 + 512);
        acc0 = __builtin_amdgcn_mfma_f32_32x32x16_bf16(ah, b0h, acc0, 0, 0, 0);
        acc1 = __builtin_amdgcn_mfma_f32_32x32x16_bf16(ah, b1h, acc1, 0, 0, 0);
        acc0 = __builtin_amdgcn_mfma_f32_32x32x16_bf16(al, b0h, acc0, 0, 0, 0);
        acc1 = __builtin_amdgcn_mfma_f32_32x32x16_bf16(al, b1h, acc1, 0, 0, 0);
        acc0 = __builtin_amdgcn_mfma_f32_32x32x16_bf16(ah, b0l, acc0, 0, 0, 0);
        acc1 = __builtin_amdgcn_mfma_f32_32x32x16_bf16(ah, b1l, acc1, 0, 0, 0);
    }
    #pragma unroll
    for (int t = 0; t < KCX; t++) {
        const int kc = KCH + t;
        short8 b0h = *(const short8*)(wp0 + kc * 1024);
        short8 b0l = *(const short8*)(wp0 + kc * 1024 + 512);
        short8 b1h = *(const short8*)(wp1 + kc * 1024);
        short8 b1l = *(const short8*)(wp1 + kc * 1024 + 512);
        acc0 = __builtin_amdgcn_mfma_f32_32x32x16_bf16(xh[t], b0h, acc0, 0, 0, 0);
        acc1 = __builtin_amdgcn_mfma_f32_32x32x16_bf16(xh[t], b1h, acc1, 0, 0, 0);
        acc0 = __builtin_amdgcn_mfma_f32_32x32x16_bf16(xl[t], b0h, acc0, 0, 0, 0);
        acc1 = __builtin_amdgcn_mfma_f32_32x32x16_bf16(xl[t], b1h, acc1, 0, 0, 0);
        acc0 = __builtin_amdgcn_mfma_f32_32x32x16_bf16(xh[t], b0l, acc0, 0, 0, 0);
        acc1 = __builtin_amdgcn_mfma_f32_32x32x16_bf16(xh[t], b1l, acc1, 0, 0, 0);
    }
    const float bv0 = bias[ct0 * 32 + r31];
    const float bv1 = bias[ct0 * 32 + 32 + r31];
    if (OUTMODE == 0) {
        __syncthreads();
        #pragma unroll
        for (int r = 0; r < 16; r++) {
            int row = (r & 3) + 8 * (r >> 2) + 4 * g;
            float v0 = fmaxf(acc0[r] + bv0, 0.f);
            float v1 = fmaxf(acc1[r] + bv1, 0.f);
            unsigned short h0 = bf16rne(v0), h1 = bf16rne(v1);
            Hh[row][ct0 * 32 + r31] = h0;
            Hl[row][ct0 * 32 + r31] = bf16rne(v0 - bf2f(h0));
            Hh[row][ct0 * 32 + 32 + r31] = h1;
            Hl[row][ct0 * 32 + 32 + r31] = bf16rne(v1 - bf2f(h1));
        }
        __syncthreads();
    } else {
        #pragma unroll
        for (int r = 0; r < 16; r++) {
            int row = (r & 3) + 8 * (r >> 2) + 4 * g;
            gout[(size_t)(rowbase + row) * 256 + ct0 * 32 + r31] = acc0[r] + bv0;
            gout[(size_t)(rowbase + row) * 256 + ct0 * 32 + 32 + r31] = acc1[r] + bv1;
        }
    }
}

__global__ __launch_bounds__(256, 4) void k_trunk_mfma(const float* __restrict__ x,
    const unsigned short* __restrict__ wfrag,
    const float* __restrict__ b0, const float* __restrict__ bmid,
    const float* __restrict__ bskip, const float* __restrict__ bfin,
    const float* __restrict__ wsig, const float* __restrict__ bsig,
    float* __restrict__ feat, float* __restrict__ out)
{
    __shared__ unsigned short Hh[32][264];
    __shared__ unsigned short Hl[32][264];
    const int lane = threadIdx.x & 63;
    const int wave = threadIdx.x >> 6;
    const int rowbase = blockIdx.x * 32;
    const unsigned short* W = wfrag;
    mlayer<0, 4, 0>(Hh, Hl, rowbase, x, W + (size_t)0   * 8192, b0,          nullptr, lane, wave);
    mlayer<16,0, 0>(Hh, Hl, rowbase, x, W + (size_t)4   * 8192, bmid + 0,    nullptr, lane, wave);
    mlayer<16,0, 0>(Hh, Hl, rowbase, x, W + (size_t)20  * 8192, bmid + 256,  nullptr, lane, wave);
    mlayer<16,0, 0>(Hh, Hl, rowbase, x, W + (size_t)36  * 8192, bmid + 512,  nullptr, lane, wave);
    mlayer<16,4, 0>(Hh, Hl, rowbase, x, W + (size_t)52  * 8192, bskip,       nullptr, lane, wave);
    mlayer<16,0, 0>(Hh, Hl, rowbase, x, W + (size_t)72  * 8192, bmid + 768,  nullptr, lane, wave);
    mlayer<16,0, 0>(Hh, Hl, rowbase, x, W + (size_t)88  * 8192, bmid + 1024, nullptr, lane, wave);
    mlayer<16,0, 0>(Hh, Hl, rowbase, x, W + (size_t)104 * 8192, bmid + 1280, nullptr, lane, wave);
    mlayer<16,0, 1>(Hh, Hl, rowbase, x, W + (size_t)120 * 8192, bfin,        feat,    lane, wave);
    if (wave == 0) {
        const int r31 = lane & 31, g = lane >> 5;
        float s = 0.f;
        #pragma unroll
        for (int kk = 0; kk < 32; kk++) {
            short4v hh = *(const short4v*)&Hh[r31][g * 128 + kk * 4];
            short4v hl = *(const short4v*)&Hl[r31][g * 128 + kk * 4];
            float4 wv = *(const float4*)&wsig[g * 128 + kk * 4];
            s = fmaf(bf2f((unsigned short)hh[0]) + bf2f((unsigned short)hl[0]), wv.x, s);
            s = fmaf(bf2f((unsigned short)hh[1]) + bf2f((unsigned short)hl[1]), wv.y, s);
            s = fmaf(bf2f((unsigned short)hh[2]) + bf2f((unsigned short)hl[2]), wv.z, s);
            s = fmaf(bf2f((unsigned short)hh[3]) + bf2f((unsigned short)hl[3]), wv.w, s);
        }
        s += __shfl_xor(s, 32);
        if (lane < 32) out[(size_t)(rowbase + r31) * 4 + 3] = s + bsig[0];
    }
}

// ---------------- helpers for fp32 tile GEMMs (pq/edge) ----------------
__device__ __forceinline__ void fma88(float acc[8][8], float4 a0, float4 a1,
                                      float4 b0, float4 b1)
{
    float av[8] = {a0.x,a0.y,a0.z,a0.w,a1.x,a1.y,a1.z,a1.w};
    float bv[8] = {b0.x,b0.y,b0.z,b0.w,b1.x,b1.y,b1.z,b1.w};
    #pragma unroll
    for (int i = 0; i < 8; i++)
        #pragma unroll
        for (int j = 0; j < 8; j++)
            acc[i][j] = fmaf(av[i], bv[j], acc[i][j]);
}

__device__ __forceinline__ void stage_wpq(const float* __restrict__ ew1, int k0, int K,
                                          float4 st[4], int tid)
{
    #pragma unroll
    for (int u = 0; u < 4; u++) {
        int f = tid + (u << 8);
        int kk = f >> 6, c4 = (f & 63) << 2;
        int k = k0 + kk;
        if (k >= K) st[u] = make_float4(0.f, 0.f, 0.f, 0.f);
        else st[u] = (c4 < 128) ? *(const float4*)&ew1[(size_t)k * 128 + c4]
                                : *(const float4*)&ew1[(size_t)(K + k) * 128 + (c4 - 128)];
    }
}

__device__ __forceinline__ void stage_write(float (*buf)[256], const float4 st[4], int tid)
{
    #pragma unroll
    for (int u = 0; u < 4; u++) {
        int f = tid + (u << 8);
        int kk = f >> 6, c4 = (f & 63) << 2;
        *(float4*)&buf[kk][c4] = st[u];
    }
}

// ---------------- PQ GEMMs for edge convs ----------------
__global__ __launch_bounds__(256) void k_pq1(const float* __restrict__ feat,
    const float* __restrict__ x, const float* __restrict__ ew1,
    float* __restrict__ PQ)
{
    __shared__ float aT[288][HPAD];
    __shared__ float wbuf[2][16][256];
    const int tid = threadIdx.x;
    const int tx = tid & 31, ty = tid >> 5;
    const int cLo = tx * 4, cHi = 128 + tx * 4, r0 = ty * 8;
    const int row0 = blockIdx.x * 64;
    const int K = 283;
    for (int s = tid; s < 64 * 256; s += 256) {
        int r = s >> 8, k = s & 255;
        aT[k][r] = feat[(size_t)(row0 + r) * 256 + k];
    }
    for (int s = tid; s < 32 * 64; s += 256) {
        int dd = s >> 6, r = s & 63;
        aT[256 + dd][r] = (dd < 27) ? x[(size_t)(row0 + r) * 90 + 63 + dd] : 0.f;
    }
    float4 st[4];
    stage_wpq(ew1, 0, K, st, tid);
    __syncthreads();
    stage_write(wbuf[0], st, tid);
    __syncthreads();

    float acc[8][8];
    #pragma unroll
    for (int i = 0; i < 8; i++)
        #pragma unroll
        for (int j = 0; j < 8; j++) acc[i][j] = 0.f;

    const int nch = (K + 15) >> 4;
    for (int c = 0; c < nch; c++) {
        const int cur = c & 1;
        const bool more = (c + 1 < nch);
        if (more) stage_wpq(ew1, (c + 1) << 4, K, st, tid);
        const float (*wb)[256] = wbuf[cur];
        const int kbase = c << 4;
        #pragma unroll
        for (int kk = 0; kk < 16; kk++) {
            const int k = kbase + kk;
            float4 a0 = *(const float4*)&aT[k][r0];
            float4 a1 = *(const float4*)&aT[k][r0 + 4];
            float4 b0 = *(const float4*)&wb[kk][cLo];
            float4 b1 = *(const float4*)&wb[kk][cHi];
            fma88(acc, a0, a1, b0, b1);
        }
        if (more) stage_write(wbuf[cur ^ 1], st, tid);
        __syncthreads();
    }
    #pragma unroll
    for (int i = 0; i < 8; i++) {
        *(float4*)&PQ[(size_t)(row0 + r0 + i) * 256 + cLo] =
            make_float4(acc[i][0], acc[i][1], acc[i][2], acc[i][3]);
        *(float4*)&PQ[(size_t)(row0 + r0 + i) * 256 + cHi] =
            make_float4(acc[i][4], acc[i][5], acc[i][6], acc[i][7]);
    }
}

__global__ __launch_bounds__(256) void k_pq2(const float* __restrict__ d1,
    const float* __restrict__ ew1, float* __restrict__ PQ)
{
    __shared__ float aT[128][HPAD];
    __shared__ float wbuf[2][16][256];
    const int tid = threadIdx.x;
    const int tx = tid & 31, ty = tid >> 5;
    const int cLo = tx * 4, cHi = 128 + tx * 4, r0 = ty * 8;
    const int row0 = blockIdx.x * 64;
    const int K = 128;
    for (int s = tid; s < 64 * 128; s += 256) {
        int r = s >> 7, k = s & 127;
        aT[k][r] = d1[(size_t)(row0 + r) * 128 + k];
    }
    float4 st[4];
    stage_wpq(ew1, 0, K, st, tid);
    __syncthreads();
    stage_write(wbuf[0], st, tid);
    __syncthreads();

    float acc[8][8];
    #pragma unroll
    for (int i = 0; i < 8; i++)
        #pragma unroll
        for (int j = 0; j < 8; j++) acc[i][j] = 0.f;

    for (int c = 0; c < 8; c++) {
        const int cur = c & 1;
        const bool more = (c < 7);
        if (more) stage_wpq(ew1, (c + 1) << 4, K, st, tid);
        const float (*wb)[256] = wbuf[cur];
        const int kbase = c << 4;
        #pragma unroll
        for (int kk = 0; kk < 16; kk++) {
            const int k = kbase + kk;
            float4 a0 = *(const float4*)&aT[k][r0];
            float4 a1 = *(const float4*)&aT[k][r0 + 4];
            float4 b0 = *(const float4*)&wb[kk][cLo];
            float4 b1 = *(const float4*)&wb[kk][cHi];
            fma88(acc, a0, a1, b0, b1);
        }
        if (more) stage_write(wbuf[cur ^ 1], st, tid);
        __syncthreads();
    }
    #pragma unroll
    for (int i = 0; i < 8; i++) {
        *(float4*)&PQ[(size_t)(row0 + r0 + i) * 256 + cLo] =
            make_float4(acc[i][0], acc[i][1], acc[i][2], acc[i][3]);
        *(float4*)&PQ[(size_t)(row0 + r0 + i) * 256 + cHi] =
            make_float4(acc[i][4], acc[i][5], acc[i][6], acc[i][7]);
    }
}

// ---------------- edge conv ----------------
template<int RGB>
__global__ __launch_bounds__(256) void k_edge(const float* __restrict__ PQ,
    const float* __restrict__ b1, const float* __restrict__ w2,
    const float* __restrict__ b2, const int* __restrict__ nbr,
    float* __restrict__ dout,
    const float* __restrict__ wrgb, const float* __restrict__ brgb,
    float* __restrict__ out)
{
    __shared__ float h1T[128][97];
    __shared__ float wb[32][128];
    const int tid = threadIdx.x;
    const int n0 = blockIdx.x * 32;
    {
        const int c = tid & 127, eg = tid >> 7;
        const float bias = b1[c];
        for (int e = eg; e < 96; e += 2) {
            int n = e / 3;
            int jj = e - n * 3;
            int i = n0 + n;
            int j = nbr[(size_t)i * 3 + jj];
            float v = PQ[(size_t)i * 256 + c] + bias
                    + PQ[(size_t)j * 256 + 128 + c] - PQ[(size_t)i * 256 + 128 + c];
            h1T[c][e] = fmaxf(v, 0.f);
        }
    }
    const int cg = tid & 15, rg = tid >> 4;
    const int cLo = cg * 4, cHi = 64 + cg * 4, e0 = rg * 6;
    float acc[6][8];
    #pragma unroll
    for (int m = 0; m < 6; m++)
        #pragma unroll
        for (int j = 0; j < 8; j++) acc[m][j] = 0.f;
    for (int k0 = 0; k0 < 128; k0 += 32) {
        __syncthreads();
        for (int s = tid; s < 32 * 128; s += 256) {
            int kk = s >> 7, c = s & 127;
            wb[kk][c] = w2[(size_t)(k0 + kk) * 128 + c];
        }
        __syncthreads();
        for (int kk = 0; kk < 32; kk++) {
            const int k = k0 + kk;
            float av[6];
            #pragma unroll
            for (int m = 0; m < 6; m++) av[m] = h1T[k][e0 + m];
            float4 w0v = *(const float4*)&wb[kk][cLo];
            float4 w1v = *(const float4*)&wb[kk][cHi];
            float bv[8] = {w0v.x,w0v.y,w0v.z,w0v.w,w1v.x,w1v.y,w1v.z,w1v.w};
            #pragma unroll
            for (int m = 0; m < 6; m++)
                #pragma unroll
                for (int j = 0; j < 8; j++)
                    acc[m][j] = fmaf(av[m], bv[j], acc[m][j]);
        }
    }
    float bb[8];
    #pragma unroll
    for (int j = 0; j < 8; j++) bb[j] = b2[(j < 4) ? (cLo + j) : (cHi + j - 4)];
    float dA[8], dB[8];
    #pragma unroll
    for (int j = 0; j < 8; j++) {
        float h0 = fmaxf(acc[0][j] + bb[j], 0.f);
        float h1 = fmaxf(acc[1][j] + bb[j], 0.f);
        float h2 = fmaxf(acc[2][j] + bb[j], 0.f);
        float h3 = fmaxf(acc[3][j] + bb[j], 0.f);
        float h4 = fmaxf(acc[4][j] + bb[j], 0.f);
        float h5 = fmaxf(acc[5][j] + bb[j], 0.f);
        dA[j] = (h0 + h1 + h2) * (1.f / 3.f);
        dB[j] = (h3 + h4 + h5) * (1.f / 3.f);
    }
    if (!RGB) {
        *(float4*)&dout[(size_t)(n0 + 2*rg) * 128 + cLo] = make_float4(dA[0], dA[1], dA[2], dA[3]);
        *(float4*)&dout[(size_t)(n0 + 2*rg) * 128 + cHi] = make_float4(dA[4], dA[5], dA[6], dA[7]);
        *(float4*)&dout[(size_t)(n0 + 2*rg + 1) * 128 + cLo] = make_float4(dB[0], dB[1], dB[2], dB[3]);
        *(float4*)&dout[(size_t)(n0 + 2*rg + 1) * 128 + cHi] = make_float4(dB[4], dB[5], dB[6], dB[7]);
    } else {
        __syncthreads();
        float* d2L = &h1T[0][0];
        #pragma unroll
        for (int j = 0; j < 4; j++) {
            d2L[(2*rg)     * 130 + cLo + j] = dA[j];
            d2L[(2*rg)     * 130 + cHi + j] = dA[j + 4];
            d2L[(2*rg + 1) * 130 + cLo + j] = dB[j];
            d2L[(2*rg + 1) * 130 + cHi + j] = dB[j + 4];
        }
        __syncthreads();
        if (tid < 96) {
            int n = tid / 3, ch = tid - 3 * (tid / 3);
            float s = brgb[ch];
            for (int k = 0; k < 128; k++) s = fmaf(d2L[n * 130 + k], wrgb[k * 3 + ch], s);
            out[(size_t)(n0 + n) * 4 + ch] = 1.f / (1.f + expf(-s));
        }
    }
}

// ---------------- launch ----------------
extern "C" void kernel_launch(void* const* d_in, const int* in_sizes, int n_in,
                              void* d_out, int out_size, void* d_ws, size_t ws_size,
                              hipStream_t stream)
{
    const float* x     = (const float*)d_in[0];
    const int*   bid   = (const int*)d_in[1];
    const float* w0    = (const float*)d_in[2];
    const float* b0    = (const float*)d_in[3];
    const float* wmid  = (const float*)d_in[4];
    const float* bmid  = (const float*)d_in[5];
    const float* wskip = (const float*)d_in[6];
    const float* bskip = (const float*)d_in[7];
    const float* wfin  = (const float*)d_in[8];
    const float* bfin  = (const float*)d_in[9];
    const float* wsig  = (const float*)d_in[10];
    const float* bsig  = (const float*)d_in[11];
    const float* e1w1  = (const float*)d_in[12];
    const float* e1b1  = (const float*)d_in[13];
    const float* e1w2  = (const float*)d_in[14];
    const float* e1b2  = (const float*)d_in[15];
    const float* e2w1  = (const float*)d_in[16];
    const float* e2b1  = (const float*)d_in[17];
    const float* e2w2  = (const float*)d_in[18];
    const float* e2b2  = (const float*)d_in[19];
    const float* wrgb  = (const float*)d_in[20];
    const float* brgb  = (const float*)d_in[21];
    float* out = (float*)d_out;

    char* ws = (char*)d_ws;
    int* cnt = (int*)ws;
    int* grp = (int*)(ws + 256);
    int* nbr = (int*)(ws + 256 + NGRP * GSZ * 4);
    float* bufA = (float*)(ws + (1 << 20));                // 41.9 MB
    float* bufB = bufA + (size_t)B_TOTAL * 256;            // 41.9 MB

    unsigned short* xbh = (unsigned short*)bufA;
    unsigned short* xbl = xbh + (size_t)B_TOTAL * 64;
    float* cn   = (float*)(xbl + (size_t)B_TOTAL * 64);
    unsigned long long* pkey = (unsigned long long*)(cn + B_TOTAL);  // 40960*12 u64 = 3.9MB
    unsigned short* wfrag = (unsigned short*)((char*)bufB + ((size_t)39 << 20));

    hipMemsetAsync(cnt, 0, 256, stream);
    k_scatter<<<B_TOTAL / 256, 256, 0, stream>>>(bid, grp, cnt);
    k_wprep<<<(557056 + 255) / 256, 256, 0, stream>>>(w0, wmid, wskip, wfin, wfrag);
    k_gather<<<dim3(GSZ / 128, NGRP), 256, 0, stream>>>(x, grp, xbh, xbl, cn);
    k_knn_mfma<<<dim3(GSZ / 64, CPART, NGRP), 256, 0, stream>>>(xbh, xbl, cn, pkey);
    k_knn_merge<<<(NGRP * GSZ + 255) / 256, 256, 0, stream>>>(pkey, grp, nbr);
    k_trunk_mfma<<<B_TOTAL / 32, 256, 0, stream>>>(x, wfrag, b0, bmid, bskip, bfin,
                                                   wsig, bsig, bufA, out);
    k_pq1<<<B_TOTAL / 64, 256, 0, stream>>>(bufA, x, e1w1, bufB);
    k_edge<0><<<B_TOTAL / 32, 256, 0, stream>>>(bufB, e1b1, e1w2, e1b2, nbr, bufA,
                                                nullptr, nullptr, nullptr);
    k_pq2<<<B_TOTAL / 64, 256, 0, stream>>>(bufA, e2w1, bufB);
    k_edge<1><<<B_TOTAL / 32, 256, 0, stream>>>(bufB, e2b1, e2w2, e2b2, nbr, nullptr,
                                                wrgb, brgb, out);
}

// Round 10
// 628.744 us; speedup vs baseline: 1.9780x; 1.1922x over previous
//
#include <hip/hip_runtime.h>
#include <hip/hip_bf16.h>
#include <math.h>

#define B_TOTAL 40960
#define NGRP 20
#define GSZ 2048
#define CPART 4

typedef short short8 __attribute__((ext_vector_type(8)));
typedef short short4v __attribute__((ext_vector_type(4)));
typedef float f32x4 __attribute__((ext_vector_type(4)));
typedef float f32x16 __attribute__((ext_vector_type(16)));

// ---------------- group scatter ----------------
__global__ void k_scatter(const int* __restrict__ bid, int* __restrict__ grp,
                          int* __restrict__ cnt)
{
    int i = blockIdx.x * 256 + threadIdx.x;
    if (i < B_TOTAL) {
        int g = bid[i];
        int p = atomicAdd(&cnt[g], 1);
        grp[g * GSZ + p] = i;
    }
}

// ---------------- bf16 helpers ----------------
__device__ __forceinline__ unsigned short bf16rne(float v)
{
    unsigned int u = __float_as_uint(v);
    unsigned int r = (u + 0x7FFFu + ((u >> 16) & 1u)) >> 16;
    return (unsigned short)r;
}

__device__ __forceinline__ float bf2f(unsigned short h)
{
    return __uint_as_float((unsigned int)h << 16);
}

__device__ __forceinline__ void splitbf16(const float* v, short8& hi, short8& lo)
{
    #pragma unroll
    for (int j = 0; j < 8; j++) {
        unsigned short h = bf16rne(v[j]);
        hi[j] = (short)h;
        lo[j] = (short)bf16rne(v[j] - bf2f(h));
    }
}

// ordered-float key: monotonic unsigned encoding of float
__device__ __forceinline__ unsigned int fkey(float f)
{
    unsigned int u = __float_as_uint(f);
    unsigned int m = (unsigned int)((int)u >> 31) | 0x80000000u;
    return u ^ m;
}

// branch-free sorted insert of (k,i) into ((k0,i0) <= (k1,i1) <= (k2,i2))
__device__ __forceinline__ void ins3p(unsigned int k, unsigned int i,
    unsigned int& k0, unsigned int& i0, unsigned int& k1, unsigned int& i1,
    unsigned int& k2, unsigned int& i2)
{
    bool c0 = k < k0;
    unsigned int tk = c0 ? k0 : k, ti = c0 ? i0 : i;
    k0 = c0 ? k : k0;  i0 = c0 ? i : i0;
    bool c1 = tk < k1;
    unsigned int sk = c1 ? k1 : tk, si = c1 ? i1 : ti;
    k1 = c1 ? tk : k1; i1 = c1 ? ti : i1;
    bool c2 = sk < k2;
    k2 = c2 ? sk : k2; i2 = c2 ? si : i2;
}

__device__ __forceinline__ void mergerow(unsigned int& k0, unsigned int& i0,
    unsigned int& k1, unsigned int& i1, unsigned int& k2, unsigned int& i2)
{
    #pragma unroll
    for (int m = 1; m <= 8; m <<= 1) {
        unsigned int ok0 = (unsigned int)__shfl_xor((int)k0, m);
        unsigned int oi0 = (unsigned int)__shfl_xor((int)i0, m);
        unsigned int ok1 = (unsigned int)__shfl_xor((int)k1, m);
        unsigned int oi1 = (unsigned int)__shfl_xor((int)i1, m);
        unsigned int ok2 = (unsigned int)__shfl_xor((int)k2, m);
        unsigned int oi2 = (unsigned int)__shfl_xor((int)i2, m);
        ins3p(ok0, oi0, k0, i0, k1, i1, k2, i2);
        ins3p(ok1, oi1, k0, i0, k1, i1, k2, i2);
        ins3p(ok2, oi2, k0, i0, k1, i1, k2, i2);
    }
}

// ---------------- kNN stage 1: gather -> packed bf16 hi/lo planes + norms ----------------
__global__ __launch_bounds__(256) void k_gather(const float* __restrict__ x,
    const int* __restrict__ grp, unsigned short* __restrict__ xbh,
    unsigned short* __restrict__ xbl, float* __restrict__ cn)
{
    __shared__ float tile[128][65];
    __shared__ int ids[128];
    const int tid = threadIdx.x;
    const int g = blockIdx.y;
    const int q0 = blockIdx.x * 128;
    if (tid < 128) ids[tid] = grp[g * GSZ + q0 + tid];
    __syncthreads();
    for (int s = tid; s < 128 * 64; s += 256) {
        int q = s >> 6, d = s & 63;
        tile[q][d] = (d < 63) ? x[(size_t)ids[q] * 90 + d] : 0.f;
    }
    __syncthreads();
    if (tid < 128) {
        float a = 0.f;
        #pragma unroll
        for (int d = 0; d < 63; d++) a = fmaf(tile[tid][d], tile[tid][d], a);
        cn[g * GSZ + q0 + tid] = a;
    }
    for (int s = tid; s < 128 * 32; s += 256) {
        int q = s >> 5, dp = (s & 31) << 1;
        float v0 = tile[q][dp], v1 = tile[q][dp + 1];
        unsigned short h0 = bf16rne(v0), h1 = bf16rne(v1);
        unsigned short l0 = bf16rne(v0 - bf2f(h0)), l1 = bf16rne(v1 - bf2f(h1));
        size_t pt = (size_t)g * GSZ + q0 + q;
        ((unsigned int*)xbh)[pt * 32 + (dp >> 1)] = (unsigned int)h0 | ((unsigned int)h1 << 16);
        ((unsigned int*)xbl)[pt * 32 + (dp >> 1)] = (unsigned int)l0 | ((unsigned int)l1 << 16);
    }
}

// ---------------- kNN stage 2: MFMA distance tiles, LDS-shared stream, branch-free top3 ----------------
__global__ __launch_bounds__(256) void k_knn_mfma(const unsigned short* __restrict__ xbh,
    const unsigned short* __restrict__ xbl, const float* __restrict__ cn,
    unsigned long long* __restrict__ pkey)
{
    __shared__ char cbuf[2][16384];
    const int tid = threadIdx.x;
    const int lane = tid & 63;
    const int wave = tid >> 6;
    const int g = blockIdx.z;
    const int part = blockIdx.y;
    const int qt0 = blockIdx.x * 64 + wave * 16;
    const size_t gbase = (size_t)g * GSZ;
    const int lp = lane & 15;
    const int kgrp = lane >> 4;
    const int kg = kgrp << 3;

    const size_t qb = (gbase + qt0 + lp) * 64;
    short8 ah0 = *(const short8*)(xbh + qb + kg);
    short8 ah1 = *(const short8*)(xbh + qb + 32 + kg);
    short8 al0 = *(const short8*)(xbl + qb + kg);
    short8 al1 = *(const short8*)(xbl + qb + 32 + kg);

    const int qp0 = qt0 + (kgrp << 2);   // query row of acc[r] is qp0 + r

    unsigned int K00 = ~0u, I00 = 0, K01 = ~0u, I01 = 0, K02 = ~0u, I02 = 0;
    unsigned int K10 = ~0u, I10 = 0, K11 = ~0u, I11 = 0, K12 = ~0u, I12 = 0;
    unsigned int K20 = ~0u, I20 = 0, K21 = ~0u, I21 = 0, K22 = ~0u, I22 = 0;
    unsigned int K30 = ~0u, I30 = 0, K31 = ~0u, I31 = 0, K32 = ~0u, I32 = 0;

    const int scand = tid & 63;
    const int cbeg = part * (GSZ / CPART);
    const int s0 = wave, s1 = 4 + wave, s2 = 8 + wave, s3 = 12 + wave;
    const unsigned short* pl0 = (s0 < 8) ? xbh : xbl;
    const unsigned short* pl1 = (s1 < 8) ? xbh : xbl;
    const unsigned short* pl2 = (s2 < 8) ? xbh : xbl;
    const unsigned short* pl3 = (s3 < 8) ? xbh : xbl;

    short8 st0, st1, st2, st3;
    {
        size_t cb = (gbase + cbeg + scand) * 64;
        st0 = *(const short8*)(pl0 + cb + (s0 & 7) * 8);
        st1 = *(const short8*)(pl1 + cb + (s1 & 7) * 8);
        st2 = *(const short8*)(pl2 + cb + (s2 & 7) * 8);
        st3 = *(const short8*)(pl3 + cb + (s3 & 7) * 8);
    }
    *(short8*)&cbuf[0][(s0 << 10) + (scand << 4)] = st0;
    *(short8*)&cbuf[0][(s1 << 10) + (scand << 4)] = st1;
    *(short8*)&cbuf[0][(s2 << 10) + (scand << 4)] = st2;
    *(short8*)&cbuf[0][(s3 << 10) + (scand << 4)] = st3;

    for (int ch = 0; ch < 8; ch++) {
        const int cur = ch & 1;
        __syncthreads();                   // cbuf[cur] ready for all waves
        if (ch < 7) {                      // issue next chunk's loads early
            size_t cb = (gbase + cbeg + (ch + 1) * 64 + scand) * 64;
            st0 = *(const short8*)(pl0 + cb + (s0 & 7) * 8);
            st1 = *(const short8*)(pl1 + cb + (s1 & 7) * 8);
            st2 = *(const short8*)(pl2 + cb + (s2 & 7) * 8);
            st3 = *(const short8*)(pl3 + cb + (s3 & 7) * 8);
        }
        const int cc0 = cbeg + ch * 64;
        #pragma unroll
        for (int ct = 0; ct < 4; ct++) {
            const int coff = ((ct * 16 + lp) << 4);
            short8 bh0 = *(const short8*)&cbuf[cur][((kgrp)      << 10) + coff];
            short8 bh1 = *(const short8*)&cbuf[cur][((4 + kgrp)  << 10) + coff];
            short8 bl0 = *(const short8*)&cbuf[cur][((8 + kgrp)  << 10) + coff];
            short8 bl1 = *(const short8*)&cbuf[cur][((12 + kgrp) << 10) + coff];
            f32x4 acc = {0.f, 0.f, 0.f, 0.f};
            acc = __builtin_amdgcn_mfma_f32_16x16x32_bf16(ah0, bh0, acc, 0, 0, 0);
            acc = __builtin_amdgcn_mfma_f32_16x16x32_bf16(ah1, bh1, acc, 0, 0, 0);
            acc = __builtin_amdgcn_mfma_f32_16x16x32_bf16(al0, bh0, acc, 0, 0, 0);
            acc = __builtin_amdgcn_mfma_f32_16x16x32_bf16(al1, bh1, acc, 0, 0, 0);
            acc = __builtin_amdgcn_mfma_f32_16x16x32_bf16(ah0, bl0, acc, 0, 0, 0);
            acc = __builtin_amdgcn_mfma_f32_16x16x32_bf16(ah1, bl1, acc, 0, 0, 0);
            const float cnv = cn[gbase + cc0 + ct * 16 + lp];
            const int cpos = cc0 + ct * 16 + lp;
            const unsigned int ci = (unsigned int)cpos;
            {
                unsigned int k = fkey(fmaf(-2.f, acc[0], cnv));
                k = (cpos == qp0 + 0) ? 0xFFFFFFFFu : k;
                ins3p(k, ci, K00, I00, K01, I01, K02, I02);
            }
            {
                unsigned int k = fkey(fmaf(-2.f, acc[1], cnv));
                k = (cpos == qp0 + 1) ? 0xFFFFFFFFu : k;
                ins3p(k, ci, K10, I10, K11, I11, K12, I12);
            }
            {
                unsigned int k = fkey(fmaf(-2.f, acc[2], cnv));
                k = (cpos == qp0 + 2) ? 0xFFFFFFFFu : k;
                ins3p(k, ci, K20, I20, K21, I21, K22, I22);
            }
            {
                unsigned int k = fkey(fmaf(-2.f, acc[3], cnv));
                k = (cpos == qp0 + 3) ? 0xFFFFFFFFu : k;
                ins3p(k, ci, K30, I30, K31, I31, K32, I32);
            }
        }
        if (ch < 7) {
            *(short8*)&cbuf[cur ^ 1][(s0 << 10) + (scand << 4)] = st0;
            *(short8*)&cbuf[cur ^ 1][(s1 << 10) + (scand << 4)] = st1;
            *(short8*)&cbuf[cur ^ 1][(s2 << 10) + (scand << 4)] = st2;
            *(short8*)&cbuf[cur ^ 1][(s3 << 10) + (scand << 4)] = st3;
        }
    }

    mergerow(K00, I00, K01, I01, K02, I02);
    mergerow(K10, I10, K11, I11, K12, I12);
    mergerow(K20, I20, K21, I21, K22, I22);
    mergerow(K30, I30, K31, I31, K32, I32);

    if (lp == 0) {
        size_t ob = (gbase + (size_t)qp0) * (CPART * 3) + part * 3;
        pkey[ob + 0]  = ((unsigned long long)K00 << 32) | I00;
        pkey[ob + 1]  = ((unsigned long long)K01 << 32) | I01;
        pkey[ob + 2]  = ((unsigned long long)K02 << 32) | I02;
        pkey[ob + 12] = ((unsigned long long)K10 << 32) | I10;
        pkey[ob + 13] = ((unsigned long long)K11 << 32) | I11;
        pkey[ob + 14] = ((unsigned long long)K12 << 32) | I12;
        pkey[ob + 24] = ((unsigned long long)K20 << 32) | I20;
        pkey[ob + 25] = ((unsigned long long)K21 << 32) | I21;
        pkey[ob + 26] = ((unsigned long long)K22 << 32) | I22;
        pkey[ob + 36] = ((unsigned long long)K30 << 32) | I30;
        pkey[ob + 37] = ((unsigned long long)K31 << 32) | I31;
        pkey[ob + 38] = ((unsigned long long)K32 << 32) | I32;
    }
}

// ---------------- kNN stage 3: merge CPART partials from u64 keys ----------------
__device__ __forceinline__ void ins3u(unsigned long long k,
    unsigned long long& k0, unsigned long long& k1, unsigned long long& k2)
{
    if (k < k0)      { k2 = k1; k1 = k0; k0 = k; }
    else if (k < k1) { k2 = k1; k1 = k; }
    else if (k < k2) { k2 = k; }
}

__global__ void k_knn_merge(const unsigned long long* __restrict__ pkey,
                            const int* __restrict__ grp, int* __restrict__ nbr)
{
    int t = blockIdx.x * 256 + threadIdx.x;
    if (t >= NGRP * GSZ) return;
    int g = t >> 11;
    unsigned long long k0 = ~0ull, k1 = ~0ull, k2 = ~0ull;
    const unsigned long long* pk = pkey + (size_t)t * (CPART * 3);
    #pragma unroll
    for (int r = 0; r < CPART * 3; r++) ins3u(pk[r], k0, k1, k2);
    int qi = grp[t];
    nbr[(size_t)qi * 3 + 0] = grp[(g << 11) + (int)(k0 & 0xFFFFFFFFull)];
    nbr[(size_t)qi * 3 + 1] = grp[(g << 11) + (int)(k1 & 0xFFFFFFFFull)];
    nbr[(size_t)qi * 3 + 2] = grp[(g << 11) + (int)(k2 & 0xFFFFFFFFull)];
}

// ---------------- trunk weight prep: split-bf16, fragment-major ----------------
__global__ void k_wprep(const float* __restrict__ w0, const float* __restrict__ wmid,
                        const float* __restrict__ wskip, const float* __restrict__ wfin,
                        unsigned short* __restrict__ wfrag)
{
    int t = blockIdx.x * 256 + threadIdx.x;
    if (t >= 557056) return;
    const int CUMa[10] = {0,4,20,36,52,72,88,104,120,136};
    const int KCa[9]   = {4,16,16,16,20,16,16,16,16};
    int q = t >> 12;
    int L = 0;
    #pragma unroll
    for (int i = 0; i < 9; i++) if (q >= CUMa[i + 1]) L = i + 1;
    int cum = 0, kcn = 16;
    #pragma unroll
    for (int i = 0; i < 9; i++) if (L == i) { cum = CUMa[i]; kcn = KCa[i]; }
    int u = t - (cum << 12);
    int j = u & 7, lane = (u >> 3) & 63;
    int ckk = u >> 9;
    int kc = ckk % kcn, ct = ckk / kcn;
    int col = ct * 32 + (lane & 31);
    int k = kc * 16 + ((lane >> 5) << 3) + j;
    float w;
    if (L == 0)      w = (k < 63)  ? w0[k * 256 + col] : 0.f;
    else if (L == 4) w = (k < 256) ? wskip[(63 + k) * 256 + col]
                       : (k < 319) ? wskip[(k - 256) * 256 + col] : 0.f;
    else if (L == 8) w = wfin[k * 256 + col];
    else {
        int m = (L <= 3) ? (L - 1) : (L - 2);
        w = wmid[(size_t)m * 65536 + k * 256 + col];
    }
    unsigned short hi = bf16rne(w);
    unsigned short lo = bf16rne(w - bf2f(hi));
    size_t base = ((size_t)cum << 13) + (size_t)(ct * kcn + kc) * 1024 + lane * 8 + j;
    wfrag[base] = hi;
    wfrag[base + 512] = lo;
}

// ---------------- PQ weight prep: combined [K][256] (top|bottom), split-bf16 frag-major ----------------
__global__ void k_wprep_pq(const float* __restrict__ src, int K, int KCN,
                           unsigned short* __restrict__ dst)
{
    int t = blockIdx.x * 256 + threadIdx.x;
    if (t >= KCN * 8 * 512) return;
    int j = t & 7, lane = (t >> 3) & 63;
    int ckk = t >> 9;
    int kc = ckk % KCN, ct = ckk / KCN;
    int col = ct * 32 + (lane & 31);
    int k = kc * 16 + ((lane >> 5) << 3) + j;
    float w = 0.f;
    if (k < K) w = (col < 128) ? src[(size_t)k * 128 + col]
                               : src[(size_t)(K + k) * 128 + (col - 128)];
    unsigned short hi = bf16rne(w);
    unsigned short lo = bf16rne(w - bf2f(hi));
    size_t base = (size_t)(ct * KCN + kc) * 1024 + lane * 8 + j;
    dst[base] = hi;
    dst[base + 512] = lo;
}

// ---------------- fused trunk MLP: 4 waves share one 32-row tile, split-bf16 H in LDS ----------------
template<int KCH, int KCX, int OUTMODE>   // OUTMODE 0: relu->LDS H; 1: -> global bf16 planes
__device__ __forceinline__ void mlayer(unsigned short (*Hh)[264], unsigned short (*Hl)[264],
    int rowbase, const float* __restrict__ x, const unsigned short* __restrict__ wl,
    const float* __restrict__ bias, unsigned short* __restrict__ gh,
    unsigned short* __restrict__ gl, int lane, int wave)
{
    const int r31 = lane & 31, g = lane >> 5;
    constexpr int KC = KCH + KCX;
    short8 xh[KCX > 0 ? KCX : 1], xl[KCX > 0 ? KCX : 1];
    if (KCX > 0) {
        #pragma unroll
        for (int t = 0; t < KCX; t++) {
            float v[8];
            #pragma unroll
            for (int j = 0; j < 8; j++) {
                int kx = t * 16 + g * 8 + j;
                v[j] = (kx < 63) ? x[(size_t)(rowbase + r31) * 90 + kx] : 0.f;
            }
            splitbf16(v, xh[t], xl[t]);
        }
    }
    const int ct0 = wave * 2;
    f32x16 acc0, acc1;
    #pragma unroll
    for (int r = 0; r < 16; r++) { acc0[r] = 0.f; acc1[r] = 0.f; }
    const unsigned short* wp0 = wl + (size_t)ct0 * KC * 1024 + lane * 8;
    const unsigned short* wp1 = wp0 + (size_t)KC * 1024;
    #pragma unroll
    for (int kc = 0; kc < KCH; kc++) {
        short8 ah = *(const short8*)&Hh[r31][kc * 16 + g * 8];
        short8 al = *(const short8*)&Hl[r31][kc * 16 + g * 8];
        short8 b0h = *(const short8*)(wp0 + kc * 1024);
        short8 b0l = *(const short8*)(wp0 + kc * 1024 + 512);
        short8 b1h = *(const short8*)(wp1 + kc * 1024);
        short8 b1l = *(const short8*)(wp1 + kc * 1024 + 512);
        acc0 = __builtin_amdgcn_mfma_f32_32x32x16_bf16(ah, b0h, acc0, 0, 0, 0);
        acc1 = __builtin_amdgcn_mfma_f32_32x32x16_bf16(ah, b1h, acc1, 0, 0, 0);
        acc0 = __builtin_amdgcn_mfma_f32_32x32x16_bf16(al, b0h, acc0, 0, 0, 0);
        acc1 = __builtin_amdgcn_mfma_f32_32x32x16_bf16(al, b1h, acc1, 0, 0, 0);
        acc0 = __builtin_amdgcn_mfma_f32_32x32x16_bf16(ah, b0l, acc0, 0, 0, 0);
        acc1 = __builtin_amdgcn_mfma_f32_32x32x16_bf16(ah, b1l, acc1, 0, 0, 0);
    }
    #pragma unroll
    for (int t = 0; t < KCX; t++) {
        const int kc = KCH + t;
        short8 b0h = *(const short8*)(wp0 + kc * 1024);
        short8 b0l = *(const short8*)(wp0 + kc * 1024 + 512);
        short8 b1h = *(const short8*)(wp1 + kc * 1024);
        short8 b1l = *(const short8*)(wp1 + kc * 1024 + 512);
        acc0 = __builtin_amdgcn_mfma_f32_32x32x16_bf16(xh[t], b0h, acc0, 0, 0, 0);
        acc1 = __builtin_amdgcn_mfma_f32_32x32x16_bf16(xh[t], b1h, acc1, 0, 0, 0);
        acc0 = __builtin_amdgcn_mfma_f32_32x32x16_bf16(xl[t], b0h, acc0, 0, 0, 0);
        acc1 = __builtin_amdgcn_mfma_f32_32x32x16_bf16(xl[t], b1h, acc1, 0, 0, 0);
        acc0 = __builtin_amdgcn_mfma_f32_32x32x16_bf16(xh[t], b0l, acc0, 0, 0, 0);
        acc1 = __builtin_amdgcn_mfma_f32_32x32x16_bf16(xh[t], b1l, acc1, 0, 0, 0);
    }
    const float bv0 = bias[ct0 * 32 + r31];
    const float bv1 = bias[ct0 * 32 + 32 + r31];
    if (OUTMODE == 0) {
        __syncthreads();
        #pragma unroll
        for (int r = 0; r < 16; r++) {
            int row = (r & 3) + 8 * (r >> 2) + 4 * g;
            float v0 = fmaxf(acc0[r] + bv0, 0.f);
            float v1 = fmaxf(acc1[r] + bv1, 0.f);
            unsigned short h0 = bf16rne(v0), h1 = bf16rne(v1);
            Hh[row][ct0 * 32 + r31] = h0;
            Hl[row][ct0 * 32 + r31] = bf16rne(v0 - bf2f(h0));
            Hh[row][ct0 * 32 + 32 + r31] = h1;
            Hl[row][ct0 * 32 + 32 + r31] = bf16rne(v1 - bf2f(h1));
        }
        __syncthreads();
    } else {
        #pragma unroll
        for (int r = 0; r < 16; r++) {
            int row = (r & 3) + 8 * (r >> 2) + 4 * g;
            float v0 = acc0[r] + bv0;
            float v1 = acc1[r] + bv1;
            unsigned short h0 = bf16rne(v0), h1 = bf16rne(v1);
            size_t o0 = (size_t)(rowbase + row) * 256 + ct0 * 32 + r31;
            gh[o0] = h0;
            gl[o0] = bf16rne(v0 - bf2f(h0));
            gh[o0 + 32] = h1;
            gl[o0 + 32] = bf16rne(v1 - bf2f(h1));
        }
    }
}

__global__ __launch_bounds__(256, 4) void k_trunk_mfma(const float* __restrict__ x,
    const unsigned short* __restrict__ wfrag,
    const float* __restrict__ b0, const float* __restrict__ bmid,
    const float* __restrict__ bskip, const float* __restrict__ bfin,
    const float* __restrict__ wsig, const float* __restrict__ bsig,
    unsigned short* __restrict__ fphi, unsigned short* __restrict__ fplo,
    float* __restrict__ out)
{
    __shared__ unsigned short Hh[32][264];
    __shared__ unsigned short Hl[32][264];
    const int lane = threadIdx.x & 63;
    const int wave = threadIdx.x >> 6;
    const int rowbase = blockIdx.x * 32;
    const unsigned short* W = wfrag;
    mlayer<0, 4, 0>(Hh, Hl, rowbase, x, W + (size_t)0   * 8192, b0,          nullptr, nullptr, lane, wave);
    mlayer<16,0, 0>(Hh, Hl, rowbase, x, W + (size_t)4   * 8192, bmid + 0,    nullptr, nullptr, lane, wave);
    mlayer<16,0, 0>(Hh, Hl, rowbase, x, W + (size_t)20  * 8192, bmid + 256,  nullptr, nullptr, lane, wave);
    mlayer<16,0, 0>(Hh, Hl, rowbase, x, W + (size_t)36  * 8192, bmid + 512,  nullptr, nullptr, lane, wave);
    mlayer<16,4, 0>(Hh, Hl, rowbase, x, W + (size_t)52  * 8192, bskip,       nullptr, nullptr, lane, wave);
    mlayer<16,0, 0>(Hh, Hl, rowbase, x, W + (size_t)72  * 8192, bmid + 768,  nullptr, nullptr, lane, wave);
    mlayer<16,0, 0>(Hh, Hl, rowbase, x, W + (size_t)88  * 8192, bmid + 1024, nullptr, nullptr, lane, wave);
    mlayer<16,0, 0>(Hh, Hl, rowbase, x, W + (size_t)104 * 8192, bmid + 1280, nullptr, nullptr, lane, wave);
    mlayer<16,0, 1>(Hh, Hl, rowbase, x, W + (size_t)120 * 8192, bfin,        fphi,    fplo,    lane, wave);
    if (wave == 0) {
        const int r31 = lane & 31, g = lane >> 5;
        float s = 0.f;
        #pragma unroll
        for (int kk = 0; kk < 32; kk++) {
            short4v hh = *(const short4v*)&Hh[r31][g * 128 + kk * 4];
            short4v hl = *(const short4v*)&Hl[r31][g * 128 + kk * 4];
            float4 wv = *(const float4*)&wsig[g * 128 + kk * 4];
            s = fmaf(bf2f((unsigned short)hh[0]) + bf2f((unsigned short)hl[0]), wv.x, s);
            s = fmaf(bf2f((unsigned short)hh[1]) + bf2f((unsigned short)hl[1]), wv.y, s);
            s = fmaf(bf2f((unsigned short)hh[2]) + bf2f((unsigned short)hl[2]), wv.z, s);
            s = fmaf(bf2f((unsigned short)hh[3]) + bf2f((unsigned short)hl[3]), wv.w, s);
        }
        s += __shfl_xor(s, 32);
        if (lane < 32) out[(size_t)(rowbase + r31) * 4 + 3] = s + bsig[0];
    }
}

// ---------------- PQ1: [feat(256 bf16 planes), dir(27)] x 288 -> 256 cols, MFMA ----------------
__global__ __launch_bounds__(256, 4) void k_pq1_mfma(
    const unsigned short* __restrict__ fphi, const unsigned short* __restrict__ fplo,
    const float* __restrict__ x, const unsigned short* __restrict__ wf,
    float* __restrict__ PQ)
{
    __shared__ unsigned short Hh[32][302];
    __shared__ unsigned short Hl[32][302];
    const int tid = threadIdx.x;
    const int lane = tid & 63, wave = tid >> 6;
    const int r31 = lane & 31, g = lane >> 5;
    const int rowbase = blockIdx.x * 32;
    for (int s = tid; s < 32 * 32; s += 256) {
        int r = s >> 5, c8 = (s & 31) << 3;
        *(short8*)&Hh[r][c8] = *(const short8*)&fphi[(size_t)(rowbase + r) * 256 + c8];
        *(short8*)&Hl[r][c8] = *(const short8*)&fplo[(size_t)(rowbase + r) * 256 + c8];
    }
    for (int s = tid; s < 32 * 32; s += 256) {
        int r = s >> 5, d = s & 31;
        float v = (d < 27) ? x[(size_t)(rowbase + r) * 90 + 63 + d] : 0.f;
        unsigned short h = bf16rne(v);
        Hh[r][256 + d] = h;
        Hl[r][256 + d] = bf16rne(v - bf2f(h));
    }
    __syncthreads();
    const int ct0 = wave * 2;
    f32x16 acc0, acc1;
    #pragma unroll
    for (int r = 0; r < 16; r++) { acc0[r] = 0.f; acc1[r] = 0.f; }
    const unsigned short* wp0 = wf + (size_t)ct0 * 18 * 1024 + lane * 8;
    const unsigned short* wp1 = wp0 + (size_t)18 * 1024;
    #pragma unroll
    for (int kc = 0; kc < 18; kc++) {
        short8 ah = *(const short8*)&Hh[r31][kc * 16 + g * 8];
        short8 al = *(const short8*)&Hl[r31][kc * 16 + g * 8];
        short8 b0h = *(const short8*)(wp0 + kc * 1024);
        short8 b0l = *(const short8*)(wp0 + kc * 1024 + 512);
        short8 b1h = *(const short8*)(wp1 + kc * 1024);
        short8 b1l = *(const short8*)(wp1 + kc * 1024 + 512);
        acc0 = __builtin_amdgcn_mfma_f32_32x32x16_bf16(ah, b0h, acc0, 0, 0, 0);
        acc1 = __builtin_amdgcn_mfma_f32_32x32x16_bf16(ah, b1h, acc1, 0, 0, 0);
        acc0 = __builtin_amdgcn_mfma_f32_32x32x16_bf16(al, b0h, acc0, 0, 0, 0);
        acc1 = __builtin_amdgcn_mfma_f32_32x32x16_bf16(al, b1h, acc1, 0, 0, 0);
        acc0 = __builtin_amdgcn_mfma_f32_32x32x16_bf16(ah, b0l, acc0, 0, 0, 0);
        acc1 = __builtin_amdgcn_mfma_f32_32x32x16_bf16(ah, b1l, acc1, 0, 0, 0);
    }
    #pragma unroll
    for (int r = 0; r < 16; r++) {
        int row = (r & 3) + 8 * (r >> 2) + 4 * g;
        PQ[(size_t)(rowbase + row) * 256 + ct0 * 32 + r31] = acc0[r];
        PQ[(size_t)(rowbase + row) * 256 + ct0 * 32 + 32 + r31] = acc1[r];
    }
}

// ---------------- PQ2: d1(128 fp32) -> 256 cols, MFMA ----------------
__global__ __launch_bounds__(256, 4) void k_pq2_mfma(
    const float* __restrict__ d1, const unsigned short* __restrict__ wf,
    float* __restrict__ PQ)
{
    __shared__ unsigned short Hh[32][134];
    __shared__ unsigned short Hl[32][134];
    const int tid = threadIdx.x;
    const int lane = tid & 63, wave = tid >> 6;
    const int r31 = lane & 31, g = lane >> 5;
    const int rowbase = blockIdx.x * 32;
    for (int s = tid; s < 32 * 128; s += 256) {
        int r = s >> 7, c = s & 127;
        float v = d1[(size_t)(rowbase + r) * 128 + c];
        unsigned short h = bf16rne(v);
        Hh[r][c] = h;
        Hl[r][c] = bf16rne(v - bf2f(h));
    }
    __syncthreads();
    const int ct0 = wave * 2;
    f32x16 acc0, acc1;
    #pragma unroll
    for (int r = 0; r < 16; r++) { acc0[r] = 0.f; acc1[r] = 0.f; }
    const unsigned short* wp0 = wf + (size_t)ct0 * 8 * 1024 + lane * 8;
    const unsigned short* wp1 = wp0 + (size_t)8 * 1024;
    #pragma unroll
    for (int kc = 0; kc < 8; kc++) {
        short8 ah = *(const short8*)&Hh[r31][kc * 16 + g * 8];
        short8 al = *(const short8*)&Hl[r31][kc * 16 + g * 8];
        short8 b0h = *(const short8*)(wp0 + kc * 1024);
        short8 b0l = *(const short8*)(wp0 + kc * 1024 + 512);
        short8 b1h = *(const short8*)(wp1 + kc * 1024);
        short8 b1l = *(const short8*)(wp1 + kc * 1024 + 512);
        acc0 = __builtin_amdgcn_mfma_f32_32x32x16_bf16(ah, b0h, acc0, 0, 0, 0);
        acc1 = __builtin_amdgcn_mfma_f32_32x32x16_bf16(ah, b1h, acc1, 0, 0, 0);
        acc0 = __builtin_amdgcn_mfma_f32_32x32x16_bf16(al, b0h, acc0, 0, 0, 0);
        acc1 = __builtin_amdgcn_mfma_f32_32x32x16_bf16(al, b1h, acc1, 0, 0, 0);
        acc0 = __builtin_amdgcn_mfma_f32_32x32x16_bf16(ah, b0l, acc0, 0, 0, 0);
        acc1 = __builtin_amdgcn_mfma_f32_32x32x16_bf16(ah, b1l, acc1, 0, 0, 0);
    }
    #pragma unroll
    for (int r = 0; r < 16; r++) {
        int row = (r & 3) + 8 * (r >> 2) + 4 * g;
        PQ[(size_t)(rowbase + row) * 256 + ct0 * 32 + r31] = acc0[r];
        PQ[(size_t)(rowbase + row) * 256 + ct0 * 32 + 32 + r31] = acc1[r];
    }
}

// ---------------- edge conv (unchanged fp32) ----------------
template<int RGB>
__global__ __launch_bounds__(256) void k_edge(const float* __restrict__ PQ,
    const float* __restrict__ b1, const float* __restrict__ w2,
    const float* __restrict__ b2, const int* __restrict__ nbr,
    float* __restrict__ dout,
    const float* __restrict__ wrgb, const float* __restrict__ brgb,
    float* __restrict__ out)
{
    __shared__ float h1T[128][97];
    __shared__ float wb[32][128];
    const int tid = threadIdx.x;
    const int n0 = blockIdx.x * 32;
    {
        const int c = tid & 127, eg = tid >> 7;
        const float bias = b1[c];
        for (int e = eg; e < 96; e += 2) {
            int n = e / 3;
            int jj = e - n * 3;
            int i = n0 + n;
            int j = nbr[(size_t)i * 3 + jj];
            float v = PQ[(size_t)i * 256 + c] + bias
                    + PQ[(size_t)j * 256 + 128 + c] - PQ[(size_t)i * 256 + 128 + c];
            h1T[c][e] = fmaxf(v, 0.f);
        }
    }
    const int cg = tid & 15, rg = tid >> 4;
    const int cLo = cg * 4, cHi = 64 + cg * 4, e0 = rg * 6;
    float acc[6][8];
    #pragma unroll
    for (int m = 0; m < 6; m++)
        #pragma unroll
        for (int j = 0; j < 8; j++) acc[m][j] = 0.f;
    for (int k0 = 0; k0 < 128; k0 += 32) {
        __syncthreads();
        for (int s = tid; s < 32 * 128; s += 256) {
            int kk = s >> 7, c = s & 127;
            wb[kk][c] = w2[(size_t)(k0 + kk) * 128 + c];
        }
        __syncthreads();
        for (int kk = 0; kk < 32; kk++) {
            const int k = k0 + kk;
            float av[6];
            #pragma unroll
            for (int m = 0; m < 6; m++) av[m] = h1T[k][e0 + m];
            float4 w0v = *(const float4*)&wb[kk][cLo];
            float4 w1v = *(const float4*)&wb[kk][cHi];
            float bv[8] = {w0v.x,w0v.y,w0v.z,w0v.w,w1v.x,w1v.y,w1v.z,w1v.w};
            #pragma unroll
            for (int m = 0; m < 6; m++)
                #pragma unroll
                for (int j = 0; j < 8; j++)
                    acc[m][j] = fmaf(av[m], bv[j], acc[m][j]);
        }
    }
    float bb[8];
    #pragma unroll
    for (int j = 0; j < 8; j++) bb[j] = b2[(j < 4) ? (cLo + j) : (cHi + j - 4)];
    float dA[8], dB[8];
    #pragma unroll
    for (int j = 0; j < 8; j++) {
        float h0 = fmaxf(acc[0][j] + bb[j], 0.f);
        float h1 = fmaxf(acc[1][j] + bb[j], 0.f);
        float h2 = fmaxf(acc[2][j] + bb[j], 0.f);
        float h3 = fmaxf(acc[3][j] + bb[j], 0.f);
        float h4 = fmaxf(acc[4][j] + bb[j], 0.f);
        float h5 = fmaxf(acc[5][j] + bb[j], 0.f);
        dA[j] = (h0 + h1 + h2) * (1.f / 3.f);
        dB[j] = (h3 + h4 + h5) * (1.f / 3.f);
    }
    if (!RGB) {
        *(float4*)&dout[(size_t)(n0 + 2*rg) * 128 + cLo] = make_float4(dA[0], dA[1], dA[2], dA[3]);
        *(float4*)&dout[(size_t)(n0 + 2*rg) * 128 + cHi] = make_float4(dA[4], dA[5], dA[6], dA[7]);
        *(float4*)&dout[(size_t)(n0 + 2*rg + 1) * 128 + cLo] = make_float4(dB[0], dB[1], dB[2], dB[3]);
        *(float4*)&dout[(size_t)(n0 + 2*rg + 1) * 128 + cHi] = make_float4(dB[4], dB[5], dB[6], dB[7]);
    } else {
        __syncthreads();
        float* d2L = &h1T[0][0];
        #pragma unroll
        for (int j = 0; j < 4; j++) {
            d2L[(2*rg)     * 130 + cLo + j] = dA[j];
            d2L[(2*rg)     * 130 + cHi + j] = dA[j + 4];
            d2L[(2*rg + 1) * 130 + cLo + j] = dB[j];
            d2L[(2*rg + 1) * 130 + cHi + j] = dB[j + 4];
        }
        __syncthreads();
        if (tid < 96) {
            int n = tid / 3, ch = tid - 3 * (tid / 3);
            float s = brgb[ch];
            for (int k = 0; k < 128; k++) s = fmaf(d2L[n * 130 + k], wrgb[k * 3 + ch], s);
            out[(size_t)(n0 + n) * 4 + ch] = 1.f / (1.f + expf(-s));
        }
    }
}

// ---------------- launch ----------------
extern "C" void kernel_launch(void* const* d_in, const int* in_sizes, int n_in,
                              void* d_out, int out_size, void* d_ws, size_t ws_size,
                              hipStream_t stream)
{
    const float* x     = (const float*)d_in[0];
    const int*   bid   = (const int*)d_in[1];
    const float* w0    = (const float*)d_in[2];
    const float* b0    = (const float*)d_in[3];
    const float* wmid  = (const float*)d_in[4];
    const float* bmid  = (const float*)d_in[5];
    const float* wskip = (const float*)d_in[6];
    const float* bskip = (const float*)d_in[7];
    const float* wfin  = (const float*)d_in[8];
    const float* bfin  = (const float*)d_in[9];
    const float* wsig  = (const float*)d_in[10];
    const float* bsig  = (const float*)d_in[11];
    const float* e1w1  = (const float*)d_in[12];
    const float* e1b1  = (const float*)d_in[13];
    const float* e1w2  = (const float*)d_in[14];
    const float* e1b2  = (const float*)d_in[15];
    const float* e2w1  = (const float*)d_in[16];
    const float* e2b1  = (const float*)d_in[17];
    const float* e2w2  = (const float*)d_in[18];
    const float* e2b2  = (const float*)d_in[19];
    const float* wrgb  = (const float*)d_in[20];
    const float* brgb  = (const float*)d_in[21];
    float* out = (float*)d_out;

    char* ws = (char*)d_ws;
    int* cnt = (int*)ws;                                        // 256 B
    int* grp = (int*)(ws + 256);                                // 160 KB
    int* nbr = (int*)(ws + 164096);                             // 480 KB -> ends 655616
    unsigned short* wfpq1 = (unsigned short*)(ws + 655616);     // 288 KB -> ends 950528
    unsigned short* wfpq2 = (unsigned short*)(ws + 950528);     // 128 KB -> ends ~1.03 MB
    float* bufA = (float*)(ws + (2 << 20));                     // 42 MB
    float* bufB = bufA + (size_t)B_TOTAL * 256;                 // 42 MB

    // kNN overlays on bufA (dead before trunk writes fphi/fplo there):
    unsigned short* xbh = (unsigned short*)bufA;
    unsigned short* xbl = xbh + (size_t)B_TOTAL * 64;
    float* cn   = (float*)(xbl + (size_t)B_TOTAL * 64);
    unsigned long long* pkey = (unsigned long long*)(cn + B_TOTAL);
    // trunk outputs / edge intermediates:
    unsigned short* fphi = (unsigned short*)bufA;               // 21 MB
    unsigned short* fplo = fphi + (size_t)B_TOTAL * 256;        // 21 MB
    float* d1 = (float*)bufA;                                   // 21 MB (after pq1 consumed fphi/fplo)
    float* PQ = bufB;                                           // 42 MB
    unsigned short* wfrag = (unsigned short*)((char*)bufB + ((size_t)39 << 20));  // dead before PQ written

    hipMemsetAsync(cnt, 0, 256, stream);
    k_scatter<<<B_TOTAL / 256, 256, 0, stream>>>(bid, grp, cnt);
    k_wprep<<<(557056 + 255) / 256, 256, 0, stream>>>(w0, wmid, wskip, wfin, wfrag);
    k_wprep_pq<<<(18 * 8 * 512 + 255) / 256, 256, 0, stream>>>(e1w1, 283, 18, wfpq1);
    k_wprep_pq<<<(8 * 8 * 512 + 255) / 256, 256, 0, stream>>>(e2w1, 128, 8, wfpq2);
    k_gather<<<dim3(GSZ / 128, NGRP), 256, 0, stream>>>(x, grp, xbh, xbl, cn);
    k_knn_mfma<<<dim3(GSZ / 64, CPART, NGRP), 256, 0, stream>>>(xbh, xbl, cn, pkey);
    k_knn_merge<<<(NGRP * GSZ + 255) / 256, 256, 0, stream>>>(pkey, grp, nbr);
    k_trunk_mfma<<<B_TOTAL / 32, 256, 0, stream>>>(x, wfrag, b0, bmid, bskip, bfin,
                                                   wsig, bsig, fphi, fplo, out);
    k_pq1_mfma<<<B_TOTAL / 32, 256, 0, stream>>>(fphi, fplo, x, wfpq1, PQ);
    k_edge<0><<<B_TOTAL / 32, 256, 0, stream>>>(PQ, e1b1, e1w2, e1b2, nbr, d1,
                                                nullptr, nullptr, nullptr);
    k_pq2_mfma<<<B_TOTAL / 32, 256, 0, stream>>>(d1, wfpq2, PQ);
    k_edge<1><<<B_TOTAL / 32, 256, 0, stream>>>(PQ, e2b1, e2w2, e2b2, nbr, nullptr,
                                                wrgb, brgb, out);
}

// Round 11
// 610.184 us; speedup vs baseline: 2.0382x; 1.0304x over previous
//
#include <hip/hip_runtime.h>
#include <hip/hip_bf16.h>
#include <math.h>

#define B_TOTAL 40960
#define NGRP 20
#define GSZ 2048
#define CPART 4

typedef short short8 __attribute__((ext_vector_type(8)));
typedef short short4v __attribute__((ext_vector_type(4)));
typedef float f32x4 __attribute__((ext_vector_type(4)));
typedef float f32x16 __attribute__((ext_vector_type(16)));

// ---------------- group scatter ----------------
__global__ void k_scatter(const int* __restrict__ bid, int* __restrict__ grp,
                          int* __restrict__ cnt)
{
    int i = blockIdx.x * 256 + threadIdx.x;
    if (i < B_TOTAL) {
        int g = bid[i];
        int p = atomicAdd(&cnt[g], 1);
        grp[g * GSZ + p] = i;
    }
}

// ---------------- bf16 helpers ----------------
__device__ __forceinline__ unsigned short bf16rne(float v)
{
    unsigned int u = __float_as_uint(v);
    unsigned int r = (u + 0x7FFFu + ((u >> 16) & 1u)) >> 16;
    return (unsigned short)r;
}

__device__ __forceinline__ float bf2f(unsigned short h)
{
    return __uint_as_float((unsigned int)h << 16);
}

__device__ __forceinline__ void splitbf16(const float* v, short8& hi, short8& lo)
{
    #pragma unroll
    for (int j = 0; j < 8; j++) {
        unsigned short h = bf16rne(v[j]);
        hi[j] = (short)h;
        lo[j] = (short)bf16rne(v[j] - bf2f(h));
    }
}

// ordered-float key: monotonic unsigned encoding of float
__device__ __forceinline__ unsigned int fkey(float f)
{
    unsigned int u = __float_as_uint(f);
    unsigned int m = (unsigned int)((int)u >> 31) | 0x80000000u;
    return u ^ m;
}

// branch-free sorted insert of (k,i) into ((k0,i0) <= (k1,i1) <= (k2,i2))
__device__ __forceinline__ void ins3p(unsigned int k, unsigned int i,
    unsigned int& k0, unsigned int& i0, unsigned int& k1, unsigned int& i1,
    unsigned int& k2, unsigned int& i2)
{
    bool c0 = k < k0;
    unsigned int tk = c0 ? k0 : k, ti = c0 ? i0 : i;
    k0 = c0 ? k : k0;  i0 = c0 ? i : i0;
    bool c1 = tk < k1;
    unsigned int sk = c1 ? k1 : tk, si = c1 ? i1 : ti;
    k1 = c1 ? tk : k1; i1 = c1 ? ti : i1;
    bool c2 = sk < k2;
    k2 = c2 ? sk : k2; i2 = c2 ? si : i2;
}

__device__ __forceinline__ void mergerow(unsigned int& k0, unsigned int& i0,
    unsigned int& k1, unsigned int& i1, unsigned int& k2, unsigned int& i2)
{
    #pragma unroll
    for (int m = 1; m <= 8; m <<= 1) {
        unsigned int ok0 = (unsigned int)__shfl_xor((int)k0, m);
        unsigned int oi0 = (unsigned int)__shfl_xor((int)i0, m);
        unsigned int ok1 = (unsigned int)__shfl_xor((int)k1, m);
        unsigned int oi1 = (unsigned int)__shfl_xor((int)i1, m);
        unsigned int ok2 = (unsigned int)__shfl_xor((int)k2, m);
        unsigned int oi2 = (unsigned int)__shfl_xor((int)i2, m);
        ins3p(ok0, oi0, k0, i0, k1, i1, k2, i2);
        ins3p(ok1, oi1, k0, i0, k1, i1, k2, i2);
        ins3p(ok2, oi2, k0, i0, k1, i1, k2, i2);
    }
}

// ---------------- kNN stage 1: gather -> packed bf16 hi/lo planes + norms ----------------
__global__ __launch_bounds__(256) void k_gather(const float* __restrict__ x,
    const int* __restrict__ grp, unsigned short* __restrict__ xbh,
    unsigned short* __restrict__ xbl, float* __restrict__ cn)
{
    __shared__ float tile[128][65];
    __shared__ int ids[128];
    const int tid = threadIdx.x;
    const int g = blockIdx.y;
    const int q0 = blockIdx.x * 128;
    if (tid < 128) ids[tid] = grp[g * GSZ + q0 + tid];
    __syncthreads();
    for (int s = tid; s < 128 * 64; s += 256) {
        int q = s >> 6, d = s & 63;
        tile[q][d] = (d < 63) ? x[(size_t)ids[q] * 90 + d] : 0.f;
    }
    __syncthreads();
    if (tid < 128) {
        float a = 0.f;
        #pragma unroll
        for (int d = 0; d < 63; d++) a = fmaf(tile[tid][d], tile[tid][d], a);
        cn[g * GSZ + q0 + tid] = a;
    }
    for (int s = tid; s < 128 * 32; s += 256) {
        int q = s >> 5, dp = (s & 31) << 1;
        float v0 = tile[q][dp], v1 = tile[q][dp + 1];
        unsigned short h0 = bf16rne(v0), h1 = bf16rne(v1);
        unsigned short l0 = bf16rne(v0 - bf2f(h0)), l1 = bf16rne(v1 - bf2f(h1));
        size_t pt = (size_t)g * GSZ + q0 + q;
        ((unsigned int*)xbh)[pt * 32 + (dp >> 1)] = (unsigned int)h0 | ((unsigned int)h1 << 16);
        ((unsigned int*)xbl)[pt * 32 + (dp >> 1)] = (unsigned int)l0 | ((unsigned int)l1 << 16);
    }
}

// ---------------- kNN stage 2: MFMA distance tiles, LDS-shared stream, branch-free top3 ----------------
__global__ __launch_bounds__(256) void k_knn_mfma(const unsigned short* __restrict__ xbh,
    const unsigned short* __restrict__ xbl, const float* __restrict__ cn,
    unsigned long long* __restrict__ pkey)
{
    __shared__ char cbuf[2][16384];
    const int tid = threadIdx.x;
    const int lane = tid & 63;
    const int wave = tid >> 6;
    const int g = blockIdx.z;
    const int part = blockIdx.y;
    const int qt0 = blockIdx.x * 64 + wave * 16;
    const size_t gbase = (size_t)g * GSZ;
    const int lp = lane & 15;
    const int kgrp = lane >> 4;
    const int kg = kgrp << 3;

    const size_t qb = (gbase + qt0 + lp) * 64;
    short8 ah0 = *(const short8*)(xbh + qb + kg);
    short8 ah1 = *(const short8*)(xbh + qb + 32 + kg);
    short8 al0 = *(const short8*)(xbl + qb + kg);
    short8 al1 = *(const short8*)(xbl + qb + 32 + kg);

    const int qp0 = qt0 + (kgrp << 2);   // query row of acc[r] is qp0 + r

    unsigned int K00 = ~0u, I00 = 0, K01 = ~0u, I01 = 0, K02 = ~0u, I02 = 0;
    unsigned int K10 = ~0u, I10 = 0, K11 = ~0u, I11 = 0, K12 = ~0u, I12 = 0;
    unsigned int K20 = ~0u, I20 = 0, K21 = ~0u, I21 = 0, K22 = ~0u, I22 = 0;
    unsigned int K30 = ~0u, I30 = 0, K31 = ~0u, I31 = 0, K32 = ~0u, I32 = 0;

    const int scand = tid & 63;
    const int cbeg = part * (GSZ / CPART);
    const int s0 = wave, s1 = 4 + wave, s2 = 8 + wave, s3 = 12 + wave;
    const unsigned short* pl0 = (s0 < 8) ? xbh : xbl;
    const unsigned short* pl1 = (s1 < 8) ? xbh : xbl;
    const unsigned short* pl2 = (s2 < 8) ? xbh : xbl;
    const unsigned short* pl3 = (s3 < 8) ? xbh : xbl;

    short8 st0, st1, st2, st3;
    {
        size_t cb = (gbase + cbeg + scand) * 64;
        st0 = *(const short8*)(pl0 + cb + (s0 & 7) * 8);
        st1 = *(const short8*)(pl1 + cb + (s1 & 7) * 8);
        st2 = *(const short8*)(pl2 + cb + (s2 & 7) * 8);
        st3 = *(const short8*)(pl3 + cb + (s3 & 7) * 8);
    }
    *(short8*)&cbuf[0][(s0 << 10) + (scand << 4)] = st0;
    *(short8*)&cbuf[0][(s1 << 10) + (scand << 4)] = st1;
    *(short8*)&cbuf[0][(s2 << 10) + (scand << 4)] = st2;
    *(short8*)&cbuf[0][(s3 << 10) + (scand << 4)] = st3;

    for (int ch = 0; ch < 8; ch++) {
        const int cur = ch & 1;
        __syncthreads();                   // cbuf[cur] ready for all waves
        if (ch < 7) {                      // issue next chunk's loads early
            size_t cb = (gbase + cbeg + (ch + 1) * 64 + scand) * 64;
            st0 = *(const short8*)(pl0 + cb + (s0 & 7) * 8);
            st1 = *(const short8*)(pl1 + cb + (s1 & 7) * 8);
            st2 = *(const short8*)(pl2 + cb + (s2 & 7) * 8);
            st3 = *(const short8*)(pl3 + cb + (s3 & 7) * 8);
        }
        const int cc0 = cbeg + ch * 64;
        #pragma unroll
        for (int ct = 0; ct < 4; ct++) {
            const int coff = ((ct * 16 + lp) << 4);
            short8 bh0 = *(const short8*)&cbuf[cur][((kgrp)      << 10) + coff];
            short8 bh1 = *(const short8*)&cbuf[cur][((4 + kgrp)  << 10) + coff];
            short8 bl0 = *(const short8*)&cbuf[cur][((8 + kgrp)  << 10) + coff];
            short8 bl1 = *(const short8*)&cbuf[cur][((12 + kgrp) << 10) + coff];
            f32x4 acc = {0.f, 0.f, 0.f, 0.f};
            acc = __builtin_amdgcn_mfma_f32_16x16x32_bf16(ah0, bh0, acc, 0, 0, 0);
            acc = __builtin_amdgcn_mfma_f32_16x16x32_bf16(ah1, bh1, acc, 0, 0, 0);
            acc = __builtin_amdgcn_mfma_f32_16x16x32_bf16(al0, bh0, acc, 0, 0, 0);
            acc = __builtin_amdgcn_mfma_f32_16x16x32_bf16(al1, bh1, acc, 0, 0, 0);
            acc = __builtin_amdgcn_mfma_f32_16x16x32_bf16(ah0, bl0, acc, 0, 0, 0);
            acc = __builtin_amdgcn_mfma_f32_16x16x32_bf16(ah1, bl1, acc, 0, 0, 0);
            const float cnv = cn[gbase + cc0 + ct * 16 + lp];
            const int cpos = cc0 + ct * 16 + lp;
            const unsigned int ci = (unsigned int)cpos;
            {
                unsigned int k = fkey(fmaf(-2.f, acc[0], cnv));
                k = (cpos == qp0 + 0) ? 0xFFFFFFFFu : k;
                ins3p(k, ci, K00, I00, K01, I01, K02, I02);
            }
            {
                unsigned int k = fkey(fmaf(-2.f, acc[1], cnv));
                k = (cpos == qp0 + 1) ? 0xFFFFFFFFu : k;
                ins3p(k, ci, K10, I10, K11, I11, K12, I12);
            }
            {
                unsigned int k = fkey(fmaf(-2.f, acc[2], cnv));
                k = (cpos == qp0 + 2) ? 0xFFFFFFFFu : k;
                ins3p(k, ci, K20, I20, K21, I21, K22, I22);
            }
            {
                unsigned int k = fkey(fmaf(-2.f, acc[3], cnv));
                k = (cpos == qp0 + 3) ? 0xFFFFFFFFu : k;
                ins3p(k, ci, K30, I30, K31, I31, K32, I32);
            }
        }
        if (ch < 7) {
            *(short8*)&cbuf[cur ^ 1][(s0 << 10) + (scand << 4)] = st0;
            *(short8*)&cbuf[cur ^ 1][(s1 << 10) + (scand << 4)] = st1;
            *(short8*)&cbuf[cur ^ 1][(s2 << 10) + (scand << 4)] = st2;
            *(short8*)&cbuf[cur ^ 1][(s3 << 10) + (scand << 4)] = st3;
        }
    }

    mergerow(K00, I00, K01, I01, K02, I02);
    mergerow(K10, I10, K11, I11, K12, I12);
    mergerow(K20, I20, K21, I21, K22, I22);
    mergerow(K30, I30, K31, I31, K32, I32);

    if (lp == 0) {
        size_t ob = (gbase + (size_t)qp0) * (CPART * 3) + part * 3;
        pkey[ob + 0]  = ((unsigned long long)K00 << 32) | I00;
        pkey[ob + 1]  = ((unsigned long long)K01 << 32) | I01;
        pkey[ob + 2]  = ((unsigned long long)K02 << 32) | I02;
        pkey[ob + 12] = ((unsigned long long)K10 << 32) | I10;
        pkey[ob + 13] = ((unsigned long long)K11 << 32) | I11;
        pkey[ob + 14] = ((unsigned long long)K12 << 32) | I12;
        pkey[ob + 24] = ((unsigned long long)K20 << 32) | I20;
        pkey[ob + 25] = ((unsigned long long)K21 << 32) | I21;
        pkey[ob + 26] = ((unsigned long long)K22 << 32) | I22;
        pkey[ob + 36] = ((unsigned long long)K30 << 32) | I30;
        pkey[ob + 37] = ((unsigned long long)K31 << 32) | I31;
        pkey[ob + 38] = ((unsigned long long)K32 << 32) | I32;
    }
}

// ---------------- kNN stage 3: merge CPART partials from u64 keys ----------------
__device__ __forceinline__ void ins3u(unsigned long long k,
    unsigned long long& k0, unsigned long long& k1, unsigned long long& k2)
{
    if (k < k0)      { k2 = k1; k1 = k0; k0 = k; }
    else if (k < k1) { k2 = k1; k1 = k; }
    else if (k < k2) { k2 = k; }
}

__global__ void k_knn_merge(const unsigned long long* __restrict__ pkey,
                            const int* __restrict__ grp, int* __restrict__ nbr)
{
    int t = blockIdx.x * 256 + threadIdx.x;
    if (t >= NGRP * GSZ) return;
    int g = t >> 11;
    unsigned long long k0 = ~0ull, k1 = ~0ull, k2 = ~0ull;
    const unsigned long long* pk = pkey + (size_t)t * (CPART * 3);
    #pragma unroll
    for (int r = 0; r < CPART * 3; r++) ins3u(pk[r], k0, k1, k2);
    int qi = grp[t];
    nbr[(size_t)qi * 3 + 0] = grp[(g << 11) + (int)(k0 & 0xFFFFFFFFull)];
    nbr[(size_t)qi * 3 + 1] = grp[(g << 11) + (int)(k1 & 0xFFFFFFFFull)];
    nbr[(size_t)qi * 3 + 2] = grp[(g << 11) + (int)(k2 & 0xFFFFFFFFull)];
}

// ---------------- trunk weight prep: split-bf16, fragment-major ----------------
__global__ void k_wprep(const float* __restrict__ w0, const float* __restrict__ wmid,
                        const float* __restrict__ wskip, const float* __restrict__ wfin,
                        unsigned short* __restrict__ wfrag)
{
    int t = blockIdx.x * 256 + threadIdx.x;
    if (t >= 557056) return;
    const int CUMa[10] = {0,4,20,36,52,72,88,104,120,136};
    const int KCa[9]   = {4,16,16,16,20,16,16,16,16};
    int q = t >> 12;
    int L = 0;
    #pragma unroll
    for (int i = 0; i < 9; i++) if (q >= CUMa[i + 1]) L = i + 1;
    int cum = 0, kcn = 16;
    #pragma unroll
    for (int i = 0; i < 9; i++) if (L == i) { cum = CUMa[i]; kcn = KCa[i]; }
    int u = t - (cum << 12);
    int j = u & 7, lane = (u >> 3) & 63;
    int ckk = u >> 9;
    int kc = ckk % kcn, ct = ckk / kcn;
    int col = ct * 32 + (lane & 31);
    int k = kc * 16 + ((lane >> 5) << 3) + j;
    float w;
    if (L == 0)      w = (k < 63)  ? w0[k * 256 + col] : 0.f;
    else if (L == 4) w = (k < 256) ? wskip[(63 + k) * 256 + col]
                       : (k < 319) ? wskip[(k - 256) * 256 + col] : 0.f;
    else if (L == 8) w = wfin[k * 256 + col];
    else {
        int m = (L <= 3) ? (L - 1) : (L - 2);
        w = wmid[(size_t)m * 65536 + k * 256 + col];
    }
    unsigned short hi = bf16rne(w);
    unsigned short lo = bf16rne(w - bf2f(hi));
    size_t base = ((size_t)cum << 13) + (size_t)(ct * kcn + kc) * 1024 + lane * 8 + j;
    wfrag[base] = hi;
    wfrag[base + 512] = lo;
}

// ---------------- PQ weight prep: combined [K][256] (top|bottom), split-bf16 frag-major ----------------
__global__ void k_wprep_pq(const float* __restrict__ src, int K, int KCN,
                           unsigned short* __restrict__ dst)
{
    int t = blockIdx.x * 256 + threadIdx.x;
    if (t >= KCN * 8 * 512) return;
    int j = t & 7, lane = (t >> 3) & 63;
    int ckk = t >> 9;
    int kc = ckk % KCN, ct = ckk / KCN;
    int col = ct * 32 + (lane & 31);
    int k = kc * 16 + ((lane >> 5) << 3) + j;
    float w = 0.f;
    if (k < K) w = (col < 128) ? src[(size_t)k * 128 + col]
                               : src[(size_t)(K + k) * 128 + (col - 128)];
    unsigned short hi = bf16rne(w);
    unsigned short lo = bf16rne(w - bf2f(hi));
    size_t base = (size_t)(ct * KCN + kc) * 1024 + lane * 8 + j;
    dst[base] = hi;
    dst[base + 512] = lo;
}

// ---------------- fused trunk MLP: 8 waves, 64-row tile, wave = 1 column-tile ----------------
// Hh/Hl: [64][264] bf16 planes. Wave w computes ct = w over rows 0-31 (acc0) and 32-63 (acc1).
template<int KCH, int KCX, int OUTMODE>   // OUTMODE 0: relu->LDS H; 1: -> global bf16 planes
__device__ __forceinline__ void mlayer64(unsigned short (*Hh)[264], unsigned short (*Hl)[264],
    int rowbase, const float* __restrict__ x, const unsigned short* __restrict__ wl,
    const float* __restrict__ bias, unsigned short* __restrict__ gh,
    unsigned short* __restrict__ gl, int lane, int wave)
{
    const int r31 = lane & 31, g = lane >> 5;
    constexpr int KC = KCH + KCX;
    const int ct = wave;
    f32x16 acc0, acc1;
    #pragma unroll
    for (int r = 0; r < 16; r++) { acc0[r] = 0.f; acc1[r] = 0.f; }
    const unsigned short* wp = wl + (size_t)ct * KC * 1024 + lane * 8;
    #pragma unroll
    for (int kc = 0; kc < KCH; kc++) {
        short8 ah0 = *(const short8*)&Hh[r31][kc * 16 + g * 8];
        short8 al0 = *(const short8*)&Hl[r31][kc * 16 + g * 8];
        short8 ah1 = *(const short8*)&Hh[32 + r31][kc * 16 + g * 8];
        short8 al1 = *(const short8*)&Hl[32 + r31][kc * 16 + g * 8];
        short8 bh = *(const short8*)(wp + kc * 1024);
        short8 bl = *(const short8*)(wp + kc * 1024 + 512);
        acc0 = __builtin_amdgcn_mfma_f32_32x32x16_bf16(ah0, bh, acc0, 0, 0, 0);
        acc1 = __builtin_amdgcn_mfma_f32_32x32x16_bf16(ah1, bh, acc1, 0, 0, 0);
        acc0 = __builtin_amdgcn_mfma_f32_32x32x16_bf16(al0, bh, acc0, 0, 0, 0);
        acc1 = __builtin_amdgcn_mfma_f32_32x32x16_bf16(al1, bh, acc1, 0, 0, 0);
        acc0 = __builtin_amdgcn_mfma_f32_32x32x16_bf16(ah0, bl, acc0, 0, 0, 0);
        acc1 = __builtin_amdgcn_mfma_f32_32x32x16_bf16(ah1, bl, acc1, 0, 0, 0);
    }
    #pragma unroll
    for (int t = 0; t < KCX; t++) {
        const int kc = KCH + t;
        float v0[8], v1[8];
        #pragma unroll
        for (int j = 0; j < 8; j++) {
            int kx = t * 16 + g * 8 + j;
            v0[j] = (kx < 63) ? x[(size_t)(rowbase + r31) * 90 + kx] : 0.f;
            v1[j] = (kx < 63) ? x[(size_t)(rowbase + 32 + r31) * 90 + kx] : 0.f;
        }
        short8 xh0, xl0, xh1, xl1;
        splitbf16(v0, xh0, xl0);
        splitbf16(v1, xh1, xl1);
        short8 bh = *(const short8*)(wp + kc * 1024);
        short8 bl = *(const short8*)(wp + kc * 1024 + 512);
        acc0 = __builtin_amdgcn_mfma_f32_32x32x16_bf16(xh0, bh, acc0, 0, 0, 0);
        acc1 = __builtin_amdgcn_mfma_f32_32x32x16_bf16(xh1, bh, acc1, 0, 0, 0);
        acc0 = __builtin_amdgcn_mfma_f32_32x32x16_bf16(xl0, bh, acc0, 0, 0, 0);
        acc1 = __builtin_amdgcn_mfma_f32_32x32x16_bf16(xl1, bh, acc1, 0, 0, 0);
        acc0 = __builtin_amdgcn_mfma_f32_32x32x16_bf16(xh0, bl, acc0, 0, 0, 0);
        acc1 = __builtin_amdgcn_mfma_f32_32x32x16_bf16(xh1, bl, acc1, 0, 0, 0);
    }
    const float bv = bias[ct * 32 + r31];
    if (OUTMODE == 0) {
        __syncthreads();                    // all waves done reading H
        #pragma unroll
        for (int r = 0; r < 16; r++) {
            int row = (r & 3) + 8 * (r >> 2) + 4 * g;
            float v0 = fmaxf(acc0[r] + bv, 0.f);
            float v1 = fmaxf(acc1[r] + bv, 0.f);
            unsigned short h0 = bf16rne(v0), h1 = bf16rne(v1);
            Hh[row][ct * 32 + r31] = h0;
            Hl[row][ct * 32 + r31] = bf16rne(v0 - bf2f(h0));
            Hh[32 + row][ct * 32 + r31] = h1;
            Hl[32 + row][ct * 32 + r31] = bf16rne(v1 - bf2f(h1));
        }
        __syncthreads();                    // H ready for next layer
    } else {
        #pragma unroll
        for (int r = 0; r < 16; r++) {
            int row = (r & 3) + 8 * (r >> 2) + 4 * g;
            float v0 = acc0[r] + bv;
            float v1 = acc1[r] + bv;
            unsigned short h0 = bf16rne(v0), h1 = bf16rne(v1);
            size_t o0 = (size_t)(rowbase + row) * 256 + ct * 32 + r31;
            size_t o1 = (size_t)(rowbase + 32 + row) * 256 + ct * 32 + r31;
            gh[o0] = h0;
            gl[o0] = bf16rne(v0 - bf2f(h0));
            gh[o1] = h1;
            gl[o1] = bf16rne(v1 - bf2f(h1));
        }
    }
}

__global__ __launch_bounds__(512, 4) void k_trunk_mfma(const float* __restrict__ x,
    const unsigned short* __restrict__ wfrag,
    const float* __restrict__ b0, const float* __restrict__ bmid,
    const float* __restrict__ bskip, const float* __restrict__ bfin,
    const float* __restrict__ wsig, const float* __restrict__ bsig,
    unsigned short* __restrict__ fphi, unsigned short* __restrict__ fplo,
    float* __restrict__ out)
{
    __shared__ unsigned short Hh[64][264];
    __shared__ unsigned short Hl[64][264];
    const int lane = threadIdx.x & 63;
    const int wave = threadIdx.x >> 6;
    const int rowbase = blockIdx.x * 64;
    const unsigned short* W = wfrag;
    mlayer64<0, 4, 0>(Hh, Hl, rowbase, x, W + (size_t)0   * 8192, b0,          nullptr, nullptr, lane, wave);
    mlayer64<16,0, 0>(Hh, Hl, rowbase, x, W + (size_t)4   * 8192, bmid + 0,    nullptr, nullptr, lane, wave);
    mlayer64<16,0, 0>(Hh, Hl, rowbase, x, W + (size_t)20  * 8192, bmid + 256,  nullptr, nullptr, lane, wave);
    mlayer64<16,0, 0>(Hh, Hl, rowbase, x, W + (size_t)36  * 8192, bmid + 512,  nullptr, nullptr, lane, wave);
    mlayer64<16,4, 0>(Hh, Hl, rowbase, x, W + (size_t)52  * 8192, bskip,       nullptr, nullptr, lane, wave);
    mlayer64<16,0, 0>(Hh, Hl, rowbase, x, W + (size_t)72  * 8192, bmid + 768,  nullptr, nullptr, lane, wave);
    mlayer64<16,0, 0>(Hh, Hl, rowbase, x, W + (size_t)88  * 8192, bmid + 1024, nullptr, nullptr, lane, wave);
    mlayer64<16,0, 0>(Hh, Hl, rowbase, x, W + (size_t)104 * 8192, bmid + 1280, nullptr, nullptr, lane, wave);
    mlayer64<16,0, 1>(Hh, Hl, rowbase, x, W + (size_t)120 * 8192, bfin,        fphi,    fplo,    lane, wave);
    if (wave < 2) {   // sigma from layer-7 H (rows wave*32 .. wave*32+31)
        const int r31 = lane & 31, g = lane >> 5;
        const int row = wave * 32 + r31;
        float s = 0.f;
        #pragma unroll
        for (int kk = 0; kk < 32; kk++) {
            short4v hh = *(const short4v*)&Hh[row][g * 128 + kk * 4];
            short4v hl = *(const short4v*)&Hl[row][g * 128 + kk * 4];
            float4 wv = *(const float4*)&wsig[g * 128 + kk * 4];
            s = fmaf(bf2f((unsigned short)hh[0]) + bf2f((unsigned short)hl[0]), wv.x, s);
            s = fmaf(bf2f((unsigned short)hh[1]) + bf2f((unsigned short)hl[1]), wv.y, s);
            s = fmaf(bf2f((unsigned short)hh[2]) + bf2f((unsigned short)hl[2]), wv.z, s);
            s = fmaf(bf2f((unsigned short)hh[3]) + bf2f((unsigned short)hl[3]), wv.w, s);
        }
        s += __shfl_xor(s, 32);
        if (lane < 32) out[(size_t)(rowbase + row) * 4 + 3] = s + bsig[0];
    }
}

// ---------------- PQ1: [feat(256 bf16 planes), dir(27)] x 288 -> 256 cols, MFMA ----------------
__global__ __launch_bounds__(256, 4) void k_pq1_mfma(
    const unsigned short* __restrict__ fphi, const unsigned short* __restrict__ fplo,
    const float* __restrict__ x, const unsigned short* __restrict__ wf,
    float* __restrict__ PQ)
{
    __shared__ unsigned short Hh[32][302];
    __shared__ unsigned short Hl[32][302];
    const int tid = threadIdx.x;
    const int lane = tid & 63, wave = tid >> 6;
    const int r31 = lane & 31, g = lane >> 5;
    const int rowbase = blockIdx.x * 32;
    for (int s = tid; s < 32 * 32; s += 256) {
        int r = s >> 5, c8 = (s & 31) << 3;
        *(short8*)&Hh[r][c8] = *(const short8*)&fphi[(size_t)(rowbase + r) * 256 + c8];
        *(short8*)&Hl[r][c8] = *(const short8*)&fplo[(size_t)(rowbase + r) * 256 + c8];
    }
    for (int s = tid; s < 32 * 32; s += 256) {
        int r = s >> 5, d = s & 31;
        float v = (d < 27) ? x[(size_t)(rowbase + r) * 90 + 63 + d] : 0.f;
        unsigned short h = bf16rne(v);
        Hh[r][256 + d] = h;
        Hl[r][256 + d] = bf16rne(v - bf2f(h));
    }
    __syncthreads();
    const int ct0 = wave * 2;
    f32x16 acc0, acc1;
    #pragma unroll
    for (int r = 0; r < 16; r++) { acc0[r] = 0.f; acc1[r] = 0.f; }
    const unsigned short* wp0 = wf + (size_t)ct0 * 18 * 1024 + lane * 8;
    const unsigned short* wp1 = wp0 + (size_t)18 * 1024;
    #pragma unroll
    for (int kc = 0; kc < 18; kc++) {
        short8 ah = *(const short8*)&Hh[r31][kc * 16 + g * 8];
        short8 al = *(const short8*)&Hl[r31][kc * 16 + g * 8];
        short8 b0h = *(const short8*)(wp0 + kc * 1024);
        short8 b0l = *(const short8*)(wp0 + kc * 1024 + 512);
        short8 b1h = *(const short8*)(wp1 + kc * 1024);
        short8 b1l = *(const short8*)(wp1 + kc * 1024 + 512);
        acc0 = __builtin_amdgcn_mfma_f32_32x32x16_bf16(ah, b0h, acc0, 0, 0, 0);
        acc1 = __builtin_amdgcn_mfma_f32_32x32x16_bf16(ah, b1h, acc1, 0, 0, 0);
        acc0 = __builtin_amdgcn_mfma_f32_32x32x16_bf16(al, b0h, acc0, 0, 0, 0);
        acc1 = __builtin_amdgcn_mfma_f32_32x32x16_bf16(al, b1h, acc1, 0, 0, 0);
        acc0 = __builtin_amdgcn_mfma_f32_32x32x16_bf16(ah, b0l, acc0, 0, 0, 0);
        acc1 = __builtin_amdgcn_mfma_f32_32x32x16_bf16(ah, b1l, acc1, 0, 0, 0);
    }
    #pragma unroll
    for (int r = 0; r < 16; r++) {
        int row = (r & 3) + 8 * (r >> 2) + 4 * g;
        PQ[(size_t)(rowbase + row) * 256 + ct0 * 32 + r31] = acc0[r];
        PQ[(size_t)(rowbase + row) * 256 + ct0 * 32 + 32 + r31] = acc1[r];
    }
}

// ---------------- PQ2: d1(128 fp32) -> 256 cols, MFMA ----------------
__global__ __launch_bounds__(256, 4) void k_pq2_mfma(
    const float* __restrict__ d1, const unsigned short* __restrict__ wf,
    float* __restrict__ PQ)
{
    __shared__ unsigned short Hh[32][134];
    __shared__ unsigned short Hl[32][134];
    const int tid = threadIdx.x;
    const int lane = tid & 63, wave = tid >> 6;
    const int r31 = lane & 31, g = lane >> 5;
    const int rowbase = blockIdx.x * 32;
    for (int s = tid; s < 32 * 128; s += 256) {
        int r = s >> 7, c = s & 127;
        float v = d1[(size_t)(rowbase + r) * 128 + c];
        unsigned short h = bf16rne(v);
        Hh[r][c] = h;
        Hl[r][c] = bf16rne(v - bf2f(h));
    }
    __syncthreads();
    const int ct0 = wave * 2;
    f32x16 acc0, acc1;
    #pragma unroll
    for (int r = 0; r < 16; r++) { acc0[r] = 0.f; acc1[r] = 0.f; }
    const unsigned short* wp0 = wf + (size_t)ct0 * 8 * 1024 + lane * 8;
    const unsigned short* wp1 = wp0 + (size_t)8 * 1024;
    #pragma unroll
    for (int kc = 0; kc < 8; kc++) {
        short8 ah = *(const short8*)&Hh[r31][kc * 16 + g * 8];
        short8 al = *(const short8*)&Hl[r31][kc * 16 + g * 8];
        short8 b0h = *(const short8*)(wp0 + kc * 1024);
        short8 b0l = *(const short8*)(wp0 + kc * 1024 + 512);
        short8 b1h = *(const short8*)(wp1 + kc * 1024);
        short8 b1l = *(const short8*)(wp1 + kc * 1024 + 512);
        acc0 = __builtin_amdgcn_mfma_f32_32x32x16_bf16(ah, b0h, acc0, 0, 0, 0);
        acc1 = __builtin_amdgcn_mfma_f32_32x32x16_bf16(ah, b1h, acc1, 0, 0, 0);
        acc0 = __builtin_amdgcn_mfma_f32_32x32x16_bf16(al, b0h, acc0, 0, 0, 0);
        acc1 = __builtin_amdgcn_mfma_f32_32x32x16_bf16(al, b1h, acc1, 0, 0, 0);
        acc0 = __builtin_amdgcn_mfma_f32_32x32x16_bf16(ah, b0l, acc0, 0, 0, 0);
        acc1 = __builtin_amdgcn_mfma_f32_32x32x16_bf16(ah, b1l, acc1, 0, 0, 0);
    }
    #pragma unroll
    for (int r = 0; r < 16; r++) {
        int row = (r & 3) + 8 * (r >> 2) + 4 * g;
        PQ[(size_t)(rowbase + row) * 256 + ct0 * 32 + r31] = acc0[r];
        PQ[(size_t)(rowbase + row) * 256 + ct0 * 32 + 32 + r31] = acc1[r];
    }
}

// ---------------- edge conv (unchanged fp32) ----------------
template<int RGB>
__global__ __launch_bounds__(256) void k_edge(const float* __restrict__ PQ,
    const float* __restrict__ b1, const float* __restrict__ w2,
    const float* __restrict__ b2, const int* __restrict__ nbr,
    float* __restrict__ dout,
    const float* __restrict__ wrgb, const float* __restrict__ brgb,
    float* __restrict__ out)
{
    __shared__ float h1T[128][97];
    __shared__ float wb[32][128];
    const int tid = threadIdx.x;
    const int n0 = blockIdx.x * 32;
    {
        const int c = tid & 127, eg = tid >> 7;
        const float bias = b1[c];
        for (int e = eg; e < 96; e += 2) {
            int n = e / 3;
            int jj = e - n * 3;
            int i = n0 + n;
            int j = nbr[(size_t)i * 3 + jj];
            float v = PQ[(size_t)i * 256 + c] + bias
                    + PQ[(size_t)j * 256 + 128 + c] - PQ[(size_t)i * 256 + 128 + c];
            h1T[c][e] = fmaxf(v, 0.f);
        }
    }
    const int cg = tid & 15, rg = tid >> 4;
    const int cLo = cg * 4, cHi = 64 + cg * 4, e0 = rg * 6;
    float acc[6][8];
    #pragma unroll
    for (int m = 0; m < 6; m++)
        #pragma unroll
        for (int j = 0; j < 8; j++) acc[m][j] = 0.f;
    for (int k0 = 0; k0 < 128; k0 += 32) {
        __syncthreads();
        for (int s = tid; s < 32 * 128; s += 256) {
            int kk = s >> 7, c = s & 127;
            wb[kk][c] = w2[(size_t)(k0 + kk) * 128 + c];
        }
        __syncthreads();
        for (int kk = 0; kk < 32; kk++) {
            const int k = k0 + kk;
            float av[6];
            #pragma unroll
            for (int m = 0; m < 6; m++) av[m] = h1T[k][e0 + m];
            float4 w0v = *(const float4*)&wb[kk][cLo];
            float4 w1v = *(const float4*)&wb[kk][cHi];
            float bv[8] = {w0v.x,w0v.y,w0v.z,w0v.w,w1v.x,w1v.y,w1v.z,w1v.w};
            #pragma unroll
            for (int m = 0; m < 6; m++)
                #pragma unroll
                for (int j = 0; j < 8; j++)
                    acc[m][j] = fmaf(av[m], bv[j], acc[m][j]);
        }
    }
    float bb[8];
    #pragma unroll
    for (int j = 0; j < 8; j++) bb[j] = b2[(j < 4) ? (cLo + j) : (cHi + j - 4)];
    float dA[8], dB[8];
    #pragma unroll
    for (int j = 0; j < 8; j++) {
        float h0 = fmaxf(acc[0][j] + bb[j], 0.f);
        float h1 = fmaxf(acc[1][j] + bb[j], 0.f);
        float h2 = fmaxf(acc[2][j] + bb[j], 0.f);
        float h3 = fmaxf(acc[3][j] + bb[j], 0.f);
        float h4 = fmaxf(acc[4][j] + bb[j], 0.f);
        float h5 = fmaxf(acc[5][j] + bb[j], 0.f);
        dA[j] = (h0 + h1 + h2) * (1.f / 3.f);
        dB[j] = (h3 + h4 + h5) * (1.f / 3.f);
    }
    if (!RGB) {
        *(float4*)&dout[(size_t)(n0 + 2*rg) * 128 + cLo] = make_float4(dA[0], dA[1], dA[2], dA[3]);
        *(float4*)&dout[(size_t)(n0 + 2*rg) * 128 + cHi] = make_float4(dA[4], dA[5], dA[6], dA[7]);
        *(float4*)&dout[(size_t)(n0 + 2*rg + 1) * 128 + cLo] = make_float4(dB[0], dB[1], dB[2], dB[3]);
        *(float4*)&dout[(size_t)(n0 + 2*rg + 1) * 128 + cHi] = make_float4(dB[4], dB[5], dB[6], dB[7]);
    } else {
        __syncthreads();
        float* d2L = &h1T[0][0];
        #pragma unroll
        for (int j = 0; j < 4; j++) {
            d2L[(2*rg)     * 130 + cLo + j] = dA[j];
            d2L[(2*rg)     * 130 + cHi + j] = dA[j + 4];
            d2L[(2*rg + 1) * 130 + cLo + j] = dB[j];
            d2L[(2*rg + 1) * 130 + cHi + j] = dB[j + 4];
        }
        __syncthreads();
        if (tid < 96) {
            int n = tid / 3, ch = tid - 3 * (tid / 3);
            float s = brgb[ch];
            for (int k = 0; k < 128; k++) s = fmaf(d2L[n * 130 + k], wrgb[k * 3 + ch], s);
            out[(size_t)(n0 + n) * 4 + ch] = 1.f / (1.f + expf(-s));
        }
    }
}

// ---------------- launch ----------------
extern "C" void kernel_launch(void* const* d_in, const int* in_sizes, int n_in,
                              void* d_out, int out_size, void* d_ws, size_t ws_size,
                              hipStream_t stream)
{
    const float* x     = (const float*)d_in[0];
    const int*   bid   = (const int*)d_in[1];
    const float* w0    = (const float*)d_in[2];
    const float* b0    = (const float*)d_in[3];
    const float* wmid  = (const float*)d_in[4];
    const float* bmid  = (const float*)d_in[5];
    const float* wskip = (const float*)d_in[6];
    const float* bskip = (const float*)d_in[7];
    const float* wfin  = (const float*)d_in[8];
    const float* bfin  = (const float*)d_in[9];
    const float* wsig  = (const float*)d_in[10];
    const float* bsig  = (const float*)d_in[11];
    const float* e1w1  = (const float*)d_in[12];
    const float* e1b1  = (const float*)d_in[13];
    const float* e1w2  = (const float*)d_in[14];
    const float* e1b2  = (const float*)d_in[15];
    const float* e2w1  = (const float*)d_in[16];
    const float* e2b1  = (const float*)d_in[17];
    const float* e2w2  = (const float*)d_in[18];
    const float* e2b2  = (const float*)d_in[19];
    const float* wrgb  = (const float*)d_in[20];
    const float* brgb  = (const float*)d_in[21];
    float* out = (float*)d_out;

    char* ws = (char*)d_ws;
    int* cnt = (int*)ws;                                        // 256 B
    int* grp = (int*)(ws + 256);                                // 160 KB
    int* nbr = (int*)(ws + 164096);                             // 480 KB -> ends 655616
    unsigned short* wfpq1 = (unsigned short*)(ws + 655616);     // 288 KB
    unsigned short* wfpq2 = (unsigned short*)(ws + 950528);     // 128 KB
    float* bufA = (float*)(ws + (2 << 20));                     // 42 MB
    float* bufB = bufA + (size_t)B_TOTAL * 256;                 // 42 MB

    // kNN overlays on bufA (dead before trunk writes fphi/fplo there):
    unsigned short* xbh = (unsigned short*)bufA;
    unsigned short* xbl = xbh + (size_t)B_TOTAL * 64;
    float* cn   = (float*)(xbl + (size_t)B_TOTAL * 64);
    unsigned long long* pkey = (unsigned long long*)(cn + B_TOTAL);
    // trunk outputs / edge intermediates:
    unsigned short* fphi = (unsigned short*)bufA;               // 21 MB
    unsigned short* fplo = fphi + (size_t)B_TOTAL * 256;        // 21 MB
    float* d1 = (float*)bufA;                                   // 21 MB (after pq1 consumed fphi/fplo)
    float* PQ = bufB;                                           // 42 MB
    unsigned short* wfrag = (unsigned short*)((char*)bufB + ((size_t)39 << 20));  // dead before PQ written

    hipMemsetAsync(cnt, 0, 256, stream);
    k_scatter<<<B_TOTAL / 256, 256, 0, stream>>>(bid, grp, cnt);
    k_wprep<<<(557056 + 255) / 256, 256, 0, stream>>>(w0, wmid, wskip, wfin, wfrag);
    k_wprep_pq<<<(18 * 8 * 512 + 255) / 256, 256, 0, stream>>>(e1w1, 283, 18, wfpq1);
    k_wprep_pq<<<(8 * 8 * 512 + 255) / 256, 256, 0, stream>>>(e2w1, 128, 8, wfpq2);
    k_gather<<<dim3(GSZ / 128, NGRP), 256, 0, stream>>>(x, grp, xbh, xbl, cn);
    k_knn_mfma<<<dim3(GSZ / 64, CPART, NGRP), 256, 0, stream>>>(xbh, xbl, cn, pkey);
    k_knn_merge<<<(NGRP * GSZ + 255) / 256, 256, 0, stream>>>(pkey, grp, nbr);
    k_trunk_mfma<<<B_TOTAL / 64, 512, 0, stream>>>(x, wfrag, b0, bmid, bskip, bfin,
                                                   wsig, bsig, fphi, fplo, out);
    k_pq1_mfma<<<B_TOTAL / 32, 256, 0, stream>>>(fphi, fplo, x, wfpq1, PQ);
    k_edge<0><<<B_TOTAL / 32, 256, 0, stream>>>(PQ, e1b1, e1w2, e1b2, nbr, d1,
                                                nullptr, nullptr, nullptr);
    k_pq2_mfma<<<B_TOTAL / 32, 256, 0, stream>>>(d1, wfpq2, PQ);
    k_edge<1><<<B_TOTAL / 32, 256, 0, stream>>>(PQ, e2b1, e2w2, e2b2, nbr, nullptr,
                                                wrgb, brgb, out);
}

// Round 12
// 524.468 us; speedup vs baseline: 2.3713x; 1.1634x over previous
//
#include <hip/hip_runtime.h>
#include <hip/hip_bf16.h>
#include <math.h>

#define B_TOTAL 40960
#define NGRP 20
#define GSZ 2048
#define CPART 4

typedef short short8 __attribute__((ext_vector_type(8)));
typedef short short4v __attribute__((ext_vector_type(4)));
typedef float f32x4 __attribute__((ext_vector_type(4)));
typedef float f32x16 __attribute__((ext_vector_type(16)));

// ---------------- group scatter ----------------
__global__ void k_scatter(const int* __restrict__ bid, int* __restrict__ grp,
                          int* __restrict__ cnt)
{
    int i = blockIdx.x * 256 + threadIdx.x;
    if (i < B_TOTAL) {
        int g = bid[i];
        int p = atomicAdd(&cnt[g], 1);
        grp[g * GSZ + p] = i;
    }
}

// ---------------- bf16 helpers ----------------
__device__ __forceinline__ unsigned short bf16rne(float v)
{
    unsigned int u = __float_as_uint(v);
    unsigned int r = (u + 0x7FFFu + ((u >> 16) & 1u)) >> 16;
    return (unsigned short)r;
}

__device__ __forceinline__ float bf2f(unsigned short h)
{
    return __uint_as_float((unsigned int)h << 16);
}

__device__ __forceinline__ void splitbf16(const float* v, short8& hi, short8& lo)
{
    #pragma unroll
    for (int j = 0; j < 8; j++) {
        unsigned short h = bf16rne(v[j]);
        hi[j] = (short)h;
        lo[j] = (short)bf16rne(v[j] - bf2f(h));
    }
}

// ordered-float key: monotonic unsigned encoding of float
__device__ __forceinline__ unsigned int fkey(float f)
{
    unsigned int u = __float_as_uint(f);
    unsigned int m = (unsigned int)((int)u >> 31) | 0x80000000u;
    return u ^ m;
}

// branch-free sorted insert of (k,i) into ((k0,i0) <= (k1,i1) <= (k2,i2))
__device__ __forceinline__ void ins3p(unsigned int k, unsigned int i,
    unsigned int& k0, unsigned int& i0, unsigned int& k1, unsigned int& i1,
    unsigned int& k2, unsigned int& i2)
{
    bool c0 = k < k0;
    unsigned int tk = c0 ? k0 : k, ti = c0 ? i0 : i;
    k0 = c0 ? k : k0;  i0 = c0 ? i : i0;
    bool c1 = tk < k1;
    unsigned int sk = c1 ? k1 : tk, si = c1 ? i1 : ti;
    k1 = c1 ? tk : k1; i1 = c1 ? ti : i1;
    bool c2 = sk < k2;
    k2 = c2 ? sk : k2; i2 = c2 ? si : i2;
}

__device__ __forceinline__ void mergerow(unsigned int& k0, unsigned int& i0,
    unsigned int& k1, unsigned int& i1, unsigned int& k2, unsigned int& i2)
{
    #pragma unroll
    for (int m = 1; m <= 8; m <<= 1) {
        unsigned int ok0 = (unsigned int)__shfl_xor((int)k0, m);
        unsigned int oi0 = (unsigned int)__shfl_xor((int)i0, m);
        unsigned int ok1 = (unsigned int)__shfl_xor((int)k1, m);
        unsigned int oi1 = (unsigned int)__shfl_xor((int)i1, m);
        unsigned int ok2 = (unsigned int)__shfl_xor((int)k2, m);
        unsigned int oi2 = (unsigned int)__shfl_xor((int)i2, m);
        ins3p(ok0, oi0, k0, i0, k1, i1, k2, i2);
        ins3p(ok1, oi1, k0, i0, k1, i1, k2, i2);
        ins3p(ok2, oi2, k0, i0, k1, i1, k2, i2);
    }
}

// ---------------- kNN stage 1: gather -> packed bf16 hi/lo planes + norms ----------------
__global__ __launch_bounds__(256) void k_gather(const float* __restrict__ x,
    const int* __restrict__ grp, unsigned short* __restrict__ xbh,
    unsigned short* __restrict__ xbl, float* __restrict__ cn)
{
    __shared__ float tile[128][65];
    __shared__ int ids[128];
    const int tid = threadIdx.x;
    const int g = blockIdx.y;
    const int q0 = blockIdx.x * 128;
    if (tid < 128) ids[tid] = grp[g * GSZ + q0 + tid];
    __syncthreads();
    for (int s = tid; s < 128 * 64; s += 256) {
        int q = s >> 6, d = s & 63;
        tile[q][d] = (d < 63) ? x[(size_t)ids[q] * 90 + d] : 0.f;
    }
    __syncthreads();
    if (tid < 128) {
        float a = 0.f;
        #pragma unroll
        for (int d = 0; d < 63; d++) a = fmaf(tile[tid][d], tile[tid][d], a);
        cn[g * GSZ + q0 + tid] = a;
    }
    for (int s = tid; s < 128 * 32; s += 256) {
        int q = s >> 5, dp = (s & 31) << 1;
        float v0 = tile[q][dp], v1 = tile[q][dp + 1];
        unsigned short h0 = bf16rne(v0), h1 = bf16rne(v1);
        unsigned short l0 = bf16rne(v0 - bf2f(h0)), l1 = bf16rne(v1 - bf2f(h1));
        size_t pt = (size_t)g * GSZ + q0 + q;
        ((unsigned int*)xbh)[pt * 32 + (dp >> 1)] = (unsigned int)h0 | ((unsigned int)h1 << 16);
        ((unsigned int*)xbl)[pt * 32 + (dp >> 1)] = (unsigned int)l0 | ((unsigned int)l1 << 16);
    }
}

// ---------------- kNN stage 2: MFMA distance tiles, LDS-shared stream, branch-free top3 ----------------
__global__ __launch_bounds__(256) void k_knn_mfma(const unsigned short* __restrict__ xbh,
    const unsigned short* __restrict__ xbl, const float* __restrict__ cn,
    unsigned long long* __restrict__ pkey)
{
    __shared__ char cbuf[2][16384];
    const int tid = threadIdx.x;
    const int lane = tid & 63;
    const int wave = tid >> 6;
    const int g = blockIdx.z;
    const int part = blockIdx.y;
    const int qt0 = blockIdx.x * 64 + wave * 16;
    const size_t gbase = (size_t)g * GSZ;
    const int lp = lane & 15;
    const int kgrp = lane >> 4;
    const int kg = kgrp << 3;

    const size_t qb = (gbase + qt0 + lp) * 64;
    short8 ah0 = *(const short8*)(xbh + qb + kg);
    short8 ah1 = *(const short8*)(xbh + qb + 32 + kg);
    short8 al0 = *(const short8*)(xbl + qb + kg);
    short8 al1 = *(const short8*)(xbl + qb + 32 + kg);

    const int qp0 = qt0 + (kgrp << 2);

    unsigned int K00 = ~0u, I00 = 0, K01 = ~0u, I01 = 0, K02 = ~0u, I02 = 0;
    unsigned int K10 = ~0u, I10 = 0, K11 = ~0u, I11 = 0, K12 = ~0u, I12 = 0;
    unsigned int K20 = ~0u, I20 = 0, K21 = ~0u, I21 = 0, K22 = ~0u, I22 = 0;
    unsigned int K30 = ~0u, I30 = 0, K31 = ~0u, I31 = 0, K32 = ~0u, I32 = 0;

    const int scand = tid & 63;
    const int cbeg = part * (GSZ / CPART);
    const int s0 = wave, s1 = 4 + wave, s2 = 8 + wave, s3 = 12 + wave;
    const unsigned short* pl0 = (s0 < 8) ? xbh : xbl;
    const unsigned short* pl1 = (s1 < 8) ? xbh : xbl;
    const unsigned short* pl2 = (s2 < 8) ? xbh : xbl;
    const unsigned short* pl3 = (s3 < 8) ? xbh : xbl;

    short8 st0, st1, st2, st3;
    {
        size_t cb = (gbase + cbeg + scand) * 64;
        st0 = *(const short8*)(pl0 + cb + (s0 & 7) * 8);
        st1 = *(const short8*)(pl1 + cb + (s1 & 7) * 8);
        st2 = *(const short8*)(pl2 + cb + (s2 & 7) * 8);
        st3 = *(const short8*)(pl3 + cb + (s3 & 7) * 8);
    }
    *(short8*)&cbuf[0][(s0 << 10) + (scand << 4)] = st0;
    *(short8*)&cbuf[0][(s1 << 10) + (scand << 4)] = st1;
    *(short8*)&cbuf[0][(s2 << 10) + (scand << 4)] = st2;
    *(short8*)&cbuf[0][(s3 << 10) + (scand << 4)] = st3;

    for (int ch = 0; ch < 8; ch++) {
        const int cur = ch & 1;
        __syncthreads();
        if (ch < 7) {
            size_t cb = (gbase + cbeg + (ch + 1) * 64 + scand) * 64;
            st0 = *(const short8*)(pl0 + cb + (s0 & 7) * 8);
            st1 = *(const short8*)(pl1 + cb + (s1 & 7) * 8);
            st2 = *(const short8*)(pl2 + cb + (s2 & 7) * 8);
            st3 = *(const short8*)(pl3 + cb + (s3 & 7) * 8);
        }
        const int cc0 = cbeg + ch * 64;
        #pragma unroll
        for (int ct = 0; ct < 4; ct++) {
            const int coff = ((ct * 16 + lp) << 4);
            short8 bh0 = *(const short8*)&cbuf[cur][((kgrp)      << 10) + coff];
            short8 bh1 = *(const short8*)&cbuf[cur][((4 + kgrp)  << 10) + coff];
            short8 bl0 = *(const short8*)&cbuf[cur][((8 + kgrp)  << 10) + coff];
            short8 bl1 = *(const short8*)&cbuf[cur][((12 + kgrp) << 10) + coff];
            f32x4 acc = {0.f, 0.f, 0.f, 0.f};
            acc = __builtin_amdgcn_mfma_f32_16x16x32_bf16(ah0, bh0, acc, 0, 0, 0);
            acc = __builtin_amdgcn_mfma_f32_16x16x32_bf16(ah1, bh1, acc, 0, 0, 0);
            acc = __builtin_amdgcn_mfma_f32_16x16x32_bf16(al0, bh0, acc, 0, 0, 0);
            acc = __builtin_amdgcn_mfma_f32_16x16x32_bf16(al1, bh1, acc, 0, 0, 0);
            acc = __builtin_amdgcn_mfma_f32_16x16x32_bf16(ah0, bl0, acc, 0, 0, 0);
            acc = __builtin_amdgcn_mfma_f32_16x16x32_bf16(ah1, bl1, acc, 0, 0, 0);
            const float cnv = cn[gbase + cc0 + ct * 16 + lp];
            const int cpos = cc0 + ct * 16 + lp;
            const unsigned int ci = (unsigned int)cpos;
            {
                unsigned int k = fkey(fmaf(-2.f, acc[0], cnv));
                k = (cpos == qp0 + 0) ? 0xFFFFFFFFu : k;
                ins3p(k, ci, K00, I00, K01, I01, K02, I02);
            }
            {
                unsigned int k = fkey(fmaf(-2.f, acc[1], cnv));
                k = (cpos == qp0 + 1) ? 0xFFFFFFFFu : k;
                ins3p(k, ci, K10, I10, K11, I11, K12, I12);
            }
            {
                unsigned int k = fkey(fmaf(-2.f, acc[2], cnv));
                k = (cpos == qp0 + 2) ? 0xFFFFFFFFu : k;
                ins3p(k, ci, K20, I20, K21, I21, K22, I22);
            }
            {
                unsigned int k = fkey(fmaf(-2.f, acc[3], cnv));
                k = (cpos == qp0 + 3) ? 0xFFFFFFFFu : k;
                ins3p(k, ci, K30, I30, K31, I31, K32, I32);
            }
        }
        if (ch < 7) {
            *(short8*)&cbuf[cur ^ 1][(s0 << 10) + (scand << 4)] = st0;
            *(short8*)&cbuf[cur ^ 1][(s1 << 10) + (scand << 4)] = st1;
            *(short8*)&cbuf[cur ^ 1][(s2 << 10) + (scand << 4)] = st2;
            *(short8*)&cbuf[cur ^ 1][(s3 << 10) + (scand << 4)] = st3;
        }
    }

    mergerow(K00, I00, K01, I01, K02, I02);
    mergerow(K10, I10, K11, I11, K12, I12);
    mergerow(K20, I20, K21, I21, K22, I22);
    mergerow(K30, I30, K31, I31, K32, I32);

    if (lp == 0) {
        size_t ob = (gbase + (size_t)qp0) * (CPART * 3) + part * 3;
        pkey[ob + 0]  = ((unsigned long long)K00 << 32) | I00;
        pkey[ob + 1]  = ((unsigned long long)K01 << 32) | I01;
        pkey[ob + 2]  = ((unsigned long long)K02 << 32) | I02;
        pkey[ob + 12] = ((unsigned long long)K10 << 32) | I10;
        pkey[ob + 13] = ((unsigned long long)K11 << 32) | I11;
        pkey[ob + 14] = ((unsigned long long)K12 << 32) | I12;
        pkey[ob + 24] = ((unsigned long long)K20 << 32) | I20;
        pkey[ob + 25] = ((unsigned long long)K21 << 32) | I21;
        pkey[ob + 26] = ((unsigned long long)K22 << 32) | I22;
        pkey[ob + 36] = ((unsigned long long)K30 << 32) | I30;
        pkey[ob + 37] = ((unsigned long long)K31 << 32) | I31;
        pkey[ob + 38] = ((unsigned long long)K32 << 32) | I32;
    }
}

// ---------------- kNN stage 3: merge CPART partials from u64 keys ----------------
__device__ __forceinline__ void ins3u(unsigned long long k,
    unsigned long long& k0, unsigned long long& k1, unsigned long long& k2)
{
    if (k < k0)      { k2 = k1; k1 = k0; k0 = k; }
    else if (k < k1) { k2 = k1; k1 = k; }
    else if (k < k2) { k2 = k; }
}

__global__ void k_knn_merge(const unsigned long long* __restrict__ pkey,
                            const int* __restrict__ grp, int* __restrict__ nbr)
{
    int t = blockIdx.x * 256 + threadIdx.x;
    if (t >= NGRP * GSZ) return;
    int g = t >> 11;
    unsigned long long k0 = ~0ull, k1 = ~0ull, k2 = ~0ull;
    const unsigned long long* pk = pkey + (size_t)t * (CPART * 3);
    #pragma unroll
    for (int r = 0; r < CPART * 3; r++) ins3u(pk[r], k0, k1, k2);
    int qi = grp[t];
    nbr[(size_t)qi * 3 + 0] = grp[(g << 11) + (int)(k0 & 0xFFFFFFFFull)];
    nbr[(size_t)qi * 3 + 1] = grp[(g << 11) + (int)(k1 & 0xFFFFFFFFull)];
    nbr[(size_t)qi * 3 + 2] = grp[(g << 11) + (int)(k2 & 0xFFFFFFFFull)];
}

// ---------------- trunk weight prep: split-bf16, fragment-major ----------------
__global__ void k_wprep(const float* __restrict__ w0, const float* __restrict__ wmid,
                        const float* __restrict__ wskip, const float* __restrict__ wfin,
                        unsigned short* __restrict__ wfrag)
{
    int t = blockIdx.x * 256 + threadIdx.x;
    if (t >= 557056) return;
    const int CUMa[10] = {0,4,20,36,52,72,88,104,120,136};
    const int KCa[9]   = {4,16,16,16,20,16,16,16,16};
    int q = t >> 12;
    int L = 0;
    #pragma unroll
    for (int i = 0; i < 9; i++) if (q >= CUMa[i + 1]) L = i + 1;
    int cum = 0, kcn = 16;
    #pragma unroll
    for (int i = 0; i < 9; i++) if (L == i) { cum = CUMa[i]; kcn = KCa[i]; }
    int u = t - (cum << 12);
    int j = u & 7, lane = (u >> 3) & 63;
    int ckk = u >> 9;
    int kc = ckk % kcn, ct = ckk / kcn;
    int col = ct * 32 + (lane & 31);
    int k = kc * 16 + ((lane >> 5) << 3) + j;
    float w;
    if (L == 0)      w = (k < 63)  ? w0[k * 256 + col] : 0.f;
    else if (L == 4) w = (k < 256) ? wskip[(63 + k) * 256 + col]
                       : (k < 319) ? wskip[(k - 256) * 256 + col] : 0.f;
    else if (L == 8) w = wfin[k * 256 + col];
    else {
        int m = (L <= 3) ? (L - 1) : (L - 2);
        w = wmid[(size_t)m * 65536 + k * 256 + col];
    }
    unsigned short hi = bf16rne(w);
    unsigned short lo = bf16rne(w - bf2f(hi));
    size_t base = ((size_t)cum << 13) + (size_t)(ct * kcn + kc) * 1024 + lane * 8 + j;
    wfrag[base] = hi;
    wfrag[base + 512] = lo;
}

// ---------------- PQ weight prep: combined [K][256] (top|bottom), split-bf16 frag-major ----------------
__global__ void k_wprep_pq(const float* __restrict__ src, int K, int KCN,
                           unsigned short* __restrict__ dst)
{
    int t = blockIdx.x * 256 + threadIdx.x;
    if (t >= KCN * 8 * 512) return;
    int j = t & 7, lane = (t >> 3) & 63;
    int ckk = t >> 9;
    int kc = ckk % KCN, ct = ckk / KCN;
    int col = ct * 32 + (lane & 31);
    int k = kc * 16 + ((lane >> 5) << 3) + j;
    float w = 0.f;
    if (k < K) w = (col < 128) ? src[(size_t)k * 128 + col]
                               : src[(size_t)(K + k) * 128 + (col - 128)];
    unsigned short hi = bf16rne(w);
    unsigned short lo = bf16rne(w - bf2f(hi));
    size_t base = (size_t)(ct * KCN + kc) * 1024 + lane * 8 + j;
    dst[base] = hi;
    dst[base + 512] = lo;
}

// ---------------- square weight prep: [128][128], split-bf16 frag-major (4 ct, 8 kc) ----------------
__global__ void k_wprep_sq(const float* __restrict__ src, unsigned short* __restrict__ dst)
{
    int t = blockIdx.x * 256 + threadIdx.x;
    if (t >= 4 * 8 * 512) return;
    int j = t & 7, lane = (t >> 3) & 63;
    int ckk = t >> 9;
    int kc = ckk & 7, ct = ckk >> 3;
    int col = ct * 32 + (lane & 31);
    int k = kc * 16 + ((lane >> 5) << 3) + j;
    float w = src[(size_t)k * 128 + col];
    unsigned short hi = bf16rne(w);
    unsigned short lo = bf16rne(w - bf2f(hi));
    size_t base = (size_t)(ct * 8 + kc) * 1024 + lane * 8 + j;
    dst[base] = hi;
    dst[base + 512] = lo;
}

// ---------------- fused trunk MLP: 8 waves, 64-row tile, wave = 1 column-tile ----------------
template<int KCH, int KCX, int OUTMODE>
__device__ __forceinline__ void mlayer64(unsigned short (*Hh)[264], unsigned short (*Hl)[264],
    int rowbase, const float* __restrict__ x, const unsigned short* __restrict__ wl,
    const float* __restrict__ bias, unsigned short* __restrict__ gh,
    unsigned short* __restrict__ gl, int lane, int wave)
{
    const int r31 = lane & 31, g = lane >> 5;
    constexpr int KC = KCH + KCX;
    const int ct = wave;
    f32x16 acc0, acc1;
    #pragma unroll
    for (int r = 0; r < 16; r++) { acc0[r] = 0.f; acc1[r] = 0.f; }
    const unsigned short* wp = wl + (size_t)ct * KC * 1024 + lane * 8;
    #pragma unroll
    for (int kc = 0; kc < KCH; kc++) {
        short8 ah0 = *(const short8*)&Hh[r31][kc * 16 + g * 8];
        short8 al0 = *(const short8*)&Hl[r31][kc * 16 + g * 8];
        short8 ah1 = *(const short8*)&Hh[32 + r31][kc * 16 + g * 8];
        short8 al1 = *(const short8*)&Hl[32 + r31][kc * 16 + g * 8];
        short8 bh = *(const short8*)(wp + kc * 1024);
        short8 bl = *(const short8*)(wp + kc * 1024 + 512);
        acc0 = __builtin_amdgcn_mfma_f32_32x32x16_bf16(ah0, bh, acc0, 0, 0, 0);
        acc1 = __builtin_amdgcn_mfma_f32_32x32x16_bf16(ah1, bh, acc1, 0, 0, 0);
        acc0 = __builtin_amdgcn_mfma_f32_32x32x16_bf16(al0, bh, acc0, 0, 0, 0);
        acc1 = __builtin_amdgcn_mfma_f32_32x32x16_bf16(al1, bh, acc1, 0, 0, 0);
        acc0 = __builtin_amdgcn_mfma_f32_32x32x16_bf16(ah0, bl, acc0, 0, 0, 0);
        acc1 = __builtin_amdgcn_mfma_f32_32x32x16_bf16(ah1, bl, acc1, 0, 0, 0);
    }
    #pragma unroll
    for (int t = 0; t < KCX; t++) {
        const int kc = KCH + t;
        float v0[8], v1[8];
        #pragma unroll
        for (int j = 0; j < 8; j++) {
            int kx = t * 16 + g * 8 + j;
            v0[j] = (kx < 63) ? x[(size_t)(rowbase + r31) * 90 + kx] : 0.f;
            v1[j] = (kx < 63) ? x[(size_t)(rowbase + 32 + r31) * 90 + kx] : 0.f;
        }
        short8 xh0, xl0, xh1, xl1;
        splitbf16(v0, xh0, xl0);
        splitbf16(v1, xh1, xl1);
        short8 bh = *(const short8*)(wp + kc * 1024);
        short8 bl = *(const short8*)(wp + kc * 1024 + 512);
        acc0 = __builtin_amdgcn_mfma_f32_32x32x16_bf16(xh0, bh, acc0, 0, 0, 0);
        acc1 = __builtin_amdgcn_mfma_f32_32x32x16_bf16(xh1, bh, acc1, 0, 0, 0);
        acc0 = __builtin_amdgcn_mfma_f32_32x32x16_bf16(xl0, bh, acc0, 0, 0, 0);
        acc1 = __builtin_amdgcn_mfma_f32_32x32x16_bf16(xl1, bh, acc1, 0, 0, 0);
        acc0 = __builtin_amdgcn_mfma_f32_32x32x16_bf16(xh0, bl, acc0, 0, 0, 0);
        acc1 = __builtin_amdgcn_mfma_f32_32x32x16_bf16(xh1, bl, acc1, 0, 0, 0);
    }
    const float bv = bias[ct * 32 + r31];
    if (OUTMODE == 0) {
        __syncthreads();
        #pragma unroll
        for (int r = 0; r < 16; r++) {
            int row = (r & 3) + 8 * (r >> 2) + 4 * g;
            float v0 = fmaxf(acc0[r] + bv, 0.f);
            float v1 = fmaxf(acc1[r] + bv, 0.f);
            unsigned short h0 = bf16rne(v0), h1 = bf16rne(v1);
            Hh[row][ct * 32 + r31] = h0;
            Hl[row][ct * 32 + r31] = bf16rne(v0 - bf2f(h0));
            Hh[32 + row][ct * 32 + r31] = h1;
            Hl[32 + row][ct * 32 + r31] = bf16rne(v1 - bf2f(h1));
        }
        __syncthreads();
    } else {
        #pragma unroll
        for (int r = 0; r < 16; r++) {
            int row = (r & 3) + 8 * (r >> 2) + 4 * g;
            float v0 = acc0[r] + bv;
            float v1 = acc1[r] + bv;
            unsigned short h0 = bf16rne(v0), h1 = bf16rne(v1);
            size_t o0 = (size_t)(rowbase + row) * 256 + ct * 32 + r31;
            size_t o1 = (size_t)(rowbase + 32 + row) * 256 + ct * 32 + r31;
            gh[o0] = h0;
            gl[o0] = bf16rne(v0 - bf2f(h0));
            gh[o1] = h1;
            gl[o1] = bf16rne(v1 - bf2f(h1));
        }
    }
}

__global__ __launch_bounds__(512, 4) void k_trunk_mfma(const float* __restrict__ x,
    const unsigned short* __restrict__ wfrag,
    const float* __restrict__ b0, const float* __restrict__ bmid,
    const float* __restrict__ bskip, const float* __restrict__ bfin,
    const float* __restrict__ wsig, const float* __restrict__ bsig,
    unsigned short* __restrict__ fphi, unsigned short* __restrict__ fplo,
    float* __restrict__ out)
{
    __shared__ unsigned short Hh[64][264];
    __shared__ unsigned short Hl[64][264];
    const int lane = threadIdx.x & 63;
    const int wave = threadIdx.x >> 6;
    const int rowbase = blockIdx.x * 64;
    const unsigned short* W = wfrag;
    mlayer64<0, 4, 0>(Hh, Hl, rowbase, x, W + (size_t)0   * 8192, b0,          nullptr, nullptr, lane, wave);
    mlayer64<16,0, 0>(Hh, Hl, rowbase, x, W + (size_t)4   * 8192, bmid + 0,    nullptr, nullptr, lane, wave);
    mlayer64<16,0, 0>(Hh, Hl, rowbase, x, W + (size_t)20  * 8192, bmid + 256,  nullptr, nullptr, lane, wave);
    mlayer64<16,0, 0>(Hh, Hl, rowbase, x, W + (size_t)36  * 8192, bmid + 512,  nullptr, nullptr, lane, wave);
    mlayer64<16,4, 0>(Hh, Hl, rowbase, x, W + (size_t)52  * 8192, bskip,       nullptr, nullptr, lane, wave);
    mlayer64<16,0, 0>(Hh, Hl, rowbase, x, W + (size_t)72  * 8192, bmid + 768,  nullptr, nullptr, lane, wave);
    mlayer64<16,0, 0>(Hh, Hl, rowbase, x, W + (size_t)88  * 8192, bmid + 1024, nullptr, nullptr, lane, wave);
    mlayer64<16,0, 0>(Hh, Hl, rowbase, x, W + (size_t)104 * 8192, bmid + 1280, nullptr, nullptr, lane, wave);
    mlayer64<16,0, 1>(Hh, Hl, rowbase, x, W + (size_t)120 * 8192, bfin,        fphi,    fplo,    lane, wave);
    if (wave < 2) {
        const int r31 = lane & 31, g = lane >> 5;
        const int row = wave * 32 + r31;
        float s = 0.f;
        #pragma unroll
        for (int kk = 0; kk < 32; kk++) {
            short4v hh = *(const short4v*)&Hh[row][g * 128 + kk * 4];
            short4v hl = *(const short4v*)&Hl[row][g * 128 + kk * 4];
            float4 wv = *(const float4*)&wsig[g * 128 + kk * 4];
            s = fmaf(bf2f((unsigned short)hh[0]) + bf2f((unsigned short)hl[0]), wv.x, s);
            s = fmaf(bf2f((unsigned short)hh[1]) + bf2f((unsigned short)hl[1]), wv.y, s);
            s = fmaf(bf2f((unsigned short)hh[2]) + bf2f((unsigned short)hl[2]), wv.z, s);
            s = fmaf(bf2f((unsigned short)hh[3]) + bf2f((unsigned short)hl[3]), wv.w, s);
        }
        s += __shfl_xor(s, 32);
        if (lane < 32) out[(size_t)(rowbase + row) * 4 + 3] = s + bsig[0];
    }
}

// ---------------- PQ1: [feat(256 bf16 planes), dir(27)] x 288 -> 256 cols, MFMA ----------------
__global__ __launch_bounds__(256, 4) void k_pq1_mfma(
    const unsigned short* __restrict__ fphi, const unsigned short* __restrict__ fplo,
    const float* __restrict__ x, const unsigned short* __restrict__ wf,
    float* __restrict__ PQ)
{
    __shared__ unsigned short Hh[32][302];
    __shared__ unsigned short Hl[32][302];
    const int tid = threadIdx.x;
    const int lane = tid & 63, wave = tid >> 6;
    const int r31 = lane & 31, g = lane >> 5;
    const int rowbase = blockIdx.x * 32;
    for (int s = tid; s < 32 * 32; s += 256) {
        int r = s >> 5, c8 = (s & 31) << 3;
        *(short8*)&Hh[r][c8] = *(const short8*)&fphi[(size_t)(rowbase + r) * 256 + c8];
        *(short8*)&Hl[r][c8] = *(const short8*)&fplo[(size_t)(rowbase + r) * 256 + c8];
    }
    for (int s = tid; s < 32 * 32; s += 256) {
        int r = s >> 5, d = s & 31;
        float v = (d < 27) ? x[(size_t)(rowbase + r) * 90 + 63 + d] : 0.f;
        unsigned short h = bf16rne(v);
        Hh[r][256 + d] = h;
        Hl[r][256 + d] = bf16rne(v - bf2f(h));
    }
    __syncthreads();
    const int ct0 = wave * 2;
    f32x16 acc0, acc1;
    #pragma unroll
    for (int r = 0; r < 16; r++) { acc0[r] = 0.f; acc1[r] = 0.f; }
    const unsigned short* wp0 = wf + (size_t)ct0 * 18 * 1024 + lane * 8;
    const unsigned short* wp1 = wp0 + (size_t)18 * 1024;
    #pragma unroll
    for (int kc = 0; kc < 18; kc++) {
        short8 ah = *(const short8*)&Hh[r31][kc * 16 + g * 8];
        short8 al = *(const short8*)&Hl[r31][kc * 16 + g * 8];
        short8 b0h = *(const short8*)(wp0 + kc * 1024);
        short8 b0l = *(const short8*)(wp0 + kc * 1024 + 512);
        short8 b1h = *(const short8*)(wp1 + kc * 1024);
        short8 b1l = *(const short8*)(wp1 + kc * 1024 + 512);
        acc0 = __builtin_amdgcn_mfma_f32_32x32x16_bf16(ah, b0h, acc0, 0, 0, 0);
        acc1 = __builtin_amdgcn_mfma_f32_32x32x16_bf16(ah, b1h, acc1, 0, 0, 0);
        acc0 = __builtin_amdgcn_mfma_f32_32x32x16_bf16(al, b0h, acc0, 0, 0, 0);
        acc1 = __builtin_amdgcn_mfma_f32_32x32x16_bf16(al, b1h, acc1, 0, 0, 0);
        acc0 = __builtin_amdgcn_mfma_f32_32x32x16_bf16(ah, b0l, acc0, 0, 0, 0);
        acc1 = __builtin_amdgcn_mfma_f32_32x32x16_bf16(ah, b1l, acc1, 0, 0, 0);
    }
    #pragma unroll
    for (int r = 0; r < 16; r++) {
        int row = (r & 3) + 8 * (r >> 2) + 4 * g;
        PQ[(size_t)(rowbase + row) * 256 + ct0 * 32 + r31] = acc0[r];
        PQ[(size_t)(rowbase + row) * 256 + ct0 * 32 + 32 + r31] = acc1[r];
    }
}

// ---------------- PQ2: d1(128 fp32) -> 256 cols, MFMA ----------------
__global__ __launch_bounds__(256, 4) void k_pq2_mfma(
    const float* __restrict__ d1, const unsigned short* __restrict__ wf,
    float* __restrict__ PQ)
{
    __shared__ unsigned short Hh[32][134];
    __shared__ unsigned short Hl[32][134];
    const int tid = threadIdx.x;
    const int lane = tid & 63, wave = tid >> 6;
    const int r31 = lane & 31, g = lane >> 5;
    const int rowbase = blockIdx.x * 32;
    for (int s = tid; s < 32 * 128; s += 256) {
        int r = s >> 7, c = s & 127;
        float v = d1[(size_t)(rowbase + r) * 128 + c];
        unsigned short h = bf16rne(v);
        Hh[r][c] = h;
        Hl[r][c] = bf16rne(v - bf2f(h));
    }
    __syncthreads();
    const int ct0 = wave * 2;
    f32x16 acc0, acc1;
    #pragma unroll
    for (int r = 0; r < 16; r++) { acc0[r] = 0.f; acc1[r] = 0.f; }
    const unsigned short* wp0 = wf + (size_t)ct0 * 8 * 1024 + lane * 8;
    const unsigned short* wp1 = wp0 + (size_t)8 * 1024;
    #pragma unroll
    for (int kc = 0; kc < 8; kc++) {
        short8 ah = *(const short8*)&Hh[r31][kc * 16 + g * 8];
        short8 al = *(const short8*)&Hl[r31][kc * 16 + g * 8];
        short8 b0h = *(const short8*)(wp0 + kc * 1024);
        short8 b0l = *(const short8*)(wp0 + kc * 1024 + 512);
        short8 b1h = *(const short8*)(wp1 + kc * 1024);
        short8 b1l = *(const short8*)(wp1 + kc * 1024 + 512);
        acc0 = __builtin_amdgcn_mfma_f32_32x32x16_bf16(ah, b0h, acc0, 0, 0, 0);
        acc1 = __builtin_amdgcn_mfma_f32_32x32x16_bf16(ah, b1h, acc1, 0, 0, 0);
        acc0 = __builtin_amdgcn_mfma_f32_32x32x16_bf16(al, b0h, acc0, 0, 0, 0);
        acc1 = __builtin_amdgcn_mfma_f32_32x32x16_bf16(al, b1h, acc1, 0, 0, 0);
        acc0 = __builtin_amdgcn_mfma_f32_32x32x16_bf16(ah, b0l, acc0, 0, 0, 0);
        acc1 = __builtin_amdgcn_mfma_f32_32x32x16_bf16(ah, b1l, acc1, 0, 0, 0);
    }
    #pragma unroll
    for (int r = 0; r < 16; r++) {
        int row = (r & 3) + 8 * (r >> 2) + 4 * g;
        PQ[(size_t)(rowbase + row) * 256 + ct0 * 32 + r31] = acc0[r];
        PQ[(size_t)(rowbase + row) * 256 + ct0 * 32 + 32 + r31] = acc1[r];
    }
}

// ---------------- edge conv via MFMA: 32 nodes, 4 padded edge rows/node ----------------
// rows 4n+{0,1,2} real edges, 4n+3 zero (discarded). Wave w owns column tile ct=w,
// accR[rt] covers edge rows rt*32..rt*32+31. Node mean = 3 register adds (same lane).
template<int RGB>
__global__ __launch_bounds__(256) void k_edge_mfma(const float* __restrict__ PQ,
    const float* __restrict__ b1, const unsigned short* __restrict__ wf2,
    const float* __restrict__ b2, const int* __restrict__ nbr,
    float* __restrict__ dout,
    const float* __restrict__ wrgb, const float* __restrict__ brgb,
    float* __restrict__ out)
{
    __shared__ unsigned short Hh[128][136];
    __shared__ unsigned short Hl[128][136];
    const int tid = threadIdx.x;
    const int lane = tid & 63, wave = tid >> 6;
    const int r31 = lane & 31, g = lane >> 5;
    const int n0 = blockIdx.x * 32;

    // build h1 = relu(P_i + Q_j - Q_i + b1) as split-bf16 planes; rows 4n+3 zeroed
    for (int s = tid; s < 128 * 32; s += 256) {
        int e = s >> 5, c4 = (s & 31) << 2;
        int n = e >> 2, jj = e & 3;
        short4v zh = {0, 0, 0, 0};
        if (jj < 3) {
            int i = n0 + n;
            int j = nbr[(size_t)i * 3 + jj];
            float4 p  = *(const float4*)&PQ[(size_t)i * 256 + c4];
            float4 qi = *(const float4*)&PQ[(size_t)i * 256 + 128 + c4];
            float4 qj = *(const float4*)&PQ[(size_t)j * 256 + 128 + c4];
            float4 bv = *(const float4*)&b1[c4];
            float v[4];
            v[0] = fmaxf(p.x + bv.x + qj.x - qi.x, 0.f);
            v[1] = fmaxf(p.y + bv.y + qj.y - qi.y, 0.f);
            v[2] = fmaxf(p.z + bv.z + qj.z - qi.z, 0.f);
            v[3] = fmaxf(p.w + bv.w + qj.w - qi.w, 0.f);
            short4v hh, hl;
            #pragma unroll
            for (int u = 0; u < 4; u++) {
                unsigned short h = bf16rne(v[u]);
                hh[u] = (short)h;
                hl[u] = (short)bf16rne(v[u] - bf2f(h));
            }
            *(short4v*)&Hh[e][c4] = hh;
            *(short4v*)&Hl[e][c4] = hl;
        } else {
            *(short4v*)&Hh[e][c4] = zh;
            *(short4v*)&Hl[e][c4] = zh;
        }
    }
    __syncthreads();

    const int ct = wave;
    f32x16 a0, a1, a2, a3;
    #pragma unroll
    for (int r = 0; r < 16; r++) { a0[r] = 0.f; a1[r] = 0.f; a2[r] = 0.f; a3[r] = 0.f; }
    const unsigned short* wp = wf2 + (size_t)ct * 8 * 1024 + lane * 8;
    #pragma unroll
    for (int kc = 0; kc < 8; kc++) {
        short8 bh = *(const short8*)(wp + kc * 1024);
        short8 bl = *(const short8*)(wp + kc * 1024 + 512);
        short8 h0 = *(const short8*)&Hh[r31][kc * 16 + g * 8];
        short8 l0 = *(const short8*)&Hl[r31][kc * 16 + g * 8];
        a0 = __builtin_amdgcn_mfma_f32_32x32x16_bf16(h0, bh, a0, 0, 0, 0);
        a0 = __builtin_amdgcn_mfma_f32_32x32x16_bf16(l0, bh, a0, 0, 0, 0);
        a0 = __builtin_amdgcn_mfma_f32_32x32x16_bf16(h0, bl, a0, 0, 0, 0);
        short8 h1 = *(const short8*)&Hh[32 + r31][kc * 16 + g * 8];
        short8 l1 = *(const short8*)&Hl[32 + r31][kc * 16 + g * 8];
        a1 = __builtin_amdgcn_mfma_f32_32x32x16_bf16(h1, bh, a1, 0, 0, 0);
        a1 = __builtin_amdgcn_mfma_f32_32x32x16_bf16(l1, bh, a1, 0, 0, 0);
        a1 = __builtin_amdgcn_mfma_f32_32x32x16_bf16(h1, bl, a1, 0, 0, 0);
        short8 h2 = *(const short8*)&Hh[64 + r31][kc * 16 + g * 8];
        short8 l2 = *(const short8*)&Hl[64 + r31][kc * 16 + g * 8];
        a2 = __builtin_amdgcn_mfma_f32_32x32x16_bf16(h2, bh, a2, 0, 0, 0);
        a2 = __builtin_amdgcn_mfma_f32_32x32x16_bf16(l2, bh, a2, 0, 0, 0);
        a2 = __builtin_amdgcn_mfma_f32_32x32x16_bf16(h2, bl, a2, 0, 0, 0);
        short8 h3 = *(const short8*)&Hh[96 + r31][kc * 16 + g * 8];
        short8 l3 = *(const short8*)&Hl[96 + r31][kc * 16 + g * 8];
        a3 = __builtin_amdgcn_mfma_f32_32x32x16_bf16(h3, bh, a3, 0, 0, 0);
        a3 = __builtin_amdgcn_mfma_f32_32x32x16_bf16(l3, bh, a3, 0, 0, 0);
        a3 = __builtin_amdgcn_mfma_f32_32x32x16_bf16(h3, bl, a3, 0, 0, 0);
    }
    const float bv = b2[ct * 32 + r31];
    const int col = ct * 32 + r31;

    if (!RGB) {
        #pragma unroll
        for (int q = 0; q < 4; q++) {
            float s0 = fmaxf(a0[4*q] + bv, 0.f) + fmaxf(a0[4*q+1] + bv, 0.f) + fmaxf(a0[4*q+2] + bv, 0.f);
            float s1 = fmaxf(a1[4*q] + bv, 0.f) + fmaxf(a1[4*q+1] + bv, 0.f) + fmaxf(a1[4*q+2] + bv, 0.f);
            float s2 = fmaxf(a2[4*q] + bv, 0.f) + fmaxf(a2[4*q+1] + bv, 0.f) + fmaxf(a2[4*q+2] + bv, 0.f);
            float s3 = fmaxf(a3[4*q] + bv, 0.f) + fmaxf(a3[4*q+1] + bv, 0.f) + fmaxf(a3[4*q+2] + bv, 0.f);
            int nq = 2 * q + g;
            dout[(size_t)(n0 + 0  + nq) * 128 + col] = s0 * (1.f / 3.f);
            dout[(size_t)(n0 + 8  + nq) * 128 + col] = s1 * (1.f / 3.f);
            dout[(size_t)(n0 + 16 + nq) * 128 + col] = s2 * (1.f / 3.f);
            dout[(size_t)(n0 + 24 + nq) * 128 + col] = s3 * (1.f / 3.f);
        }
    } else {
        __syncthreads();                         // all waves done reading Hh/Hl
        float* d2L = (float*)&Hh[0][0];          // [32][132] overlay
        #pragma unroll
        for (int q = 0; q < 4; q++) {
            float s0 = fmaxf(a0[4*q] + bv, 0.f) + fmaxf(a0[4*q+1] + bv, 0.f) + fmaxf(a0[4*q+2] + bv, 0.f);
            float s1 = fmaxf(a1[4*q] + bv, 0.f) + fmaxf(a1[4*q+1] + bv, 0.f) + fmaxf(a1[4*q+2] + bv, 0.f);
            float s2 = fmaxf(a2[4*q] + bv, 0.f) + fmaxf(a2[4*q+1] + bv, 0.f) + fmaxf(a2[4*q+2] + bv, 0.f);
            float s3 = fmaxf(a3[4*q] + bv, 0.f) + fmaxf(a3[4*q+1] + bv, 0.f) + fmaxf(a3[4*q+2] + bv, 0.f);
            int nq = 2 * q + g;
            d2L[(0  + nq) * 132 + col] = s0 * (1.f / 3.f);
            d2L[(8  + nq) * 132 + col] = s1 * (1.f / 3.f);
            d2L[(16 + nq) * 132 + col] = s2 * (1.f / 3.f);
            d2L[(24 + nq) * 132 + col] = s3 * (1.f / 3.f);
        }
        __syncthreads();
        if (tid < 96) {
            int n = tid / 3, ch = tid - 3 * (tid / 3);
            float s = brgb[ch];
            for (int k = 0; k < 128; k++) s = fmaf(d2L[n * 132 + k], wrgb[k * 3 + ch], s);
            out[(size_t)(n0 + n) * 4 + ch] = 1.f / (1.f + expf(-s));
        }
    }
}

// ---------------- launch ----------------
extern "C" void kernel_launch(void* const* d_in, const int* in_sizes, int n_in,
                              void* d_out, int out_size, void* d_ws, size_t ws_size,
                              hipStream_t stream)
{
    const float* x     = (const float*)d_in[0];
    const int*   bid   = (const int*)d_in[1];
    const float* w0    = (const float*)d_in[2];
    const float* b0    = (const float*)d_in[3];
    const float* wmid  = (const float*)d_in[4];
    const float* bmid  = (const float*)d_in[5];
    const float* wskip = (const float*)d_in[6];
    const float* bskip = (const float*)d_in[7];
    const float* wfin  = (const float*)d_in[8];
    const float* bfin  = (const float*)d_in[9];
    const float* wsig  = (const float*)d_in[10];
    const float* bsig  = (const float*)d_in[11];
    const float* e1w1  = (const float*)d_in[12];
    const float* e1b1  = (const float*)d_in[13];
    const float* e1w2  = (const float*)d_in[14];
    const float* e1b2  = (const float*)d_in[15];
    const float* e2w1  = (const float*)d_in[16];
    const float* e2b1  = (const float*)d_in[17];
    const float* e2w2  = (const float*)d_in[18];
    const float* e2b2  = (const float*)d_in[19];
    const float* wrgb  = (const float*)d_in[20];
    const float* brgb  = (const float*)d_in[21];
    float* out = (float*)d_out;

    char* ws = (char*)d_ws;
    int* cnt = (int*)ws;                                        // 256 B
    int* grp = (int*)(ws + 256);                                // 160 KB
    int* nbr = (int*)(ws + 164096);                             // 480 KB -> ends 655616
    unsigned short* wfpq1 = (unsigned short*)(ws + 655616);     // 288 KB
    unsigned short* wfpq2 = (unsigned short*)(ws + 950528);     // 128 KB -> ends 1081600
    unsigned short* wfe1  = (unsigned short*)(ws + 1081600);    // 64 KB
    unsigned short* wfe2  = (unsigned short*)(ws + 1147136);    // 64 KB -> ends 1212672
    float* bufA = (float*)(ws + (2 << 20));                     // 42 MB
    float* bufB = bufA + (size_t)B_TOTAL * 256;                 // 42 MB

    // kNN overlays on bufA (dead before trunk writes fphi/fplo there):
    unsigned short* xbh = (unsigned short*)bufA;
    unsigned short* xbl = xbh + (size_t)B_TOTAL * 64;
    float* cn   = (float*)(xbl + (size_t)B_TOTAL * 64);
    unsigned long long* pkey = (unsigned long long*)(cn + B_TOTAL);
    // trunk outputs / edge intermediates:
    unsigned short* fphi = (unsigned short*)bufA;               // 21 MB
    unsigned short* fplo = fphi + (size_t)B_TOTAL * 256;        // 21 MB
    float* d1 = (float*)bufA;                                   // 21 MB (after pq1 consumed fphi/fplo)
    float* PQ = bufB;                                           // 42 MB
    unsigned short* wfrag = (unsigned short*)((char*)bufB + ((size_t)39 << 20));  // dead before PQ written

    hipMemsetAsync(cnt, 0, 256, stream);
    k_scatter<<<B_TOTAL / 256, 256, 0, stream>>>(bid, grp, cnt);
    k_wprep<<<(557056 + 255) / 256, 256, 0, stream>>>(w0, wmid, wskip, wfin, wfrag);
    k_wprep_pq<<<(18 * 8 * 512 + 255) / 256, 256, 0, stream>>>(e1w1, 283, 18, wfpq1);
    k_wprep_pq<<<(8 * 8 * 512 + 255) / 256, 256, 0, stream>>>(e2w1, 128, 8, wfpq2);
    k_wprep_sq<<<(4 * 8 * 512 + 255) / 256, 256, 0, stream>>>(e1w2, wfe1);
    k_wprep_sq<<<(4 * 8 * 512 + 255) / 256, 256, 0, stream>>>(e2w2, wfe2);
    k_gather<<<dim3(GSZ / 128, NGRP), 256, 0, stream>>>(x, grp, xbh, xbl, cn);
    k_knn_mfma<<<dim3(GSZ / 64, CPART, NGRP), 256, 0, stream>>>(xbh, xbl, cn, pkey);
    k_knn_merge<<<(NGRP * GSZ + 255) / 256, 256, 0, stream>>>(pkey, grp, nbr);
    k_trunk_mfma<<<B_TOTAL / 64, 512, 0, stream>>>(x, wfrag, b0, bmid, bskip, bfin,
                                                   wsig, bsig, fphi, fplo, out);
    k_pq1_mfma<<<B_TOTAL / 32, 256, 0, stream>>>(fphi, fplo, x, wfpq1, PQ);
    k_edge_mfma<0><<<B_TOTAL / 32, 256, 0, stream>>>(PQ, e1b1, wfe1, e1b2, nbr, d1,
                                                     nullptr, nullptr, nullptr);
    k_pq2_mfma<<<B_TOTAL / 32, 256, 0, stream>>>(d1, wfpq2, PQ);
    k_edge_mfma<1><<<B_TOTAL / 32, 256, 0, stream>>>(PQ, e2b1, wfe2, e2b2, nbr, nullptr,
                                                     wrgb, brgb, out);
}

// Round 13
// 459.144 us; speedup vs baseline: 2.7087x; 1.1423x over previous
//
#include <hip/hip_runtime.h>
#include <hip/hip_bf16.h>
#include <math.h>

#define B_TOTAL 40960
#define NGRP 20
#define GSZ 2048
#define CPART 4

typedef short short8 __attribute__((ext_vector_type(8)));
typedef short short4v __attribute__((ext_vector_type(4)));
typedef float f32x4 __attribute__((ext_vector_type(4)));
typedef float f32x16 __attribute__((ext_vector_type(16)));
typedef _Float16 half8 __attribute__((ext_vector_type(8)));
typedef _Float16 half4 __attribute__((ext_vector_type(4)));

// ---------------- group scatter ----------------
__global__ void k_scatter(const int* __restrict__ bid, int* __restrict__ grp,
                          int* __restrict__ cnt)
{
    int i = blockIdx.x * 256 + threadIdx.x;
    if (i < B_TOTAL) {
        int g = bid[i];
        int p = atomicAdd(&cnt[g], 1);
        grp[g * GSZ + p] = i;
    }
}

// ---------------- bf16 helpers (kNN path) ----------------
__device__ __forceinline__ unsigned short bf16rne(float v)
{
    unsigned int u = __float_as_uint(v);
    unsigned int r = (u + 0x7FFFu + ((u >> 16) & 1u)) >> 16;
    return (unsigned short)r;
}

__device__ __forceinline__ float bf2f(unsigned short h)
{
    return __uint_as_float((unsigned int)h << 16);
}

// ---------------- fp16 split helper (MLP path) ----------------
__device__ __forceinline__ void splitf16(const float* v, half8& hi, half8& lo)
{
    #pragma unroll
    for (int j = 0; j < 8; j++) {
        _Float16 h = (_Float16)v[j];
        hi[j] = h;
        lo[j] = (_Float16)(v[j] - (float)h);
    }
}

// ordered-float key
__device__ __forceinline__ unsigned int fkey(float f)
{
    unsigned int u = __float_as_uint(f);
    unsigned int m = (unsigned int)((int)u >> 31) | 0x80000000u;
    return u ^ m;
}

__device__ __forceinline__ void ins3p(unsigned int k, unsigned int i,
    unsigned int& k0, unsigned int& i0, unsigned int& k1, unsigned int& i1,
    unsigned int& k2, unsigned int& i2)
{
    bool c0 = k < k0;
    unsigned int tk = c0 ? k0 : k, ti = c0 ? i0 : i;
    k0 = c0 ? k : k0;  i0 = c0 ? i : i0;
    bool c1 = tk < k1;
    unsigned int sk = c1 ? k1 : tk, si = c1 ? i1 : ti;
    k1 = c1 ? tk : k1; i1 = c1 ? ti : i1;
    bool c2 = sk < k2;
    k2 = c2 ? sk : k2; i2 = c2 ? si : i2;
}

__device__ __forceinline__ void mergerow(unsigned int& k0, unsigned int& i0,
    unsigned int& k1, unsigned int& i1, unsigned int& k2, unsigned int& i2)
{
    #pragma unroll
    for (int m = 1; m <= 8; m <<= 1) {
        unsigned int ok0 = (unsigned int)__shfl_xor((int)k0, m);
        unsigned int oi0 = (unsigned int)__shfl_xor((int)i0, m);
        unsigned int ok1 = (unsigned int)__shfl_xor((int)k1, m);
        unsigned int oi1 = (unsigned int)__shfl_xor((int)i1, m);
        unsigned int ok2 = (unsigned int)__shfl_xor((int)k2, m);
        unsigned int oi2 = (unsigned int)__shfl_xor((int)i2, m);
        ins3p(ok0, oi0, k0, i0, k1, i1, k2, i2);
        ins3p(ok1, oi1, k0, i0, k1, i1, k2, i2);
        ins3p(ok2, oi2, k0, i0, k1, i1, k2, i2);
    }
}

// ---------------- kNN stage 1 ----------------
__global__ __launch_bounds__(256) void k_gather(const float* __restrict__ x,
    const int* __restrict__ grp, unsigned short* __restrict__ xbh,
    unsigned short* __restrict__ xbl, float* __restrict__ cn)
{
    __shared__ float tile[128][65];
    __shared__ int ids[128];
    const int tid = threadIdx.x;
    const int g = blockIdx.y;
    const int q0 = blockIdx.x * 128;
    if (tid < 128) ids[tid] = grp[g * GSZ + q0 + tid];
    __syncthreads();
    for (int s = tid; s < 128 * 64; s += 256) {
        int q = s >> 6, d = s & 63;
        tile[q][d] = (d < 63) ? x[(size_t)ids[q] * 90 + d] : 0.f;
    }
    __syncthreads();
    if (tid < 128) {
        float a = 0.f;
        #pragma unroll
        for (int d = 0; d < 63; d++) a = fmaf(tile[tid][d], tile[tid][d], a);
        cn[g * GSZ + q0 + tid] = a;
    }
    for (int s = tid; s < 128 * 32; s += 256) {
        int q = s >> 5, dp = (s & 31) << 1;
        float v0 = tile[q][dp], v1 = tile[q][dp + 1];
        unsigned short h0 = bf16rne(v0), h1 = bf16rne(v1);
        unsigned short l0 = bf16rne(v0 - bf2f(h0)), l1 = bf16rne(v1 - bf2f(h1));
        size_t pt = (size_t)g * GSZ + q0 + q;
        ((unsigned int*)xbh)[pt * 32 + (dp >> 1)] = (unsigned int)h0 | ((unsigned int)h1 << 16);
        ((unsigned int*)xbl)[pt * 32 + (dp >> 1)] = (unsigned int)l0 | ((unsigned int)l1 << 16);
    }
}

// ---------------- kNN stage 2 (bf16 split, unchanged) ----------------
__global__ __launch_bounds__(256) void k_knn_mfma(const unsigned short* __restrict__ xbh,
    const unsigned short* __restrict__ xbl, const float* __restrict__ cn,
    unsigned long long* __restrict__ pkey)
{
    __shared__ char cbuf[2][16384];
    const int tid = threadIdx.x;
    const int lane = tid & 63;
    const int wave = tid >> 6;
    const int g = blockIdx.z;
    const int part = blockIdx.y;
    const int qt0 = blockIdx.x * 64 + wave * 16;
    const size_t gbase = (size_t)g * GSZ;
    const int lp = lane & 15;
    const int kgrp = lane >> 4;
    const int kg = kgrp << 3;

    const size_t qb = (gbase + qt0 + lp) * 64;
    short8 ah0 = *(const short8*)(xbh + qb + kg);
    short8 ah1 = *(const short8*)(xbh + qb + 32 + kg);
    short8 al0 = *(const short8*)(xbl + qb + kg);
    short8 al1 = *(const short8*)(xbl + qb + 32 + kg);

    const int qp0 = qt0 + (kgrp << 2);

    unsigned int K00 = ~0u, I00 = 0, K01 = ~0u, I01 = 0, K02 = ~0u, I02 = 0;
    unsigned int K10 = ~0u, I10 = 0, K11 = ~0u, I11 = 0, K12 = ~0u, I12 = 0;
    unsigned int K20 = ~0u, I20 = 0, K21 = ~0u, I21 = 0, K22 = ~0u, I22 = 0;
    unsigned int K30 = ~0u, I30 = 0, K31 = ~0u, I31 = 0, K32 = ~0u, I32 = 0;

    const int scand = tid & 63;
    const int cbeg = part * (GSZ / CPART);
    const int s0 = wave, s1 = 4 + wave, s2 = 8 + wave, s3 = 12 + wave;
    const unsigned short* pl0 = (s0 < 8) ? xbh : xbl;
    const unsigned short* pl1 = (s1 < 8) ? xbh : xbl;
    const unsigned short* pl2 = (s2 < 8) ? xbh : xbl;
    const unsigned short* pl3 = (s3 < 8) ? xbh : xbl;

    short8 st0, st1, st2, st3;
    {
        size_t cb = (gbase + cbeg + scand) * 64;
        st0 = *(const short8*)(pl0 + cb + (s0 & 7) * 8);
        st1 = *(const short8*)(pl1 + cb + (s1 & 7) * 8);
        st2 = *(const short8*)(pl2 + cb + (s2 & 7) * 8);
        st3 = *(const short8*)(pl3 + cb + (s3 & 7) * 8);
    }
    *(short8*)&cbuf[0][(s0 << 10) + (scand << 4)] = st0;
    *(short8*)&cbuf[0][(s1 << 10) + (scand << 4)] = st1;
    *(short8*)&cbuf[0][(s2 << 10) + (scand << 4)] = st2;
    *(short8*)&cbuf[0][(s3 << 10) + (scand << 4)] = st3;

    for (int ch = 0; ch < 8; ch++) {
        const int cur = ch & 1;
        __syncthreads();
        if (ch < 7) {
            size_t cb = (gbase + cbeg + (ch + 1) * 64 + scand) * 64;
            st0 = *(const short8*)(pl0 + cb + (s0 & 7) * 8);
            st1 = *(const short8*)(pl1 + cb + (s1 & 7) * 8);
            st2 = *(const short8*)(pl2 + cb + (s2 & 7) * 8);
            st3 = *(const short8*)(pl3 + cb + (s3 & 7) * 8);
        }
        const int cc0 = cbeg + ch * 64;
        #pragma unroll
        for (int ct = 0; ct < 4; ct++) {
            const int coff = ((ct * 16 + lp) << 4);
            short8 bh0 = *(const short8*)&cbuf[cur][((kgrp)      << 10) + coff];
            short8 bh1 = *(const short8*)&cbuf[cur][((4 + kgrp)  << 10) + coff];
            short8 bl0 = *(const short8*)&cbuf[cur][((8 + kgrp)  << 10) + coff];
            short8 bl1 = *(const short8*)&cbuf[cur][((12 + kgrp) << 10) + coff];
            f32x4 acc = {0.f, 0.f, 0.f, 0.f};
            acc = __builtin_amdgcn_mfma_f32_16x16x32_bf16(ah0, bh0, acc, 0, 0, 0);
            acc = __builtin_amdgcn_mfma_f32_16x16x32_bf16(ah1, bh1, acc, 0, 0, 0);
            acc = __builtin_amdgcn_mfma_f32_16x16x32_bf16(al0, bh0, acc, 0, 0, 0);
            acc = __builtin_amdgcn_mfma_f32_16x16x32_bf16(al1, bh1, acc, 0, 0, 0);
            acc = __builtin_amdgcn_mfma_f32_16x16x32_bf16(ah0, bl0, acc, 0, 0, 0);
            acc = __builtin_amdgcn_mfma_f32_16x16x32_bf16(ah1, bl1, acc, 0, 0, 0);
            const float cnv = cn[gbase + cc0 + ct * 16 + lp];
            const int cpos = cc0 + ct * 16 + lp;
            const unsigned int ci = (unsigned int)cpos;
            {
                unsigned int k = fkey(fmaf(-2.f, acc[0], cnv));
                k = (cpos == qp0 + 0) ? 0xFFFFFFFFu : k;
                ins3p(k, ci, K00, I00, K01, I01, K02, I02);
            }
            {
                unsigned int k = fkey(fmaf(-2.f, acc[1], cnv));
                k = (cpos == qp0 + 1) ? 0xFFFFFFFFu : k;
                ins3p(k, ci, K10, I10, K11, I11, K12, I12);
            }
            {
                unsigned int k = fkey(fmaf(-2.f, acc[2], cnv));
                k = (cpos == qp0 + 2) ? 0xFFFFFFFFu : k;
                ins3p(k, ci, K20, I20, K21, I21, K22, I22);
            }
            {
                unsigned int k = fkey(fmaf(-2.f, acc[3], cnv));
                k = (cpos == qp0 + 3) ? 0xFFFFFFFFu : k;
                ins3p(k, ci, K30, I30, K31, I31, K32, I32);
            }
        }
        if (ch < 7) {
            *(short8*)&cbuf[cur ^ 1][(s0 << 10) + (scand << 4)] = st0;
            *(short8*)&cbuf[cur ^ 1][(s1 << 10) + (scand << 4)] = st1;
            *(short8*)&cbuf[cur ^ 1][(s2 << 10) + (scand << 4)] = st2;
            *(short8*)&cbuf[cur ^ 1][(s3 << 10) + (scand << 4)] = st3;
        }
    }

    mergerow(K00, I00, K01, I01, K02, I02);
    mergerow(K10, I10, K11, I11, K12, I12);
    mergerow(K20, I20, K21, I21, K22, I22);
    mergerow(K30, I30, K31, I31, K32, I32);

    if (lp == 0) {
        size_t ob = (gbase + (size_t)qp0) * (CPART * 3) + part * 3;
        pkey[ob + 0]  = ((unsigned long long)K00 << 32) | I00;
        pkey[ob + 1]  = ((unsigned long long)K01 << 32) | I01;
        pkey[ob + 2]  = ((unsigned long long)K02 << 32) | I02;
        pkey[ob + 12] = ((unsigned long long)K10 << 32) | I10;
        pkey[ob + 13] = ((unsigned long long)K11 << 32) | I11;
        pkey[ob + 14] = ((unsigned long long)K12 << 32) | I12;
        pkey[ob + 24] = ((unsigned long long)K20 << 32) | I20;
        pkey[ob + 25] = ((unsigned long long)K21 << 32) | I21;
        pkey[ob + 26] = ((unsigned long long)K22 << 32) | I22;
        pkey[ob + 36] = ((unsigned long long)K30 << 32) | I30;
        pkey[ob + 37] = ((unsigned long long)K31 << 32) | I31;
        pkey[ob + 38] = ((unsigned long long)K32 << 32) | I32;
    }
}

// ---------------- kNN stage 3 ----------------
__device__ __forceinline__ void ins3u(unsigned long long k,
    unsigned long long& k0, unsigned long long& k1, unsigned long long& k2)
{
    if (k < k0)      { k2 = k1; k1 = k0; k0 = k; }
    else if (k < k1) { k2 = k1; k1 = k; }
    else if (k < k2) { k2 = k; }
}

__global__ void k_knn_merge(const unsigned long long* __restrict__ pkey,
                            const int* __restrict__ grp, int* __restrict__ nbr)
{
    int t = blockIdx.x * 256 + threadIdx.x;
    if (t >= NGRP * GSZ) return;
    int g = t >> 11;
    unsigned long long k0 = ~0ull, k1 = ~0ull, k2 = ~0ull;
    const unsigned long long* pk = pkey + (size_t)t * (CPART * 3);
    #pragma unroll
    for (int r = 0; r < CPART * 3; r++) ins3u(pk[r], k0, k1, k2);
    int qi = grp[t];
    nbr[(size_t)qi * 3 + 0] = grp[(g << 11) + (int)(k0 & 0xFFFFFFFFull)];
    nbr[(size_t)qi * 3 + 1] = grp[(g << 11) + (int)(k1 & 0xFFFFFFFFull)];
    nbr[(size_t)qi * 3 + 2] = grp[(g << 11) + (int)(k2 & 0xFFFFFFFFull)];
}

// ---------------- trunk weight prep: fp16 single-plane, fragment-major ----------------
__global__ void k_wprep(const float* __restrict__ w0, const float* __restrict__ wmid,
                        const float* __restrict__ wskip, const float* __restrict__ wfin,
                        _Float16* __restrict__ wfrag)
{
    int t = blockIdx.x * 256 + threadIdx.x;
    if (t >= 557056) return;
    const int CUMa[10] = {0,4,20,36,52,72,88,104,120,136};
    const int KCa[9]   = {4,16,16,16,20,16,16,16,16};
    int q = t >> 12;
    int L = 0;
    #pragma unroll
    for (int i = 0; i < 9; i++) if (q >= CUMa[i + 1]) L = i + 1;
    int cum = 0, kcn = 16;
    #pragma unroll
    for (int i = 0; i < 9; i++) if (L == i) { cum = CUMa[i]; kcn = KCa[i]; }
    int u = t - (cum << 12);
    int j = u & 7, lane = (u >> 3) & 63;
    int ckk = u >> 9;
    int kc = ckk % kcn, ct = ckk / kcn;
    int col = ct * 32 + (lane & 31);
    int k = kc * 16 + ((lane >> 5) << 3) + j;
    float w;
    if (L == 0)      w = (k < 63)  ? w0[k * 256 + col] : 0.f;
    else if (L == 4) w = (k < 256) ? wskip[(63 + k) * 256 + col]
                       : (k < 319) ? wskip[(k - 256) * 256 + col] : 0.f;
    else if (L == 8) w = wfin[k * 256 + col];
    else {
        int m = (L <= 3) ? (L - 1) : (L - 2);
        w = wmid[(size_t)m * 65536 + k * 256 + col];
    }
    wfrag[((size_t)cum << 12) + (size_t)ckk * 512 + lane * 8 + j] = (_Float16)w;
}

// ---------------- PQ weight prep: fp16 single-plane ----------------
__global__ void k_wprep_pq(const float* __restrict__ src, int K, int KCN,
                           _Float16* __restrict__ dst)
{
    int t = blockIdx.x * 256 + threadIdx.x;
    if (t >= KCN * 8 * 512) return;
    int j = t & 7, lane = (t >> 3) & 63;
    int ckk = t >> 9;
    int kc = ckk % KCN, ct = ckk / KCN;
    int col = ct * 32 + (lane & 31);
    int k = kc * 16 + ((lane >> 5) << 3) + j;
    float w = 0.f;
    if (k < K) w = (col < 128) ? src[(size_t)k * 128 + col]
                               : src[(size_t)(K + k) * 128 + (col - 128)];
    dst[(size_t)ckk * 512 + lane * 8 + j] = (_Float16)w;
}

// ---------------- square weight prep: fp16 single-plane ----------------
__global__ void k_wprep_sq(const float* __restrict__ src, _Float16* __restrict__ dst)
{
    int t = blockIdx.x * 256 + threadIdx.x;
    if (t >= 4 * 8 * 512) return;
    int j = t & 7, lane = (t >> 3) & 63;
    int ckk = t >> 9;
    int kc = ckk & 7, ct = ckk >> 3;
    int col = ct * 32 + (lane & 31);
    int k = kc * 16 + ((lane >> 5) << 3) + j;
    dst[(size_t)ckk * 512 + lane * 8 + j] = (_Float16)src[(size_t)k * 128 + col];
}

// ---------------- fused trunk MLP: fp16 2-MFMA split, 8 waves, 64-row tile ----------------
template<int KCH, int KCX, int OUTMODE>
__device__ __forceinline__ void mlayer64(_Float16 (*Hh)[264], _Float16 (*Hl)[264],
    int rowbase, const float* __restrict__ x, const _Float16* __restrict__ wl,
    const float* __restrict__ bias, _Float16* __restrict__ gh,
    _Float16* __restrict__ gl, int lane, int wave)
{
    const int r31 = lane & 31, g = lane >> 5;
    constexpr int KC = KCH + KCX;
    const int ct = wave;
    f32x16 acc0, acc1;
    #pragma unroll
    for (int r = 0; r < 16; r++) { acc0[r] = 0.f; acc1[r] = 0.f; }
    const _Float16* wp = wl + (size_t)ct * KC * 512 + lane * 8;
    #pragma unroll
    for (int kc = 0; kc < KCH; kc++) {
        half8 ah0 = *(const half8*)&Hh[r31][kc * 16 + g * 8];
        half8 al0 = *(const half8*)&Hl[r31][kc * 16 + g * 8];
        half8 ah1 = *(const half8*)&Hh[32 + r31][kc * 16 + g * 8];
        half8 al1 = *(const half8*)&Hl[32 + r31][kc * 16 + g * 8];
        half8 b = *(const half8*)(wp + kc * 512);
        acc0 = __builtin_amdgcn_mfma_f32_32x32x16_f16(ah0, b, acc0, 0, 0, 0);
        acc1 = __builtin_amdgcn_mfma_f32_32x32x16_f16(ah1, b, acc1, 0, 0, 0);
        acc0 = __builtin_amdgcn_mfma_f32_32x32x16_f16(al0, b, acc0, 0, 0, 0);
        acc1 = __builtin_amdgcn_mfma_f32_32x32x16_f16(al1, b, acc1, 0, 0, 0);
    }
    #pragma unroll
    for (int t = 0; t < KCX; t++) {
        const int kc = KCH + t;
        float v0[8], v1[8];
        #pragma unroll
        for (int j = 0; j < 8; j++) {
            int kx = t * 16 + g * 8 + j;
            v0[j] = (kx < 63) ? x[(size_t)(rowbase + r31) * 90 + kx] : 0.f;
            v1[j] = (kx < 63) ? x[(size_t)(rowbase + 32 + r31) * 90 + kx] : 0.f;
        }
        half8 xh0, xl0, xh1, xl1;
        splitf16(v0, xh0, xl0);
        splitf16(v1, xh1, xl1);
        half8 b = *(const half8*)(wp + kc * 512);
        acc0 = __builtin_amdgcn_mfma_f32_32x32x16_f16(xh0, b, acc0, 0, 0, 0);
        acc1 = __builtin_amdgcn_mfma_f32_32x32x16_f16(xh1, b, acc1, 0, 0, 0);
        acc0 = __builtin_amdgcn_mfma_f32_32x32x16_f16(xl0, b, acc0, 0, 0, 0);
        acc1 = __builtin_amdgcn_mfma_f32_32x32x16_f16(xl1, b, acc1, 0, 0, 0);
    }
    const float bv = bias[ct * 32 + r31];
    if (OUTMODE == 0) {
        __syncthreads();
        #pragma unroll
        for (int r = 0; r < 16; r++) {
            int row = (r & 3) + 8 * (r >> 2) + 4 * g;
            float v0 = fmaxf(acc0[r] + bv, 0.f);
            float v1 = fmaxf(acc1[r] + bv, 0.f);
            _Float16 h0 = (_Float16)v0, h1 = (_Float16)v1;
            Hh[row][ct * 32 + r31] = h0;
            Hl[row][ct * 32 + r31] = (_Float16)(v0 - (float)h0);
            Hh[32 + row][ct * 32 + r31] = h1;
            Hl[32 + row][ct * 32 + r31] = (_Float16)(v1 - (float)h1);
        }
        __syncthreads();
    } else {
        #pragma unroll
        for (int r = 0; r < 16; r++) {
            int row = (r & 3) + 8 * (r >> 2) + 4 * g;
            float v0 = acc0[r] + bv;
            float v1 = acc1[r] + bv;
            _Float16 h0 = (_Float16)v0, h1 = (_Float16)v1;
            size_t o0 = (size_t)(rowbase + row) * 256 + ct * 32 + r31;
            size_t o1 = (size_t)(rowbase + 32 + row) * 256 + ct * 32 + r31;
            gh[o0] = h0;
            gl[o0] = (_Float16)(v0 - (float)h0);
            gh[o1] = h1;
            gl[o1] = (_Float16)(v1 - (float)h1);
        }
    }
}

__global__ __launch_bounds__(512, 4) void k_trunk_mfma(const float* __restrict__ x,
    const _Float16* __restrict__ wfrag,
    const float* __restrict__ b0, const float* __restrict__ bmid,
    const float* __restrict__ bskip, const float* __restrict__ bfin,
    const float* __restrict__ wsig, const float* __restrict__ bsig,
    _Float16* __restrict__ fphi, _Float16* __restrict__ fplo,
    float* __restrict__ out)
{
    __shared__ _Float16 Hh[64][264];
    __shared__ _Float16 Hl[64][264];
    const int lane = threadIdx.x & 63;
    const int wave = threadIdx.x >> 6;
    const int rowbase = blockIdx.x * 64;
    const _Float16* W = wfrag;
    mlayer64<0, 4, 0>(Hh, Hl, rowbase, x, W + (size_t)0   * 4096, b0,          nullptr, nullptr, lane, wave);
    mlayer64<16,0, 0>(Hh, Hl, rowbase, x, W + (size_t)4   * 4096, bmid + 0,    nullptr, nullptr, lane, wave);
    mlayer64<16,0, 0>(Hh, Hl, rowbase, x, W + (size_t)20  * 4096, bmid + 256,  nullptr, nullptr, lane, wave);
    mlayer64<16,0, 0>(Hh, Hl, rowbase, x, W + (size_t)36  * 4096, bmid + 512,  nullptr, nullptr, lane, wave);
    mlayer64<16,4, 0>(Hh, Hl, rowbase, x, W + (size_t)52  * 4096, bskip,       nullptr, nullptr, lane, wave);
    mlayer64<16,0, 0>(Hh, Hl, rowbase, x, W + (size_t)72  * 4096, bmid + 768,  nullptr, nullptr, lane, wave);
    mlayer64<16,0, 0>(Hh, Hl, rowbase, x, W + (size_t)88  * 4096, bmid + 1024, nullptr, nullptr, lane, wave);
    mlayer64<16,0, 0>(Hh, Hl, rowbase, x, W + (size_t)104 * 4096, bmid + 1280, nullptr, nullptr, lane, wave);
    mlayer64<16,0, 1>(Hh, Hl, rowbase, x, W + (size_t)120 * 4096, bfin,        fphi,    fplo,    lane, wave);
    if (wave < 2) {
        const int r31 = lane & 31, g = lane >> 5;
        const int row = wave * 32 + r31;
        float s = 0.f;
        #pragma unroll
        for (int kk = 0; kk < 32; kk++) {
            half4 hh = *(const half4*)&Hh[row][g * 128 + kk * 4];
            half4 hl = *(const half4*)&Hl[row][g * 128 + kk * 4];
            float4 wv = *(const float4*)&wsig[g * 128 + kk * 4];
            s = fmaf((float)hh[0] + (float)hl[0], wv.x, s);
            s = fmaf((float)hh[1] + (float)hl[1], wv.y, s);
            s = fmaf((float)hh[2] + (float)hl[2], wv.z, s);
            s = fmaf((float)hh[3] + (float)hl[3], wv.w, s);
        }
        s += __shfl_xor(s, 32);
        if (lane < 32) out[(size_t)(rowbase + row) * 4 + 3] = s + bsig[0];
    }
}

// ---------------- PQ1: [feat(fp16 planes), dir(27)] x 288 -> 256 cols ----------------
__global__ __launch_bounds__(256, 4) void k_pq1_mfma(
    const _Float16* __restrict__ fphi, const _Float16* __restrict__ fplo,
    const float* __restrict__ x, const _Float16* __restrict__ wf,
    float* __restrict__ PQ)
{
    __shared__ _Float16 Hh[32][302];
    __shared__ _Float16 Hl[32][302];
    const int tid = threadIdx.x;
    const int lane = tid & 63, wave = tid >> 6;
    const int r31 = lane & 31, g = lane >> 5;
    const int rowbase = blockIdx.x * 32;
    for (int s = tid; s < 32 * 32; s += 256) {
        int r = s >> 5, c8 = (s & 31) << 3;
        *(half8*)&Hh[r][c8] = *(const half8*)&fphi[(size_t)(rowbase + r) * 256 + c8];
        *(half8*)&Hl[r][c8] = *(const half8*)&fplo[(size_t)(rowbase + r) * 256 + c8];
    }
    for (int s = tid; s < 32 * 32; s += 256) {
        int r = s >> 5, d = s & 31;
        float v = (d < 27) ? x[(size_t)(rowbase + r) * 90 + 63 + d] : 0.f;
        _Float16 h = (_Float16)v;
        Hh[r][256 + d] = h;
        Hl[r][256 + d] = (_Float16)(v - (float)h);
    }
    __syncthreads();
    const int ct0 = wave * 2;
    f32x16 acc0, acc1;
    #pragma unroll
    for (int r = 0; r < 16; r++) { acc0[r] = 0.f; acc1[r] = 0.f; }
    const _Float16* wp0 = wf + (size_t)ct0 * 18 * 512 + lane * 8;
    const _Float16* wp1 = wp0 + (size_t)18 * 512;
    #pragma unroll
    for (int kc = 0; kc < 18; kc++) {
        half8 ah = *(const half8*)&Hh[r31][kc * 16 + g * 8];
        half8 al = *(const half8*)&Hl[r31][kc * 16 + g * 8];
        half8 b0 = *(const half8*)(wp0 + kc * 512);
        half8 b1 = *(const half8*)(wp1 + kc * 512);
        acc0 = __builtin_amdgcn_mfma_f32_32x32x16_f16(ah, b0, acc0, 0, 0, 0);
        acc1 = __builtin_amdgcn_mfma_f32_32x32x16_f16(ah, b1, acc1, 0, 0, 0);
        acc0 = __builtin_amdgcn_mfma_f32_32x32x16_f16(al, b0, acc0, 0, 0, 0);
        acc1 = __builtin_amdgcn_mfma_f32_32x32x16_f16(al, b1, acc1, 0, 0, 0);
    }
    #pragma unroll
    for (int r = 0; r < 16; r++) {
        int row = (r & 3) + 8 * (r >> 2) + 4 * g;
        PQ[(size_t)(rowbase + row) * 256 + ct0 * 32 + r31] = acc0[r];
        PQ[(size_t)(rowbase + row) * 256 + ct0 * 32 + 32 + r31] = acc1[r];
    }
}

// ---------------- PQ2: d1(128 fp32) -> 256 cols ----------------
__global__ __launch_bounds__(256, 4) void k_pq2_mfma(
    const float* __restrict__ d1, const _Float16* __restrict__ wf,
    float* __restrict__ PQ)
{
    __shared__ _Float16 Hh[32][134];
    __shared__ _Float16 Hl[32][134];
    const int tid = threadIdx.x;
    const int lane = tid & 63, wave = tid >> 6;
    const int r31 = lane & 31, g = lane >> 5;
    const int rowbase = blockIdx.x * 32;
    for (int s = tid; s < 32 * 128; s += 256) {
        int r = s >> 7, c = s & 127;
        float v = d1[(size_t)(rowbase + r) * 128 + c];
        _Float16 h = (_Float16)v;
        Hh[r][c] = h;
        Hl[r][c] = (_Float16)(v - (float)h);
    }
    __syncthreads();
    const int ct0 = wave * 2;
    f32x16 acc0, acc1;
    #pragma unroll
    for (int r = 0; r < 16; r++) { acc0[r] = 0.f; acc1[r] = 0.f; }
    const _Float16* wp0 = wf + (size_t)ct0 * 8 * 512 + lane * 8;
    const _Float16* wp1 = wp0 + (size_t)8 * 512;
    #pragma unroll
    for (int kc = 0; kc < 8; kc++) {
        half8 ah = *(const half8*)&Hh[r31][kc * 16 + g * 8];
        half8 al = *(const half8*)&Hl[r31][kc * 16 + g * 8];
        half8 b0 = *(const half8*)(wp0 + kc * 512);
        half8 b1 = *(const half8*)(wp1 + kc * 512);
        acc0 = __builtin_amdgcn_mfma_f32_32x32x16_f16(ah, b0, acc0, 0, 0, 0);
        acc1 = __builtin_amdgcn_mfma_f32_32x32x16_f16(ah, b1, acc1, 0, 0, 0);
        acc0 = __builtin_amdgcn_mfma_f32_32x32x16_f16(al, b0, acc0, 0, 0, 0);
        acc1 = __builtin_amdgcn_mfma_f32_32x32x16_f16(al, b1, acc1, 0, 0, 0);
    }
    #pragma unroll
    for (int r = 0; r < 16; r++) {
        int row = (r & 3) + 8 * (r >> 2) + 4 * g;
        PQ[(size_t)(rowbase + row) * 256 + ct0 * 32 + r31] = acc0[r];
        PQ[(size_t)(rowbase + row) * 256 + ct0 * 32 + 32 + r31] = acc1[r];
    }
}

// ---------------- edge conv via MFMA: fp16 2-split, 4 padded edge rows/node ----------------
template<int RGB>
__global__ __launch_bounds__(256) void k_edge_mfma(const float* __restrict__ PQ,
    const float* __restrict__ b1, const _Float16* __restrict__ wf2,
    const float* __restrict__ b2, const int* __restrict__ nbr,
    float* __restrict__ dout,
    const float* __restrict__ wrgb, const float* __restrict__ brgb,
    float* __restrict__ out)
{
    __shared__ _Float16 Hh[128][136];
    __shared__ _Float16 Hl[128][136];
    const int tid = threadIdx.x;
    const int lane = tid & 63, wave = tid >> 6;
    const int r31 = lane & 31, g = lane >> 5;
    const int n0 = blockIdx.x * 32;

    for (int s = tid; s < 128 * 32; s += 256) {
        int e = s >> 5, c4 = (s & 31) << 2;
        int n = e >> 2, jj = e & 3;
        half4 zh = {(_Float16)0.f, (_Float16)0.f, (_Float16)0.f, (_Float16)0.f};
        if (jj < 3) {
            int i = n0 + n;
            int j = nbr[(size_t)i * 3 + jj];
            float4 p  = *(const float4*)&PQ[(size_t)i * 256 + c4];
            float4 qi = *(const float4*)&PQ[(size_t)i * 256 + 128 + c4];
            float4 qj = *(const float4*)&PQ[(size_t)j * 256 + 128 + c4];
            float4 bv = *(const float4*)&b1[c4];
            float v[4];
            v[0] = fmaxf(p.x + bv.x + qj.x - qi.x, 0.f);
            v[1] = fmaxf(p.y + bv.y + qj.y - qi.y, 0.f);
            v[2] = fmaxf(p.z + bv.z + qj.z - qi.z, 0.f);
            v[3] = fmaxf(p.w + bv.w + qj.w - qi.w, 0.f);
            half4 hh, hl;
            #pragma unroll
            for (int u = 0; u < 4; u++) {
                _Float16 h = (_Float16)v[u];
                hh[u] = h;
                hl[u] = (_Float16)(v[u] - (float)h);
            }
            *(half4*)&Hh[e][c4] = hh;
            *(half4*)&Hl[e][c4] = hl;
        } else {
            *(half4*)&Hh[e][c4] = zh;
            *(half4*)&Hl[e][c4] = zh;
        }
    }
    __syncthreads();

    const int ct = wave;
    f32x16 a0, a1, a2, a3;
    #pragma unroll
    for (int r = 0; r < 16; r++) { a0[r] = 0.f; a1[r] = 0.f; a2[r] = 0.f; a3[r] = 0.f; }
    const _Float16* wp = wf2 + (size_t)ct * 8 * 512 + lane * 8;
    #pragma unroll
    for (int kc = 0; kc < 8; kc++) {
        half8 b = *(const half8*)(wp + kc * 512);
        half8 h0 = *(const half8*)&Hh[r31][kc * 16 + g * 8];
        half8 l0 = *(const half8*)&Hl[r31][kc * 16 + g * 8];
        a0 = __builtin_amdgcn_mfma_f32_32x32x16_f16(h0, b, a0, 0, 0, 0);
        a0 = __builtin_amdgcn_mfma_f32_32x32x16_f16(l0, b, a0, 0, 0, 0);
        half8 h1 = *(const half8*)&Hh[32 + r31][kc * 16 + g * 8];
        half8 l1 = *(const half8*)&Hl[32 + r31][kc * 16 + g * 8];
        a1 = __builtin_amdgcn_mfma_f32_32x32x16_f16(h1, b, a1, 0, 0, 0);
        a1 = __builtin_amdgcn_mfma_f32_32x32x16_f16(l1, b, a1, 0, 0, 0);
        half8 h2 = *(const half8*)&Hh[64 + r31][kc * 16 + g * 8];
        half8 l2 = *(const half8*)&Hl[64 + r31][kc * 16 + g * 8];
        a2 = __builtin_amdgcn_mfma_f32_32x32x16_f16(h2, b, a2, 0, 0, 0);
        a2 = __builtin_amdgcn_mfma_f32_32x32x16_f16(l2, b, a2, 0, 0, 0);
        half8 h3 = *(const half8*)&Hh[96 + r31][kc * 16 + g * 8];
        half8 l3 = *(const half8*)&Hl[96 + r31][kc * 16 + g * 8];
        a3 = __builtin_amdgcn_mfma_f32_32x32x16_f16(h3, b, a3, 0, 0, 0);
        a3 = __builtin_amdgcn_mfma_f32_32x32x16_f16(l3, b, a3, 0, 0, 0);
    }
    const float bv = b2[ct * 32 + r31];
    const int col = ct * 32 + r31;

    if (!RGB) {
        #pragma unroll
        for (int q = 0; q < 4; q++) {
            float s0 = fmaxf(a0[4*q] + bv, 0.f) + fmaxf(a0[4*q+1] + bv, 0.f) + fmaxf(a0[4*q+2] + bv, 0.f);
            float s1 = fmaxf(a1[4*q] + bv, 0.f) + fmaxf(a1[4*q+1] + bv, 0.f) + fmaxf(a1[4*q+2] + bv, 0.f);
            float s2 = fmaxf(a2[4*q] + bv, 0.f) + fmaxf(a2[4*q+1] + bv, 0.f) + fmaxf(a2[4*q+2] + bv, 0.f);
            float s3 = fmaxf(a3[4*q] + bv, 0.f) + fmaxf(a3[4*q+1] + bv, 0.f) + fmaxf(a3[4*q+2] + bv, 0.f);
            int nq = 2 * q + g;
            dout[(size_t)(n0 + 0  + nq) * 128 + col] = s0 * (1.f / 3.f);
            dout[(size_t)(n0 + 8  + nq) * 128 + col] = s1 * (1.f / 3.f);
            dout[(size_t)(n0 + 16 + nq) * 128 + col] = s2 * (1.f / 3.f);
            dout[(size_t)(n0 + 24 + nq) * 128 + col] = s3 * (1.f / 3.f);
        }
    } else {
        __syncthreads();
        float* d2L = (float*)&Hh[0][0];
        #pragma unroll
        for (int q = 0; q < 4; q++) {
            float s0 = fmaxf(a0[4*q] + bv, 0.f) + fmaxf(a0[4*q+1] + bv, 0.f) + fmaxf(a0[4*q+2] + bv, 0.f);
            float s1 = fmaxf(a1[4*q] + bv, 0.f) + fmaxf(a1[4*q+1] + bv, 0.f) + fmaxf(a1[4*q+2] + bv, 0.f);
            float s2 = fmaxf(a2[4*q] + bv, 0.f) + fmaxf(a2[4*q+1] + bv, 0.f) + fmaxf(a2[4*q+2] + bv, 0.f);
            float s3 = fmaxf(a3[4*q] + bv, 0.f) + fmaxf(a3[4*q+1] + bv, 0.f) + fmaxf(a3[4*q+2] + bv, 0.f);
            int nq = 2 * q + g;
            d2L[(0  + nq) * 132 + col] = s0 * (1.f / 3.f);
            d2L[(8  + nq) * 132 + col] = s1 * (1.f / 3.f);
            d2L[(16 + nq) * 132 + col] = s2 * (1.f / 3.f);
            d2L[(24 + nq) * 132 + col] = s3 * (1.f / 3.f);
        }
        __syncthreads();
        if (tid < 96) {
            int n = tid / 3, ch = tid - 3 * (tid / 3);
            float s = brgb[ch];
            for (int k = 0; k < 128; k++) s = fmaf(d2L[n * 132 + k], wrgb[k * 3 + ch], s);
            out[(size_t)(n0 + n) * 4 + ch] = 1.f / (1.f + expf(-s));
        }
    }
}

// ---------------- launch ----------------
extern "C" void kernel_launch(void* const* d_in, const int* in_sizes, int n_in,
                              void* d_out, int out_size, void* d_ws, size_t ws_size,
                              hipStream_t stream)
{
    const float* x     = (const float*)d_in[0];
    const int*   bid   = (const int*)d_in[1];
    const float* w0    = (const float*)d_in[2];
    const float* b0    = (const float*)d_in[3];
    const float* wmid  = (const float*)d_in[4];
    const float* bmid  = (const float*)d_in[5];
    const float* wskip = (const float*)d_in[6];
    const float* bskip = (const float*)d_in[7];
    const float* wfin  = (const float*)d_in[8];
    const float* bfin  = (const float*)d_in[9];
    const float* wsig  = (const float*)d_in[10];
    const float* bsig  = (const float*)d_in[11];
    const float* e1w1  = (const float*)d_in[12];
    const float* e1b1  = (const float*)d_in[13];
    const float* e1w2  = (const float*)d_in[14];
    const float* e1b2  = (const float*)d_in[15];
    const float* e2w1  = (const float*)d_in[16];
    const float* e2b1  = (const float*)d_in[17];
    const float* e2w2  = (const float*)d_in[18];
    const float* e2b2  = (const float*)d_in[19];
    const float* wrgb  = (const float*)d_in[20];
    const float* brgb  = (const float*)d_in[21];
    float* out = (float*)d_out;

    char* ws = (char*)d_ws;
    int* cnt = (int*)ws;
    int* grp = (int*)(ws + 256);
    int* nbr = (int*)(ws + 164096);
    _Float16* wfpq1 = (_Float16*)(ws + 655616);     // 144 KB used
    _Float16* wfpq2 = (_Float16*)(ws + 950528);     // 64 KB used
    _Float16* wfe1  = (_Float16*)(ws + 1081600);    // 32 KB used
    _Float16* wfe2  = (_Float16*)(ws + 1147136);    // 32 KB used
    float* bufA = (float*)(ws + (2 << 20));
    float* bufB = bufA + (size_t)B_TOTAL * 256;

    unsigned short* xbh = (unsigned short*)bufA;
    unsigned short* xbl = xbh + (size_t)B_TOTAL * 64;
    float* cn   = (float*)(xbl + (size_t)B_TOTAL * 64);
    unsigned long long* pkey = (unsigned long long*)(cn + B_TOTAL);
    _Float16* fphi = (_Float16*)bufA;
    _Float16* fplo = fphi + (size_t)B_TOTAL * 256;
    float* d1 = (float*)bufA;
    float* PQ = bufB;
    _Float16* wfrag = (_Float16*)((char*)bufB + ((size_t)39 << 20));   // 1.1 MB, dead before PQ written

    hipMemsetAsync(cnt, 0, 256, stream);
    k_scatter<<<B_TOTAL / 256, 256, 0, stream>>>(bid, grp, cnt);
    k_wprep<<<(557056 + 255) / 256, 256, 0, stream>>>(w0, wmid, wskip, wfin, wfrag);
    k_wprep_pq<<<(18 * 8 * 512 + 255) / 256, 256, 0, stream>>>(e1w1, 283, 18, wfpq1);
    k_wprep_pq<<<(8 * 8 * 512 + 255) / 256, 256, 0, stream>>>(e2w1, 128, 8, wfpq2);
    k_wprep_sq<<<(4 * 8 * 512 + 255) / 256, 256, 0, stream>>>(e1w2, wfe1);
    k_wprep_sq<<<(4 * 8 * 512 + 255) / 256, 256, 0, stream>>>(e2w2, wfe2);
    k_gather<<<dim3(GSZ / 128, NGRP), 256, 0, stream>>>(x, grp, xbh, xbl, cn);
    k_knn_mfma<<<dim3(GSZ / 64, CPART, NGRP), 256, 0, stream>>>(xbh, xbl, cn, pkey);
    k_knn_merge<<<(NGRP * GSZ + 255) / 256, 256, 0, stream>>>(pkey, grp, nbr);
    k_trunk_mfma<<<B_TOTAL / 64, 512, 0, stream>>>(x, wfrag, b0, bmid, bskip, bfin,
                                                   wsig, bsig, fphi, fplo, out);
    k_pq1_mfma<<<B_TOTAL / 32, 256, 0, stream>>>(fphi, fplo, x, wfpq1, PQ);
    k_edge_mfma<0><<<B_TOTAL / 32, 256, 0, stream>>>(PQ, e1b1, wfe1, e1b2, nbr, d1,
                                                     nullptr, nullptr, nullptr);
    k_pq2_mfma<<<B_TOTAL / 32, 256, 0, stream>>>(d1, wfpq2, PQ);
    k_edge_mfma<1><<<B_TOTAL / 32, 256, 0, stream>>>(PQ, e2b1, wfe2, e2b2, nbr, nullptr,
                                                     wrgb, brgb, out);
}